// Round 1
// baseline (2367.696 us; speedup 1.0000x reference)
//
#include <hip/hip_runtime.h>
#include <math.h>

#define D   128
#define D2  64   // float2 elements per row
#define WAVE 64

struct Scal {
  double esum, esumsq;     // zero-init
  unsigned maxkey[3];      // zero-init (decodes to -NaN, below all finite)
  float Z[3];              // zero-init
  float emean, einv;       // written by k_efin
};

__device__ __forceinline__ unsigned fkey(float f){
  unsigned b = __float_as_uint(f);
  return (b & 0x80000000u) ? ~b : (b | 0x80000000u);
}
__device__ __forceinline__ float fdec(unsigned k){
  return (k & 0x80000000u) ? __uint_as_float(k & 0x7fffffffu) : __uint_as_float(~k);
}
__device__ __forceinline__ void atomAddF(float* p, float v){
  __hip_atomic_fetch_add(p, v, __ATOMIC_RELAXED, __HIP_MEMORY_SCOPE_AGENT);
}
__device__ __forceinline__ void atomAddD(double* p, double v){
  __hip_atomic_fetch_add(p, v, __ATOMIC_RELAXED, __HIP_MEMORY_SCOPE_AGENT);
}
__device__ __forceinline__ float bcast(float v, int lane){
  return __int_as_float(__builtin_amdgcn_readlane(__float_as_int(v), lane));
}

// ---------- graph prep ----------
__global__ void k_hist(const int* __restrict__ src, const int* __restrict__ dst,
                       int* indeg, int* outdeg, int E){
  int e = blockIdx.x*blockDim.x + threadIdx.x;
  if(e < E){ atomicAdd(&indeg[dst[e]], 1); atomicAdd(&outdeg[src[e]], 1); }
}

// single block, 1024 threads: exclusive prefix sum of indeg -> offsets, offsets[n]=E
__global__ void k_scan(const int* __restrict__ indeg, int* __restrict__ offsets, int n){
  __shared__ int part[1024];
  int t = threadIdx.x;
  int chunk = (n + 1023) / 1024;
  int base = t * chunk;
  int s = 0;
  for(int i = 0; i < chunk; i++){ int idx = base + i; if(idx < n) s += indeg[idx]; }
  part[t] = s; __syncthreads();
  for(int o = 1; o < 1024; o <<= 1){
    int v = (t >= o) ? part[t-o] : 0;
    __syncthreads();
    part[t] += v;
    __syncthreads();
  }
  int run = (t == 0) ? 0 : part[t-1];
  for(int i = 0; i < chunk; i++){
    int idx = base + i;
    if(idx < n){ offsets[idx] = run; run += indeg[idx]; }
  }
  if(t == 1023) offsets[n] = run;
}

__global__ void k_dinv(const int* __restrict__ indeg, float* __restrict__ dinv, int n){
  int i = blockIdx.x*blockDim.x + threadIdx.x;
  if(i < n) dinv[i] = rsqrtf((float)(indeg[i] + 1));  // deg includes self-loop
}

__global__ void k_fill(const int* __restrict__ src, const int* __restrict__ dst,
                       const int* __restrict__ offsets, int* cursor, int* csr, int E){
  int e = blockIdx.x*blockDim.x + threadIdx.x;
  if(e < E){
    int d = dst[e];
    int pos = atomicAdd(&cursor[d], 1);
    csr[offsets[d] + pos] = src[e];
  }
}

// ---------- edge standardization / time diffs ----------
__global__ void k_estats(const float* __restrict__ ea, int E, Scal* sc){
  int i = blockIdx.x*blockDim.x + threadIdx.x;
  int stride = gridDim.x*blockDim.x;
  double s = 0.0, q = 0.0;
  for(; i < E; i += stride){
    float v = fminf(fmaxf(ea[i], -1000.f), 1000.f);
    s += (double)v; q += (double)v * (double)v;
  }
  for(int o = 32; o; o >>= 1){ s += __shfl_xor(s, o); q += __shfl_xor(q, o); }
  __shared__ double ls[4], lq[4];
  int wv = threadIdx.x >> 6;
  if((threadIdx.x & 63) == 0){ ls[wv] = s; lq[wv] = q; }
  __syncthreads();
  if(threadIdx.x == 0){
    double S = ls[0]+ls[1]+ls[2]+ls[3], Q = lq[0]+lq[1]+lq[2]+lq[3];
    atomAddD(&sc->esum, S); atomAddD(&sc->esumsq, Q);
  }
}

__global__ void k_efin(Scal* sc, int E){
  double mean = sc->esum / E;
  double var  = (sc->esumsq - sc->esum*sc->esum/E) / (double)(E - 1); // ddof=1
  double sd   = sqrt(var > 0.0 ? var : 0.0);
  sc->emean = (float)mean;
  sc->einv  = (float)(1.0 / (sd + 1e-9));
}

__global__ void k_td(const float* __restrict__ ea, const int* __restrict__ src,
                     const int* __restrict__ dst, const Scal* sc, float* td, int E){
  int e = blockIdx.x*blockDim.x + threadIdx.x;
  if(e < E){
    float v  = fminf(fmaxf(ea[e], -1000.f), 1000.f);
    float en = (v - sc->emean) * sc->einv;
    atomAddF(&td[src[e]], en);
    atomAddF(&td[dst[e]], en);
  }
}

__global__ void k_tdfin(float* td, const int* __restrict__ indeg,
                        const int* __restrict__ outdeg, int n){
  int i = blockIdx.x*blockDim.x + threadIdx.x;
  if(i < n) td[i] /= fmaxf((float)(indeg[i] + outdeg[i]), 1.f);
}

// ---------- GEMM: out[node,:] = A[node,:] @ W (+cvec), wave-per-node ----------
__global__ void __launch_bounds__(256)
k_gemm(const float* __restrict__ A, const float* __restrict__ W,
       const float* __restrict__ cvec, float* __restrict__ out, int n){
  __shared__ float Ws[D*D];
  {
    const float4* W4 = (const float4*)W;
    float4* Ws4 = (float4*)Ws;
    for(int i = threadIdx.x; i < D*D/4; i += blockDim.x) Ws4[i] = W4[i];
  }
  __syncthreads();
  int lane = threadIdx.x & 63;
  int wid  = (blockIdx.x*blockDim.x + threadIdx.x) >> 6;
  int nw   = (gridDim.x*blockDim.x) >> 6;
  float c0 = 0.f, c1 = 0.f;
  if(cvec){ float2 cc = ((const float2*)cvec)[lane]; c0 = cc.x; c1 = cc.y; }
  const float2* Wr = (const float2*)Ws;
  for(int node = wid; node < n; node += nw){
    float2 xv = ((const float2*)(A + (size_t)node*D))[lane];
    float a0 = c0, a1 = c1;
    #pragma unroll
    for(int k2 = 0; k2 < D2; k2++){
      float xa = bcast(xv.x, k2);
      float xb = bcast(xv.y, k2);
      float2 wa = Wr[(2*k2)*D2 + lane];
      float2 wb = Wr[(2*k2+1)*D2 + lane];
      a0 = fmaf(xa, wa.x, a0); a1 = fmaf(xa, wa.y, a1);
      a0 = fmaf(xb, wb.x, a0); a1 = fmaf(xb, wb.y, a1);
    }
    ((float2*)(out + (size_t)node*D))[lane] = make_float2(a0, a1);
  }
}

// ---------- aggregation: out = relu(Ahat@h + b); BN stat partials ----------
__global__ void __launch_bounds__(256)
k_agg(const float* __restrict__ h, const int* __restrict__ offsets,
      const int* __restrict__ csr, const float* __restrict__ dinv,
      const float* __restrict__ bias, float* __restrict__ out,
      float* __restrict__ psum, float* __restrict__ psq, int n){
  int lane = threadIdx.x & 63;
  int wid  = (blockIdx.x*blockDim.x + threadIdx.x) >> 6;
  int nw   = (gridDim.x*blockDim.x) >> 6;
  float2 bb = ((const float2*)bias)[lane];
  float cs0 = 0, cs1 = 0, cq0 = 0, cq1 = 0;
  for(int node = wid; node < n; node += nw){
    int off = offsets[node], end = offsets[node+1];
    float di = dinv[node];
    float2 hs = ((const float2*)(h + (size_t)node*D))[lane];
    float a0 = di*hs.x, a1 = di*hs.y;           // self loop: dinv_i^2 * h_i (di applied again below)
    for(int e = off; e < end; e++){
      int s = csr[e];
      float ds = dinv[s];
      float2 hv = ((const float2*)(h + (size_t)s*D))[lane];
      a0 = fmaf(ds, hv.x, a0); a1 = fmaf(ds, hv.y, a1);
    }
    float r0 = fmaxf(fmaf(di, a0, bb.x), 0.f);
    float r1 = fmaxf(fmaf(di, a1, bb.y), 0.f);
    ((float2*)(out + (size_t)node*D))[lane] = make_float2(r0, r1);
    cs0 += r0; cs1 += r1; cq0 += r0*r0; cq1 += r1*r1;
  }
  __shared__ float lcs[D], lcq[D];
  for(int i = threadIdx.x; i < D; i += blockDim.x){ lcs[i] = 0.f; lcq[i] = 0.f; }
  __syncthreads();
  atomicAdd(&lcs[2*lane],   cs0); atomicAdd(&lcs[2*lane+1], cs1);
  atomicAdd(&lcq[2*lane],   cq0); atomicAdd(&lcq[2*lane+1], cq1);
  __syncthreads();
  for(int i = threadIdx.x; i < D; i += blockDim.x){
    psum[(size_t)blockIdx.x*D + i] = lcs[i];
    psq [(size_t)blockIdx.x*D + i] = lcq[i];
  }
}

// ---------- BN params: one block per column ----------
__global__ void k_colreduce(const float* __restrict__ psum, const float* __restrict__ psq,
                            int nb, const float* __restrict__ g, const float* __restrict__ be,
                            float* scale, float* shift, int n){
  int c = blockIdx.x;
  float s = 0, q = 0;
  for(int b = threadIdx.x; b < nb; b += blockDim.x){
    s += psum[(size_t)b*D + c]; q += psq[(size_t)b*D + c];
  }
  for(int o = 32; o; o >>= 1){ s += __shfl_xor(s, o); q += __shfl_xor(q, o); }
  __shared__ float ls[4], lq[4];
  int wv = threadIdx.x >> 6;
  if((threadIdx.x & 63) == 0){ ls[wv] = s; lq[wv] = q; }
  __syncthreads();
  if(threadIdx.x == 0){
    float S = ls[0]+ls[1]+ls[2]+ls[3], Q = lq[0]+lq[1]+lq[2]+lq[3];
    float mean = S / n;
    float var  = fmaxf(Q / n - mean*mean, 0.f);   // biased, as torch BN training
    float sc   = g[c] * rsqrtf(var + 1e-5f);
    scale[c] = sc;
    shift[c] = fmaf(-mean, sc, be[c]);
  }
}

// fold BN into next W: Wmod[k][j] = scale[k]*W[k][j]; cconst[j] = sum_k shift[k]*W[k][j]
__global__ void k_fold(const float* __restrict__ W, const float* __restrict__ scale,
                       const float* __restrict__ shift, float* Wmod, float* cconst){
  int j = blockIdx.x, k = threadIdx.x;  // 128 blocks x 128 threads
  float w = W[k*D + j];
  Wmod[k*D + j] = scale[k] * w;
  float sm = shift[k] * w;
  for(int o = 32; o; o >>= 1) sm += __shfl_xor(sm, o);
  __shared__ float l2[2];
  if((k & 63) == 0) l2[k >> 6] = sm;
  __syncthreads();
  if(k == 0) cconst[j] = l2[0] + l2[1];
}

// ---------- semantic table: 32 types x {score, p0, p1} ----------
__global__ void k_sem(const float* __restrict__ emb, const float* __restrict__ Wa,
                      const float* __restrict__ ba, const float* __restrict__ Wf, float* sem){
  int t = threadIdx.x;
  if(t < 32){
    float s = ba[0], q0 = 0, q1 = 0;
    for(int c = 0; c < D; c++){
      float e = emb[t*D + c];
      s  = fmaf(e, Wa[c],     s);
      q0 = fmaf(e, Wf[2*c],   q0);
      q1 = fmaf(e, Wf[2*c+1], q1);
    }
    sem[t] = s; sem[32 + t] = q0; sem[64 + t] = q1;
  }
}

// ---------- spatial branch scores (applies BN3), also semantic max ----------
__global__ void __launch_bounds__(256)
k_spatial(const float* __restrict__ R, const float* __restrict__ scale,
          const float* __restrict__ shift, const float* __restrict__ Wa,
          const float* __restrict__ ba, const float* __restrict__ Wf,
          const int* __restrict__ tt, const float* __restrict__ sem,
          float* s_sp, float* p0_sp, float* p1_sp, unsigned* maxkey, int n){
  int lane = threadIdx.x & 63;
  int wid  = (blockIdx.x*blockDim.x + threadIdx.x) >> 6;
  int nw   = (gridDim.x*blockDim.x) >> 6;
  float2 sc = ((const float2*)scale)[lane];
  float2 sh = ((const float2*)shift)[lane];
  float2 wa = ((const float2*)Wa)[lane];
  float4 wf = ((const float4*)Wf)[lane];  // (Wf[2l][0],Wf[2l][1],Wf[2l+1][0],Wf[2l+1][1])
  float ba0 = ba[0];
  float mloc = -INFINITY, msem = -INFINITY;
  for(int node = wid; node < n; node += nw){
    float2 v = ((const float2*)(R + (size_t)node*D))[lane];
    float v0 = fmaf(v.x, sc.x, sh.x);
    float v1 = fmaf(v.y, sc.y, sh.y);
    float s  = v0*wa.x + v1*wa.y;
    float p0 = v0*wf.x + v1*wf.z;
    float p1 = v0*wf.y + v1*wf.w;
    for(int o = 32; o; o >>= 1){
      s += __shfl_xor(s, o); p0 += __shfl_xor(p0, o); p1 += __shfl_xor(p1, o);
    }
    s += ba0;
    if(lane == 0){ s_sp[node] = s; p0_sp[node] = p0; p1_sp[node] = p1; }
    mloc = fmaxf(mloc, s);
    msem = fmaxf(msem, sem[tt[node]]);
  }
  __shared__ float lm[4], lsm[4];
  int wv = threadIdx.x >> 6;
  if(lane == 0){ lm[wv] = mloc; lsm[wv] = msem; }
  __syncthreads();
  if(threadIdx.x == 0){
    float M  = fmaxf(fmaxf(lm[0], lm[1]),  fmaxf(lm[2], lm[3]));
    float M2 = fmaxf(fmaxf(lsm[0], lsm[1]), fmaxf(lsm[2], lsm[3]));
    atomicMax(&maxkey[0], fkey(M));
    atomicMax(&maxkey[2], fkey(M2));
  }
}

// ---------- temporal branch: relu([x,td]@Wt+bt) folded to scores ----------
__global__ void __launch_bounds__(256)
k_temporal(const float* __restrict__ x, const float* __restrict__ td,
           const float* __restrict__ Wt, const float* __restrict__ bt,
           const float* __restrict__ Wa, const float* __restrict__ ba,
           const float* __restrict__ Wf,
           float* s_te, float* p0_te, float* p1_te, unsigned* maxkey, int n){
  __shared__ float Ws[D*D];
  {
    const float4* W4 = (const float4*)Wt;   // rows 0..127
    float4* Ws4 = (float4*)Ws;
    for(int i = threadIdx.x; i < D*D/4; i += blockDim.x) Ws4[i] = W4[i];
  }
  __syncthreads();
  int lane = threadIdx.x & 63;
  int wid  = (blockIdx.x*blockDim.x + threadIdx.x) >> 6;
  int nw   = (gridDim.x*blockDim.x) >> 6;
  float2 wl = ((const float2*)(Wt + D*D))[lane]; // row 128 (td column)
  float2 bb = ((const float2*)bt)[lane];
  float2 wa = ((const float2*)Wa)[lane];
  float4 wf = ((const float4*)Wf)[lane];
  float ba0 = ba[0];
  const float2* Wr = (const float2*)Ws;
  float mloc = -INFINITY;
  for(int node = wid; node < n; node += nw){
    float2 xv = ((const float2*)(x + (size_t)node*D))[lane];
    float tdv = td[node];
    float a0 = fmaf(tdv, wl.x, bb.x);
    float a1 = fmaf(tdv, wl.y, bb.y);
    #pragma unroll
    for(int k2 = 0; k2 < D2; k2++){
      float xa = bcast(xv.x, k2);
      float xb = bcast(xv.y, k2);
      float2 w0 = Wr[(2*k2)*D2 + lane];
      float2 w1 = Wr[(2*k2+1)*D2 + lane];
      a0 = fmaf(xa, w0.x, a0); a1 = fmaf(xa, w0.y, a1);
      a0 = fmaf(xb, w1.x, a0); a1 = fmaf(xb, w1.y, a1);
    }
    float t0 = fmaxf(a0, 0.f), t1 = fmaxf(a1, 0.f);
    float s  = t0*wa.x + t1*wa.y;
    float p0 = t0*wf.x + t1*wf.z;
    float p1 = t0*wf.y + t1*wf.w;
    for(int o = 32; o; o >>= 1){
      s += __shfl_xor(s, o); p0 += __shfl_xor(p0, o); p1 += __shfl_xor(p1, o);
    }
    s += ba0;
    if(lane == 0){ s_te[node] = s; p0_te[node] = p0; p1_te[node] = p1; }
    mloc = fmaxf(mloc, s);
  }
  __syncthreads();                 // safe to reuse Ws for the block max
  int wv = threadIdx.x >> 6;
  if(lane == 0) Ws[wv] = mloc;
  __syncthreads();
  if(threadIdx.x == 0){
    float M = fmaxf(fmaxf(Ws[0], Ws[1]), fmaxf(Ws[2], Ws[3]));
    atomicMax(&maxkey[1], fkey(M));
  }
}

// ---------- softmax denominators ----------
__global__ void k_zsum(const float* __restrict__ s_sp, const float* __restrict__ s_te,
                       const int* __restrict__ tt, const float* __restrict__ sem,
                       Scal* sc, int n){
  float M0 = fdec(sc->maxkey[0]), M1 = fdec(sc->maxkey[1]), M2 = fdec(sc->maxkey[2]);
  int i = blockIdx.x*blockDim.x + threadIdx.x;
  int stride = gridDim.x*blockDim.x;
  float z0 = 0, z1 = 0, z2 = 0;
  for(; i < n; i += stride){
    z0 += expf(s_sp[i] - M0);
    z1 += expf(s_te[i] - M1);
    z2 += expf(sem[tt[i]] - M2);
  }
  for(int o = 32; o; o >>= 1){
    z0 += __shfl_xor(z0, o); z1 += __shfl_xor(z1, o); z2 += __shfl_xor(z2, o);
  }
  __shared__ float l0[4], l1[4], l2[4];
  int wv = threadIdx.x >> 6;
  if((threadIdx.x & 63) == 0){ l0[wv] = z0; l1[wv] = z1; l2[wv] = z2; }
  __syncthreads();
  if(threadIdx.x == 0){
    atomAddF(&sc->Z[0], l0[0]+l0[1]+l0[2]+l0[3]);
    atomAddF(&sc->Z[1], l1[0]+l1[1]+l1[2]+l1[3]);
    atomAddF(&sc->Z[2], l2[0]+l2[1]+l2[2]+l2[3]);
  }
}

// ---------- final combine ----------
__global__ void k_final(const float* __restrict__ s_sp, const float* __restrict__ p0_sp,
                        const float* __restrict__ p1_sp, const float* __restrict__ s_te,
                        const float* __restrict__ p0_te, const float* __restrict__ p1_te,
                        const int* __restrict__ tt, const float* __restrict__ sem,
                        const Scal* sc, const float* __restrict__ bf,
                        float* __restrict__ out, int n){
  int i = blockIdx.x*blockDim.x + threadIdx.x;
  if(i < n){
    float M0 = fdec(sc->maxkey[0]), M1 = fdec(sc->maxkey[1]), M2 = fdec(sc->maxkey[2]);
    float w0 = expf(s_sp[i] - M0) / sc->Z[0];
    float w1 = expf(s_te[i] - M1) / sc->Z[1];
    int t = tt[i];
    float w2 = expf(sem[t] - M2) / sc->Z[2];
    float o0 = w0*p0_sp[i] + w1*p0_te[i] + w2*sem[32 + t] + bf[0];
    float o1 = w0*p1_sp[i] + w1*p1_te[i] + w2*sem[64 + t] + bf[1];
    ((float2*)out)[i] = make_float2(o0, o1);
  }
}

extern "C" void kernel_launch(void* const* d_in, const int* in_sizes, int n_in,
                              void* d_out, int out_size, void* d_ws, size_t ws_size,
                              hipStream_t stream) {
  const int N = in_sizes[5];   // timestamps
  const int E = in_sizes[1];   // src

  const float* x   = (const float*)d_in[0];
  const int*   src = (const int*)  d_in[1];
  const int*   dst = (const int*)  d_in[2];
  const float* ea  = (const float*)d_in[3];
  const int*   tt  = (const int*)  d_in[4];
  const float* W1  = (const float*)d_in[6];  const float* b1 = (const float*)d_in[7];
  const float* W2  = (const float*)d_in[8];  const float* b2 = (const float*)d_in[9];
  const float* W3  = (const float*)d_in[10]; const float* b3 = (const float*)d_in[11];
  const float* Wt  = (const float*)d_in[12]; const float* bt = (const float*)d_in[13];
  const float* emb = (const float*)d_in[14];
  const float* Wa  = (const float*)d_in[15]; const float* ba = (const float*)d_in[16];
  const float* g1  = (const float*)d_in[17]; const float* be1= (const float*)d_in[18];
  const float* g2  = (const float*)d_in[19]; const float* be2= (const float*)d_in[20];
  const float* g3  = (const float*)d_in[21]; const float* be3= (const float*)d_in[22];
  const float* Wf  = (const float*)d_in[23]; const float* bf = (const float*)d_in[24];
  float* out = (float*)d_out;

  char* w = (char*)d_ws;
  size_t off = 0;
  auto take = [&](size_t bytes) -> char* {
    char* p = w + off;
    off = (off + bytes + 255) & ~(size_t)255;
    return p;
  };

  const int NB_AGG = 2048, NB_GEMM = 2048, NB_SP = 2048, NB_Z = 1024, NB_E = 2048;

  float* bufA    = (float*)take((size_t)N*D*4);
  float* bufB    = (float*)take((size_t)N*D*4);
  int*   csr     = (int*)  take((size_t)E*4);
  int*   offsets = (int*)  take((size_t)(N+1)*4);
  float* dinv    = (float*)take((size_t)N*4);
  float* s_sp    = (float*)take((size_t)N*4);
  float* p0_sp   = (float*)take((size_t)N*4);
  float* p1_sp   = (float*)take((size_t)N*4);
  float* s_te    = (float*)take((size_t)N*4);
  float* p0_te   = (float*)take((size_t)N*4);
  float* p1_te   = (float*)take((size_t)N*4);
  float* psum    = (float*)take((size_t)NB_AGG*D*4);
  float* psq     = (float*)take((size_t)NB_AGG*D*4);
  float* Wmod    = (float*)take((size_t)D*D*4);
  float* cconst  = (float*)take((size_t)D*4);
  float* scaleb  = (float*)take((size_t)D*4);
  float* shiftb  = (float*)take((size_t)D*4);
  float* sem     = (float*)take((size_t)96*4);
  // --- zero-init region (contiguous) ---
  Scal* sc     = (Scal*)take(sizeof(Scal));
  int*  indeg  = (int*) take((size_t)N*4);
  int*  outdeg = (int*) take((size_t)N*4);
  int*  cursor = (int*) take((size_t)N*4);
  float* td    = (float*)take((size_t)N*4);
  size_t zbytes = (size_t)((w + off) - (char*)sc);
  hipMemsetAsync(sc, 0, zbytes, stream);

  int gE = (E + 255) / 256;
  int gN = (N + 255) / 256;

  // graph prep
  k_hist<<<gE, 256, 0, stream>>>(src, dst, indeg, outdeg, E);
  k_scan<<<1, 1024, 0, stream>>>(indeg, offsets, N);
  k_dinv<<<gN, 256, 0, stream>>>(indeg, dinv, N);
  k_fill<<<gE, 256, 0, stream>>>(src, dst, offsets, cursor, csr, E);

  // time diffs
  k_estats<<<NB_E, 256, 0, stream>>>(ea, E, sc);
  k_efin<<<1, 1, 0, stream>>>(sc, E);
  k_td<<<gE, 256, 0, stream>>>(ea, src, dst, sc, td, E);
  k_tdfin<<<gN, 256, 0, stream>>>(td, indeg, outdeg, N);

  // layer 1
  k_gemm<<<NB_GEMM, 256, 0, stream>>>(x, W1, nullptr, bufA, N);
  k_agg<<<NB_AGG, 256, 0, stream>>>(bufA, offsets, csr, dinv, b1, bufB, psum, psq, N);
  k_colreduce<<<D, 256, 0, stream>>>(psum, psq, NB_AGG, g1, be1, scaleb, shiftb, N);
  k_fold<<<D, D, 0, stream>>>(W2, scaleb, shiftb, Wmod, cconst);
  // layer 2
  k_gemm<<<NB_GEMM, 256, 0, stream>>>(bufB, Wmod, cconst, bufA, N);
  k_agg<<<NB_AGG, 256, 0, stream>>>(bufA, offsets, csr, dinv, b2, bufB, psum, psq, N);
  k_colreduce<<<D, 256, 0, stream>>>(psum, psq, NB_AGG, g2, be2, scaleb, shiftb, N);
  k_fold<<<D, D, 0, stream>>>(W3, scaleb, shiftb, Wmod, cconst);
  // layer 3
  k_gemm<<<NB_GEMM, 256, 0, stream>>>(bufB, Wmod, cconst, bufA, N);
  k_agg<<<NB_AGG, 256, 0, stream>>>(bufA, offsets, csr, dinv, b3, bufB, psum, psq, N);
  k_colreduce<<<D, 256, 0, stream>>>(psum, psq, NB_AGG, g3, be3, scaleb, shiftb, N);

  // branches
  k_sem<<<1, 64, 0, stream>>>(emb, Wa, ba, Wf, sem);
  k_spatial<<<NB_SP, 256, 0, stream>>>(bufB, scaleb, shiftb, Wa, ba, Wf, tt, sem,
                                       s_sp, p0_sp, p1_sp, sc->maxkey, N);
  k_temporal<<<NB_GEMM, 256, 0, stream>>>(x, td, Wt, bt, Wa, ba, Wf,
                                          s_te, p0_te, p1_te, sc->maxkey, N);
  // softmax + combine
  k_zsum<<<NB_Z, 256, 0, stream>>>(s_sp, s_te, tt, sem, sc, N);
  k_final<<<gN, 256, 0, stream>>>(s_sp, p0_sp, p1_sp, s_te, p0_te, p1_te,
                                  tt, sem, sc, bf, out, N);
}

// Round 2
// 1562.080 us; speedup vs baseline: 1.5157x; 1.5157x over previous
//
#include <hip/hip_runtime.h>
#include <math.h>

#define D   128
#define WAVE 64

// GEMM tiling
#define BN  128   // nodes per block
#define KP  32    // K panel
#define TN  8     // nodes per thread
#define TJ  8     // outputs per thread
#define XSTR (BN + 4)  // padded xs row stride (132 floats, 16B-aligned)

struct Scal {
  double esum, esumsq;     // zero-init
  unsigned maxkey[3];      // zero-init (decodes below all finite)
  float Z[3];              // zero-init
  float emean, einv;       // written by k_efin
};

__device__ __forceinline__ unsigned fkey(float f){
  unsigned b = __float_as_uint(f);
  return (b & 0x80000000u) ? ~b : (b | 0x80000000u);
}
__device__ __forceinline__ float fdec(unsigned k){
  return (k & 0x80000000u) ? __uint_as_float(k & 0x7fffffffu) : __uint_as_float(~k);
}
__device__ __forceinline__ void atomAddF(float* p, float v){
  __hip_atomic_fetch_add(p, v, __ATOMIC_RELAXED, __HIP_MEMORY_SCOPE_AGENT);
}
__device__ __forceinline__ void atomAddD(double* p, double v){
  __hip_atomic_fetch_add(p, v, __ATOMIC_RELAXED, __HIP_MEMORY_SCOPE_AGENT);
}

// ---------- graph prep ----------
__global__ void k_hist(const int* __restrict__ src, const int* __restrict__ dst,
                       int* indeg, int* outdeg, int E){
  int e = blockIdx.x*blockDim.x + threadIdx.x;
  if(e < E){ atomicAdd(&indeg[dst[e]], 1); atomicAdd(&outdeg[src[e]], 1); }
}

__global__ void k_scan(const int* __restrict__ indeg, int* __restrict__ offsets, int n){
  __shared__ int part[1024];
  int t = threadIdx.x;
  int chunk = (n + 1023) / 1024;
  int base = t * chunk;
  int s = 0;
  for(int i = 0; i < chunk; i++){ int idx = base + i; if(idx < n) s += indeg[idx]; }
  part[t] = s; __syncthreads();
  for(int o = 1; o < 1024; o <<= 1){
    int v = (t >= o) ? part[t-o] : 0;
    __syncthreads();
    part[t] += v;
    __syncthreads();
  }
  int run = (t == 0) ? 0 : part[t-1];
  for(int i = 0; i < chunk; i++){
    int idx = base + i;
    if(idx < n){ offsets[idx] = run; run += indeg[idx]; }
  }
  if(t == 1023) offsets[n] = run;
}

__global__ void k_dinv(const int* __restrict__ indeg, float* __restrict__ dinv, int n){
  int i = blockIdx.x*blockDim.x + threadIdx.x;
  if(i < n) dinv[i] = rsqrtf((float)(indeg[i] + 1));
}

__global__ void k_fill(const int* __restrict__ src, const int* __restrict__ dst,
                       const int* __restrict__ offsets, int* cursor, int* csr, int E){
  int e = blockIdx.x*blockDim.x + threadIdx.x;
  if(e < E){
    int d = dst[e];
    int pos = atomicAdd(&cursor[d], 1);
    csr[offsets[d] + pos] = src[e];
  }
}

// ---------- edge standardization / time diffs ----------
__global__ void k_estats(const float* __restrict__ ea, int E, Scal* sc){
  int i = blockIdx.x*blockDim.x + threadIdx.x;
  int stride = gridDim.x*blockDim.x;
  double s = 0.0, q = 0.0;
  for(; i < E; i += stride){
    float v = fminf(fmaxf(ea[i], -1000.f), 1000.f);
    s += (double)v; q += (double)v * (double)v;
  }
  for(int o = 32; o; o >>= 1){ s += __shfl_xor(s, o); q += __shfl_xor(q, o); }
  __shared__ double ls[4], lq[4];
  int wv = threadIdx.x >> 6;
  if((threadIdx.x & 63) == 0){ ls[wv] = s; lq[wv] = q; }
  __syncthreads();
  if(threadIdx.x == 0){
    double S = ls[0]+ls[1]+ls[2]+ls[3], Q = lq[0]+lq[1]+lq[2]+lq[3];
    atomAddD(&sc->esum, S); atomAddD(&sc->esumsq, Q);
  }
}

__global__ void k_efin(Scal* sc, int E){
  double mean = sc->esum / E;
  double var  = (sc->esumsq - sc->esum*sc->esum/E) / (double)(E - 1);
  double sd   = sqrt(var > 0.0 ? var : 0.0);
  sc->emean = (float)mean;
  sc->einv  = (float)(1.0 / (sd + 1e-9));
}

__global__ void k_td(const float* __restrict__ ea, const int* __restrict__ src,
                     const int* __restrict__ dst, const Scal* sc, float* td, int E){
  int e = blockIdx.x*blockDim.x + threadIdx.x;
  if(e < E){
    float v  = fminf(fmaxf(ea[e], -1000.f), 1000.f);
    float en = (v - sc->emean) * sc->einv;
    atomAddF(&td[src[e]], en);
    atomAddF(&td[dst[e]], en);
  }
}

__global__ void k_tdfin(float* td, const int* __restrict__ indeg,
                        const int* __restrict__ outdeg, int n){
  int i = blockIdx.x*blockDim.x + threadIdx.x;
  if(i < n) td[i] /= fmaxf((float)(indeg[i] + outdeg[i]), 1.f);
}

// ---------- register-tiled GEMM: out[node,:] = dinv[node]*(A[node,:]@W + cvec) ----------
// block = 256 threads, tile 128 nodes x 128 outputs, K panels of 32.
__global__ void __launch_bounds__(256)
k_gemm(const float* __restrict__ A, const float* __restrict__ W,
       const float* __restrict__ cvec, const float* __restrict__ dinv,
       float* __restrict__ out, int n){
  __shared__ float xs[KP][XSTR];   // x panel, transposed
  __shared__ float ws[KP][D];      // W panel
  const int t  = threadIdx.x;
  const int jg = t & 15, ng = t >> 4;
  const int j0 = jg * TJ, n0 = ng * TN;
  const int nodeBase = blockIdx.x * BN;

  float cr[TJ];
  if(cvec){
    float4 c0 = *(const float4*)(cvec + j0);
    float4 c1 = *(const float4*)(cvec + j0 + 4);
    cr[0]=c0.x; cr[1]=c0.y; cr[2]=c0.z; cr[3]=c0.w;
    cr[4]=c1.x; cr[5]=c1.y; cr[6]=c1.z; cr[7]=c1.w;
  } else {
    #pragma unroll
    for(int j=0;j<TJ;j++) cr[j]=0.f;
  }
  float acc[TN][TJ];
  #pragma unroll
  for(int i=0;i<TN;i++)
    #pragma unroll
    for(int j=0;j<TJ;j++) acc[i][j]=cr[j];

  for(int p=0;p<D/KP;p++){
    // stage W panel (rows p*32 .. p*32+31 are contiguous)
    {
      const float4* Wp = (const float4*)(W + (size_t)p*KP*D);
      float4* ws4 = (float4*)ws;
      ws4[t]       = Wp[t];
      ws4[t + 256] = Wp[t + 256];
      ws4[t + 512] = Wp[t + 512];
      ws4[t + 768] = Wp[t + 768];
    }
    // stage x panel transposed
    #pragma unroll
    for(int q=0;q<4;q++){
      int idx = t + q*256;               // 0..1023
      int node = idx >> 3, kq = idx & 7;
      int gn = nodeBase + node; if(gn >= n) gn = n-1;
      float4 v = *(const float4*)(A + (size_t)gn*D + p*KP + kq*4);
      xs[kq*4+0][node] = v.x; xs[kq*4+1][node] = v.y;
      xs[kq*4+2][node] = v.z; xs[kq*4+3][node] = v.w;
    }
    __syncthreads();
    #pragma unroll 4
    for(int k=0;k<KP;k++){
      float4 xa = *(const float4*)&xs[k][n0];
      float4 xb = *(const float4*)&xs[k][n0+4];
      float4 wa = *(const float4*)&ws[k][j0];
      float4 wb = *(const float4*)&ws[k][j0+4];
      float xv[8] = {xa.x,xa.y,xa.z,xa.w,xb.x,xb.y,xb.z,xb.w};
      float wv[8] = {wa.x,wa.y,wa.z,wa.w,wb.x,wb.y,wb.z,wb.w};
      #pragma unroll
      for(int i=0;i<TN;i++)
        #pragma unroll
        for(int j=0;j<TJ;j++)
          acc[i][j] = fmaf(xv[i], wv[j], acc[i][j]);
    }
    __syncthreads();
  }
  // epilogue: scale by dinv, store
  #pragma unroll
  for(int i=0;i<TN;i++){
    int gn = nodeBase + n0 + i;
    if(gn < n){
      float d = dinv[gn];
      float4 o0 = make_float4(acc[i][0]*d, acc[i][1]*d, acc[i][2]*d, acc[i][3]*d);
      float4 o1 = make_float4(acc[i][4]*d, acc[i][5]*d, acc[i][6]*d, acc[i][7]*d);
      *(float4*)(out + (size_t)gn*D + j0)     = o0;
      *(float4*)(out + (size_t)gn*D + j0 + 4) = o1;
    }
  }
}

// ---------- temporal branch: register-tiled GEMM + fused score epilogue ----------
__global__ void __launch_bounds__(256)
k_temporal(const float* __restrict__ x, const float* __restrict__ td,
           const float* __restrict__ Wt, const float* __restrict__ bt,
           const float* __restrict__ Wa, const float* __restrict__ ba,
           const float* __restrict__ Wf,
           float* s_te, float* p0_te, float* p1_te, unsigned* maxkey, int n){
  __shared__ float xs[KP][XSTR];
  __shared__ float ws[KP][D];
  __shared__ unsigned mk;
  const int t  = threadIdx.x;
  const int jg = t & 15, ng = t >> 4;
  const int j0 = jg * TJ, n0 = ng * TN;
  const int nodeBase = blockIdx.x * BN;
  if(t == 0) mk = 0;

  float acc[TN][TJ];
  #pragma unroll
  for(int i=0;i<TN;i++)
    #pragma unroll
    for(int j=0;j<TJ;j++) acc[i][j]=0.f;

  for(int p=0;p<D/KP;p++){
    {
      const float4* Wp = (const float4*)(Wt + (size_t)p*KP*D);
      float4* ws4 = (float4*)ws;
      ws4[t]       = Wp[t];
      ws4[t + 256] = Wp[t + 256];
      ws4[t + 512] = Wp[t + 512];
      ws4[t + 768] = Wp[t + 768];
    }
    #pragma unroll
    for(int q=0;q<4;q++){
      int idx = t + q*256;
      int node = idx >> 3, kq = idx & 7;
      int gn = nodeBase + node; if(gn >= n) gn = n-1;
      float4 v = *(const float4*)(x + (size_t)gn*D + p*KP + kq*4);
      xs[kq*4+0][node] = v.x; xs[kq*4+1][node] = v.y;
      xs[kq*4+2][node] = v.z; xs[kq*4+3][node] = v.w;
    }
    __syncthreads();
    #pragma unroll 4
    for(int k=0;k<KP;k++){
      float4 xa = *(const float4*)&xs[k][n0];
      float4 xb = *(const float4*)&xs[k][n0+4];
      float4 wa = *(const float4*)&ws[k][j0];
      float4 wb = *(const float4*)&ws[k][j0+4];
      float xv[8] = {xa.x,xa.y,xa.z,xa.w,xb.x,xb.y,xb.z,xb.w};
      float wv[8] = {wa.x,wa.y,wa.z,wa.w,wb.x,wb.y,wb.z,wb.w};
      #pragma unroll
      for(int i=0;i<TN;i++)
        #pragma unroll
        for(int j=0;j<TJ;j++)
          acc[i][j] = fmaf(xv[i], wv[j], acc[i][j]);
    }
    __syncthreads();
  }
  // epilogue constants for this thread's 8 output columns
  float wl[TJ], bb[TJ], wa8[TJ], wf0[TJ], wf1[TJ];
  #pragma unroll
  for(int j=0;j<TJ;j++){
    wl[j]  = Wt[(size_t)D*D + j0 + j];   // td row (row 128)
    bb[j]  = bt[j0 + j];
    wa8[j] = Wa[j0 + j];
    float2 w2 = ((const float2*)Wf)[j0 + j];
    wf0[j] = w2.x; wf1[j] = w2.y;
  }
  float ba0 = ba[0];
  float mloc = -INFINITY;
  #pragma unroll
  for(int i=0;i<TN;i++){
    int gn = nodeBase + n0 + i;
    float tdv = (gn < n) ? td[gn] : 0.f;
    float s = 0.f, p0 = 0.f, p1 = 0.f;
    #pragma unroll
    for(int j=0;j<TJ;j++){
      float tj = fmaxf(acc[i][j] + tdv*wl[j] + bb[j], 0.f);
      s  = fmaf(tj, wa8[j], s);
      p0 = fmaf(tj, wf0[j], p0);
      p1 = fmaf(tj, wf1[j], p1);
    }
    #pragma unroll
    for(int o=8;o;o>>=1){
      s += __shfl_xor(s, o); p0 += __shfl_xor(p0, o); p1 += __shfl_xor(p1, o);
    }
    if(jg == 0 && gn < n){
      s += ba0;
      s_te[gn] = s; p0_te[gn] = p0; p1_te[gn] = p1;
      mloc = fmaxf(mloc, s);
    }
  }
  __syncthreads();
  if(jg == 0) atomicMax(&mk, fkey(mloc));
  __syncthreads();
  if(t == 0) atomicMax(&maxkey[1], mk);
}

// ---------- aggregation: h rows are pre-scaled by dinv[src] ----------
__global__ void __launch_bounds__(256)
k_agg(const float* __restrict__ h, const int* __restrict__ offsets,
      const int* __restrict__ csr, const float* __restrict__ dinv,
      const float* __restrict__ bias, float* __restrict__ out,
      float* __restrict__ psum, float* __restrict__ psq, int n){
  int lane = threadIdx.x & 63;
  int wid  = (blockIdx.x*blockDim.x + threadIdx.x) >> 6;
  int nw   = (gridDim.x*blockDim.x) >> 6;
  float2 bb = ((const float2*)bias)[lane];
  float cs0 = 0, cs1 = 0, cq0 = 0, cq1 = 0;
  for(int node = wid; node < n; node += nw){
    int off = offsets[node], end = offsets[node+1];
    float di = dinv[node];
    float2 hs = ((const float2*)(h + (size_t)node*D))[lane];
    float a0 = hs.x, a1 = hs.y;       // self loop (h already has dinv folded)
    float b0 = 0.f, b1v = 0.f;
    int e = off;
    for(; e + 1 < end; e += 2){
      int s1 = csr[e], s2 = csr[e+1];
      float2 h1 = ((const float2*)(h + (size_t)s1*D))[lane];
      float2 h2 = ((const float2*)(h + (size_t)s2*D))[lane];
      a0 += h1.x; a1 += h1.y; b0 += h2.x; b1v += h2.y;
    }
    if(e < end){
      int s1 = csr[e];
      float2 h1 = ((const float2*)(h + (size_t)s1*D))[lane];
      a0 += h1.x; a1 += h1.y;
    }
    float r0 = fmaxf(fmaf(di, a0 + b0,  bb.x), 0.f);
    float r1 = fmaxf(fmaf(di, a1 + b1v, bb.y), 0.f);
    ((float2*)(out + (size_t)node*D))[lane] = make_float2(r0, r1);
    cs0 += r0; cs1 += r1; cq0 += r0*r0; cq1 += r1*r1;
  }
  __shared__ float lcs[D], lcq[D];
  for(int i = threadIdx.x; i < D; i += blockDim.x){ lcs[i] = 0.f; lcq[i] = 0.f; }
  __syncthreads();
  atomicAdd(&lcs[2*lane],   cs0); atomicAdd(&lcs[2*lane+1], cs1);
  atomicAdd(&lcq[2*lane],   cq0); atomicAdd(&lcq[2*lane+1], cq1);
  __syncthreads();
  for(int i = threadIdx.x; i < D; i += blockDim.x){
    psum[(size_t)blockIdx.x*D + i] = lcs[i];
    psq [(size_t)blockIdx.x*D + i] = lcq[i];
  }
}

// ---------- BN params ----------
__global__ void k_colreduce(const float* __restrict__ psum, const float* __restrict__ psq,
                            int nb, const float* __restrict__ g, const float* __restrict__ be,
                            float* scale, float* shift, int n){
  int c = blockIdx.x;
  float s = 0, q = 0;
  for(int b = threadIdx.x; b < nb; b += blockDim.x){
    s += psum[(size_t)b*D + c]; q += psq[(size_t)b*D + c];
  }
  for(int o = 32; o; o >>= 1){ s += __shfl_xor(s, o); q += __shfl_xor(q, o); }
  __shared__ float ls[4], lq[4];
  int wv = threadIdx.x >> 6;
  if((threadIdx.x & 63) == 0){ ls[wv] = s; lq[wv] = q; }
  __syncthreads();
  if(threadIdx.x == 0){
    float S = ls[0]+ls[1]+ls[2]+ls[3], Q = lq[0]+lq[1]+lq[2]+lq[3];
    float mean = S / n;
    float var  = fmaxf(Q / n - mean*mean, 0.f);
    float sc   = g[c] * rsqrtf(var + 1e-5f);
    scale[c] = sc;
    shift[c] = fmaf(-mean, sc, be[c]);
  }
}

__global__ void k_fold(const float* __restrict__ W, const float* __restrict__ scale,
                       const float* __restrict__ shift, float* Wmod, float* cconst){
  int j = blockIdx.x, k = threadIdx.x;
  float w = W[k*D + j];
  Wmod[k*D + j] = scale[k] * w;
  float sm = shift[k] * w;
  for(int o = 32; o; o >>= 1) sm += __shfl_xor(sm, o);
  __shared__ float l2[2];
  if((k & 63) == 0) l2[k >> 6] = sm;
  __syncthreads();
  if(k == 0) cconst[j] = l2[0] + l2[1];
}

// ---------- semantic table ----------
__global__ void k_sem(const float* __restrict__ emb, const float* __restrict__ Wa,
                      const float* __restrict__ ba, const float* __restrict__ Wf, float* sem){
  int t = threadIdx.x;
  if(t < 32){
    float s = ba[0], q0 = 0, q1 = 0;
    for(int c = 0; c < D; c++){
      float e = emb[t*D + c];
      s  = fmaf(e, Wa[c],     s);
      q0 = fmaf(e, Wf[2*c],   q0);
      q1 = fmaf(e, Wf[2*c+1], q1);
    }
    sem[t] = s; sem[32 + t] = q0; sem[64 + t] = q1;
  }
}

// ---------- spatial branch scores ----------
__global__ void __launch_bounds__(256)
k_spatial(const float* __restrict__ R, const float* __restrict__ scale,
          const float* __restrict__ shift, const float* __restrict__ Wa,
          const float* __restrict__ ba, const float* __restrict__ Wf,
          const int* __restrict__ tt, const float* __restrict__ sem,
          float* s_sp, float* p0_sp, float* p1_sp, unsigned* maxkey, int n){
  int lane = threadIdx.x & 63;
  int wid  = (blockIdx.x*blockDim.x + threadIdx.x) >> 6;
  int nw   = (gridDim.x*blockDim.x) >> 6;
  float2 sc = ((const float2*)scale)[lane];
  float2 sh = ((const float2*)shift)[lane];
  float2 wa = ((const float2*)Wa)[lane];
  float4 wf = ((const float4*)Wf)[lane];
  float ba0 = ba[0];
  float mloc = -INFINITY, msem = -INFINITY;
  for(int node = wid; node < n; node += nw){
    float2 v = ((const float2*)(R + (size_t)node*D))[lane];
    float v0 = fmaf(v.x, sc.x, sh.x);
    float v1 = fmaf(v.y, sc.y, sh.y);
    float s  = v0*wa.x + v1*wa.y;
    float p0 = v0*wf.x + v1*wf.z;
    float p1 = v0*wf.y + v1*wf.w;
    for(int o = 32; o; o >>= 1){
      s += __shfl_xor(s, o); p0 += __shfl_xor(p0, o); p1 += __shfl_xor(p1, o);
    }
    s += ba0;
    if(lane == 0){ s_sp[node] = s; p0_sp[node] = p0; p1_sp[node] = p1; }
    mloc = fmaxf(mloc, s);
    msem = fmaxf(msem, sem[tt[node]]);
  }
  __shared__ float lm[4], lsm[4];
  int wv = threadIdx.x >> 6;
  if(lane == 0){ lm[wv] = mloc; lsm[wv] = msem; }
  __syncthreads();
  if(threadIdx.x == 0){
    float M  = fmaxf(fmaxf(lm[0], lm[1]),  fmaxf(lm[2], lm[3]));
    float M2 = fmaxf(fmaxf(lsm[0], lsm[1]), fmaxf(lsm[2], lsm[3]));
    atomicMax(&maxkey[0], fkey(M));
    atomicMax(&maxkey[2], fkey(M2));
  }
}

// ---------- softmax denominators ----------
__global__ void k_zsum(const float* __restrict__ s_sp, const float* __restrict__ s_te,
                       const int* __restrict__ tt, const float* __restrict__ sem,
                       Scal* sc, int n){
  float M0 = fdec(sc->maxkey[0]), M1 = fdec(sc->maxkey[1]), M2 = fdec(sc->maxkey[2]);
  int i = blockIdx.x*blockDim.x + threadIdx.x;
  int stride = gridDim.x*blockDim.x;
  float z0 = 0, z1 = 0, z2 = 0;
  for(; i < n; i += stride){
    z0 += expf(s_sp[i] - M0);
    z1 += expf(s_te[i] - M1);
    z2 += expf(sem[tt[i]] - M2);
  }
  for(int o = 32; o; o >>= 1){
    z0 += __shfl_xor(z0, o); z1 += __shfl_xor(z1, o); z2 += __shfl_xor(z2, o);
  }
  __shared__ float l0[4], l1[4], l2[4];
  int wv = threadIdx.x >> 6;
  if((threadIdx.x & 63) == 0){ l0[wv] = z0; l1[wv] = z1; l2[wv] = z2; }
  __syncthreads();
  if(threadIdx.x == 0){
    atomAddF(&sc->Z[0], l0[0]+l0[1]+l0[2]+l0[3]);
    atomAddF(&sc->Z[1], l1[0]+l1[1]+l1[2]+l1[3]);
    atomAddF(&sc->Z[2], l2[0]+l2[1]+l2[2]+l2[3]);
  }
}

// ---------- final combine ----------
__global__ void k_final(const float* __restrict__ s_sp, const float* __restrict__ p0_sp,
                        const float* __restrict__ p1_sp, const float* __restrict__ s_te,
                        const float* __restrict__ p0_te, const float* __restrict__ p1_te,
                        const int* __restrict__ tt, const float* __restrict__ sem,
                        const Scal* sc, const float* __restrict__ bf,
                        float* __restrict__ out, int n){
  int i = blockIdx.x*blockDim.x + threadIdx.x;
  if(i < n){
    float M0 = fdec(sc->maxkey[0]), M1 = fdec(sc->maxkey[1]), M2 = fdec(sc->maxkey[2]);
    float w0 = expf(s_sp[i] - M0) / sc->Z[0];
    float w1 = expf(s_te[i] - M1) / sc->Z[1];
    int t = tt[i];
    float w2 = expf(sem[t] - M2) / sc->Z[2];
    float o0 = w0*p0_sp[i] + w1*p0_te[i] + w2*sem[32 + t] + bf[0];
    float o1 = w0*p1_sp[i] + w1*p1_te[i] + w2*sem[64 + t] + bf[1];
    ((float2*)out)[i] = make_float2(o0, o1);
  }
}

extern "C" void kernel_launch(void* const* d_in, const int* in_sizes, int n_in,
                              void* d_out, int out_size, void* d_ws, size_t ws_size,
                              hipStream_t stream) {
  const int N = in_sizes[5];   // timestamps
  const int E = in_sizes[1];   // src

  const float* x   = (const float*)d_in[0];
  const int*   src = (const int*)  d_in[1];
  const int*   dst = (const int*)  d_in[2];
  const float* ea  = (const float*)d_in[3];
  const int*   tt  = (const int*)  d_in[4];
  const float* W1  = (const float*)d_in[6];  const float* b1 = (const float*)d_in[7];
  const float* W2  = (const float*)d_in[8];  const float* b2 = (const float*)d_in[9];
  const float* W3  = (const float*)d_in[10]; const float* b3 = (const float*)d_in[11];
  const float* Wt  = (const float*)d_in[12]; const float* bt = (const float*)d_in[13];
  const float* emb = (const float*)d_in[14];
  const float* Wa  = (const float*)d_in[15]; const float* ba = (const float*)d_in[16];
  const float* g1  = (const float*)d_in[17]; const float* be1= (const float*)d_in[18];
  const float* g2  = (const float*)d_in[19]; const float* be2= (const float*)d_in[20];
  const float* g3  = (const float*)d_in[21]; const float* be3= (const float*)d_in[22];
  const float* Wf  = (const float*)d_in[23]; const float* bf = (const float*)d_in[24];
  float* out = (float*)d_out;

  char* w = (char*)d_ws;
  size_t off = 0;
  auto take = [&](size_t bytes) -> char* {
    char* p = w + off;
    off = (off + bytes + 255) & ~(size_t)255;
    return p;
  };

  const int NB_AGG = 2048, NB_SP = 2048, NB_Z = 1024, NB_E = 2048;

  float* bufA    = (float*)take((size_t)N*D*4);
  float* bufB    = (float*)take((size_t)N*D*4);
  int*   csr     = (int*)  take((size_t)E*4);
  int*   offsets = (int*)  take((size_t)(N+1)*4);
  float* dinv    = (float*)take((size_t)N*4);
  float* s_sp    = (float*)take((size_t)N*4);
  float* p0_sp   = (float*)take((size_t)N*4);
  float* p1_sp   = (float*)take((size_t)N*4);
  float* s_te    = (float*)take((size_t)N*4);
  float* p0_te   = (float*)take((size_t)N*4);
  float* p1_te   = (float*)take((size_t)N*4);
  float* psum    = (float*)take((size_t)NB_AGG*D*4);
  float* psq     = (float*)take((size_t)NB_AGG*D*4);
  float* Wmod    = (float*)take((size_t)D*D*4);
  float* cconst  = (float*)take((size_t)D*4);
  float* scaleb  = (float*)take((size_t)D*4);
  float* shiftb  = (float*)take((size_t)D*4);
  float* sem     = (float*)take((size_t)96*4);
  // --- zero-init region (contiguous) ---
  Scal* sc     = (Scal*)take(sizeof(Scal));
  int*  indeg  = (int*) take((size_t)N*4);
  int*  outdeg = (int*) take((size_t)N*4);
  int*  cursor = (int*) take((size_t)N*4);
  float* td    = (float*)take((size_t)N*4);
  size_t zbytes = (size_t)((w + off) - (char*)sc);
  hipMemsetAsync(sc, 0, zbytes, stream);

  int gE = (E + 255) / 256;
  int gN = (N + 255) / 256;
  int gT = (N + BN - 1) / BN;   // GEMM tiles

  // graph prep
  k_hist<<<gE, 256, 0, stream>>>(src, dst, indeg, outdeg, E);
  k_scan<<<1, 1024, 0, stream>>>(indeg, offsets, N);
  k_dinv<<<gN, 256, 0, stream>>>(indeg, dinv, N);
  k_fill<<<gE, 256, 0, stream>>>(src, dst, offsets, cursor, csr, E);

  // time diffs
  k_estats<<<NB_E, 256, 0, stream>>>(ea, E, sc);
  k_efin<<<1, 1, 0, stream>>>(sc, E);
  k_td<<<gE, 256, 0, stream>>>(ea, src, dst, sc, td, E);
  k_tdfin<<<gN, 256, 0, stream>>>(td, indeg, outdeg, N);

  // layer 1
  k_gemm<<<gT, 256, 0, stream>>>(x, W1, nullptr, dinv, bufA, N);
  k_agg<<<NB_AGG, 256, 0, stream>>>(bufA, offsets, csr, dinv, b1, bufB, psum, psq, N);
  k_colreduce<<<D, 256, 0, stream>>>(psum, psq, NB_AGG, g1, be1, scaleb, shiftb, N);
  k_fold<<<D, D, 0, stream>>>(W2, scaleb, shiftb, Wmod, cconst);
  // layer 2
  k_gemm<<<gT, 256, 0, stream>>>(bufB, Wmod, cconst, dinv, bufA, N);
  k_agg<<<NB_AGG, 256, 0, stream>>>(bufA, offsets, csr, dinv, b2, bufB, psum, psq, N);
  k_colreduce<<<D, 256, 0, stream>>>(psum, psq, NB_AGG, g2, be2, scaleb, shiftb, N);
  k_fold<<<D, D, 0, stream>>>(W3, scaleb, shiftb, Wmod, cconst);
  // layer 3
  k_gemm<<<gT, 256, 0, stream>>>(bufB, Wmod, cconst, dinv, bufA, N);
  k_agg<<<NB_AGG, 256, 0, stream>>>(bufA, offsets, csr, dinv, b3, bufB, psum, psq, N);
  k_colreduce<<<D, 256, 0, stream>>>(psum, psq, NB_AGG, g3, be3, scaleb, shiftb, N);

  // branches
  k_sem<<<1, 64, 0, stream>>>(emb, Wa, ba, Wf, sem);
  k_spatial<<<NB_SP, 256, 0, stream>>>(bufB, scaleb, shiftb, Wa, ba, Wf, tt, sem,
                                       s_sp, p0_sp, p1_sp, sc->maxkey, N);
  k_temporal<<<gT, 256, 0, stream>>>(x, td, Wt, bt, Wa, ba, Wf,
                                     s_te, p0_te, p1_te, sc->maxkey, N);
  // softmax + combine
  k_zsum<<<NB_Z, 256, 0, stream>>>(s_sp, s_te, tt, sem, sc, N);
  k_final<<<gN, 256, 0, stream>>>(s_sp, p0_sp, p1_sp, s_te, p0_te, p1_te,
                                  tt, sem, sc, bf, out, N);
}

// Round 3
// 1358.577 us; speedup vs baseline: 1.7428x; 1.1498x over previous
//
#include <hip/hip_runtime.h>
#include <math.h>

#define D   128
#define WAVE 64

// GEMM tiling
#define BN  128   // nodes per block
#define KP  32    // K panel
#define TN  8     // nodes per thread
#define TJ  8     // outputs per thread
#define XSTR (BN + 4)  // padded xs row stride

// scan config
#define SCAN_B 256
#define SCAN_T 256

struct Scal {
  double esum, esumsq;     // zero-init
  unsigned maxkey[3];      // zero-init (decodes below all finite)
  float Z[3];              // zero-init
  float emean, einv;       // written by k_efin
};

__device__ __forceinline__ unsigned fkey(float f){
  unsigned b = __float_as_uint(f);
  return (b & 0x80000000u) ? ~b : (b | 0x80000000u);
}
__device__ __forceinline__ float fdec(unsigned k){
  return (k & 0x80000000u) ? __uint_as_float(k & 0x7fffffffu) : __uint_as_float(~k);
}
__device__ __forceinline__ void atomAddF(float* p, float v){
  __hip_atomic_fetch_add(p, v, __ATOMIC_RELAXED, __HIP_MEMORY_SCOPE_AGENT);
}
__device__ __forceinline__ void atomAddD(double* p, double v){
  __hip_atomic_fetch_add(p, v, __ATOMIC_RELAXED, __HIP_MEMORY_SCOPE_AGENT);
}

// ---------- graph prep ----------
__global__ void k_hist(const int* __restrict__ src, const int* __restrict__ dst,
                       int* indeg, int* outdeg, int E){
  int e = blockIdx.x*blockDim.x + threadIdx.x;
  if(e < E){ atomicAdd(&indeg[dst[e]], 1); atomicAdd(&outdeg[src[e]], 1); }
}

// pass 1: per-block tile sums
__global__ void __launch_bounds__(SCAN_T)
k_scan1(const int* __restrict__ indeg, int* __restrict__ blockSum, int n){
  int tile  = (n + SCAN_B - 1) / SCAN_B;
  int start = blockIdx.x * tile;
  int end   = min(start + tile, n);
  int s = 0;
  for(int i = start + threadIdx.x; i < end; i += SCAN_T) s += indeg[i];
  #pragma unroll
  for(int o = 32; o; o >>= 1) s += __shfl_xor(s, o);
  __shared__ int ls[4];
  if((threadIdx.x & 63) == 0) ls[threadIdx.x >> 6] = s;
  __syncthreads();
  if(threadIdx.x == 0) blockSum[blockIdx.x] = ls[0]+ls[1]+ls[2]+ls[3];
}

// pass 2: exclusive scan of the 256 block sums, in place
__global__ void __launch_bounds__(SCAN_B)
k_scan2(int* blockSum){
  __shared__ int tmp[SCAN_B];
  int t = threadIdx.x;
  tmp[t] = blockSum[t];
  __syncthreads();
  for(int o = 1; o < SCAN_B; o <<= 1){
    int v = (t >= o) ? tmp[t-o] : 0;
    __syncthreads();
    tmp[t] += v;
    __syncthreads();
  }
  blockSum[t] = (t == 0) ? 0 : tmp[t-1];
}

// pass 3: per-block exclusive scan + base; also writes dinv
__global__ void __launch_bounds__(SCAN_T)
k_scan3(const int* __restrict__ indeg, const int* __restrict__ blockSum,
        int* __restrict__ offsets, float* __restrict__ dinv, int n){
  int tile  = (n + SCAN_B - 1) / SCAN_B;
  int start = blockIdx.x * tile;
  int end   = min(start + tile, n);
  int chunk = (tile + SCAN_T - 1) / SCAN_T;
  int t = threadIdx.x;
  int tstart = start + t * chunk;
  int tend   = min(tstart + chunk, end);
  int s = 0;
  for(int i = tstart; i < tend; i++) s += indeg[i];
  __shared__ int tmp[SCAN_T];
  tmp[t] = s;
  __syncthreads();
  for(int o = 1; o < SCAN_T; o <<= 1){
    int v = (t >= o) ? tmp[t-o] : 0;
    __syncthreads();
    tmp[t] += v;
    __syncthreads();
  }
  int run = blockSum[blockIdx.x] + ((t == 0) ? 0 : tmp[t-1]);
  for(int i = tstart; i < tend; i++){
    int dg = indeg[i];
    offsets[i] = run;
    run += dg;
    dinv[i] = rsqrtf((float)(dg + 1));
  }
  if(blockIdx.x == SCAN_B-1 && t == SCAN_T-1) offsets[n] = run;
}

__global__ void k_fill(const int* __restrict__ src, const int* __restrict__ dst,
                       const int* __restrict__ offsets, int* cursor, int* csr, int E){
  int e = blockIdx.x*blockDim.x + threadIdx.x;
  if(e < E){
    int d = dst[e];
    int pos = atomicAdd(&cursor[d], 1);
    csr[offsets[d] + pos] = src[e];
  }
}

// ---------- edge standardization / time diffs ----------
__global__ void k_estats(const float* __restrict__ ea, int E, Scal* sc){
  int i = blockIdx.x*blockDim.x + threadIdx.x;
  int stride = gridDim.x*blockDim.x;
  double s = 0.0, q = 0.0;
  for(; i < E; i += stride){
    float v = fminf(fmaxf(ea[i], -1000.f), 1000.f);
    s += (double)v; q += (double)v * (double)v;
  }
  for(int o = 32; o; o >>= 1){ s += __shfl_xor(s, o); q += __shfl_xor(q, o); }
  __shared__ double ls[4], lq[4];
  int wv = threadIdx.x >> 6;
  if((threadIdx.x & 63) == 0){ ls[wv] = s; lq[wv] = q; }
  __syncthreads();
  if(threadIdx.x == 0){
    double S = ls[0]+ls[1]+ls[2]+ls[3], Q = lq[0]+lq[1]+lq[2]+lq[3];
    atomAddD(&sc->esum, S); atomAddD(&sc->esumsq, Q);
  }
}

__global__ void k_efin(Scal* sc, int E){
  double mean = sc->esum / E;
  double var  = (sc->esumsq - sc->esum*sc->esum/E) / (double)(E - 1);
  double sd   = sqrt(var > 0.0 ? var : 0.0);
  sc->emean = (float)mean;
  sc->einv  = (float)(1.0 / (sd + 1e-9));
}

__global__ void k_td(const float* __restrict__ ea, const int* __restrict__ src,
                     const int* __restrict__ dst, const Scal* sc, float* td, int E){
  int e = blockIdx.x*blockDim.x + threadIdx.x;
  if(e < E){
    float v  = fminf(fmaxf(ea[e], -1000.f), 1000.f);
    float en = (v - sc->emean) * sc->einv;
    atomAddF(&td[src[e]], en);
    atomAddF(&td[dst[e]], en);
  }
}

__global__ void k_tdfin(float* td, const int* __restrict__ indeg,
                        const int* __restrict__ outdeg, int n){
  int i = blockIdx.x*blockDim.x + threadIdx.x;
  if(i < n) td[i] /= fmaxf((float)(indeg[i] + outdeg[i]), 1.f);
}

// ---------- register-tiled GEMM: out[node,:] = dinv[node]*(A[node,:]@W + cvec) ----------
__global__ void __launch_bounds__(256)
k_gemm(const float* __restrict__ A, const float* __restrict__ W,
       const float* __restrict__ cvec, const float* __restrict__ dinv,
       float* __restrict__ out, int n){
  __shared__ float xs[KP][XSTR];   // x panel, transposed
  __shared__ float ws[KP][D];      // W panel
  const int t  = threadIdx.x;
  const int jg = t & 15, ng = t >> 4;
  const int j0 = jg * TJ, n0 = ng * TN;
  const int nodeBase = blockIdx.x * BN;

  float cr[TJ];
  if(cvec){
    float4 c0 = *(const float4*)(cvec + j0);
    float4 c1 = *(const float4*)(cvec + j0 + 4);
    cr[0]=c0.x; cr[1]=c0.y; cr[2]=c0.z; cr[3]=c0.w;
    cr[4]=c1.x; cr[5]=c1.y; cr[6]=c1.z; cr[7]=c1.w;
  } else {
    #pragma unroll
    for(int j=0;j<TJ;j++) cr[j]=0.f;
  }
  float acc[TN][TJ];
  #pragma unroll
  for(int i=0;i<TN;i++)
    #pragma unroll
    for(int j=0;j<TJ;j++) acc[i][j]=cr[j];

  for(int p=0;p<D/KP;p++){
    {
      const float4* Wp = (const float4*)(W + (size_t)p*KP*D);
      float4* ws4 = (float4*)ws;
      ws4[t]       = Wp[t];
      ws4[t + 256] = Wp[t + 256];
      ws4[t + 512] = Wp[t + 512];
      ws4[t + 768] = Wp[t + 768];
    }
    #pragma unroll
    for(int q=0;q<4;q++){
      int idx = t + q*256;
      int node = idx >> 3, kq = idx & 7;
      int gn = nodeBase + node; if(gn >= n) gn = n-1;
      float4 v = *(const float4*)(A + (size_t)gn*D + p*KP + kq*4);
      xs[kq*4+0][node] = v.x; xs[kq*4+1][node] = v.y;
      xs[kq*4+2][node] = v.z; xs[kq*4+3][node] = v.w;
    }
    __syncthreads();
    #pragma unroll 4
    for(int k=0;k<KP;k++){
      float4 xa = *(const float4*)&xs[k][n0];
      float4 xb = *(const float4*)&xs[k][n0+4];
      float4 wa = *(const float4*)&ws[k][j0];
      float4 wb = *(const float4*)&ws[k][j0+4];
      float xv[8] = {xa.x,xa.y,xa.z,xa.w,xb.x,xb.y,xb.z,xb.w};
      float wv[8] = {wa.x,wa.y,wa.z,wa.w,wb.x,wb.y,wb.z,wb.w};
      #pragma unroll
      for(int i=0;i<TN;i++)
        #pragma unroll
        for(int j=0;j<TJ;j++)
          acc[i][j] = fmaf(xv[i], wv[j], acc[i][j]);
    }
    __syncthreads();
  }
  #pragma unroll
  for(int i=0;i<TN;i++){
    int gn = nodeBase + n0 + i;
    if(gn < n){
      float d = dinv[gn];
      float4 o0 = make_float4(acc[i][0]*d, acc[i][1]*d, acc[i][2]*d, acc[i][3]*d);
      float4 o1 = make_float4(acc[i][4]*d, acc[i][5]*d, acc[i][6]*d, acc[i][7]*d);
      *(float4*)(out + (size_t)gn*D + j0)     = o0;
      *(float4*)(out + (size_t)gn*D + j0 + 4) = o1;
    }
  }
}

// ---------- temporal branch: register-tiled GEMM + fused score epilogue ----------
__global__ void __launch_bounds__(256)
k_temporal(const float* __restrict__ x, const float* __restrict__ td,
           const float* __restrict__ Wt, const float* __restrict__ bt,
           const float* __restrict__ Wa, const float* __restrict__ ba,
           const float* __restrict__ Wf,
           float* s_te, float* p0_te, float* p1_te, unsigned* maxkey, int n){
  __shared__ float xs[KP][XSTR];
  __shared__ float ws[KP][D];
  __shared__ unsigned mk;
  const int t  = threadIdx.x;
  const int jg = t & 15, ng = t >> 4;
  const int j0 = jg * TJ, n0 = ng * TN;
  const int nodeBase = blockIdx.x * BN;
  if(t == 0) mk = 0;

  float acc[TN][TJ];
  #pragma unroll
  for(int i=0;i<TN;i++)
    #pragma unroll
    for(int j=0;j<TJ;j++) acc[i][j]=0.f;

  for(int p=0;p<D/KP;p++){
    {
      const float4* Wp = (const float4*)(Wt + (size_t)p*KP*D);
      float4* ws4 = (float4*)ws;
      ws4[t]       = Wp[t];
      ws4[t + 256] = Wp[t + 256];
      ws4[t + 512] = Wp[t + 512];
      ws4[t + 768] = Wp[t + 768];
    }
    #pragma unroll
    for(int q=0;q<4;q++){
      int idx = t + q*256;
      int node = idx >> 3, kq = idx & 7;
      int gn = nodeBase + node; if(gn >= n) gn = n-1;
      float4 v = *(const float4*)(x + (size_t)gn*D + p*KP + kq*4);
      xs[kq*4+0][node] = v.x; xs[kq*4+1][node] = v.y;
      xs[kq*4+2][node] = v.z; xs[kq*4+3][node] = v.w;
    }
    __syncthreads();
    #pragma unroll 4
    for(int k=0;k<KP;k++){
      float4 xa = *(const float4*)&xs[k][n0];
      float4 xb = *(const float4*)&xs[k][n0+4];
      float4 wa = *(const float4*)&ws[k][j0];
      float4 wb = *(const float4*)&ws[k][j0+4];
      float xv[8] = {xa.x,xa.y,xa.z,xa.w,xb.x,xb.y,xb.z,xb.w};
      float wv[8] = {wa.x,wa.y,wa.z,wa.w,wb.x,wb.y,wb.z,wb.w};
      #pragma unroll
      for(int i=0;i<TN;i++)
        #pragma unroll
        for(int j=0;j<TJ;j++)
          acc[i][j] = fmaf(xv[i], wv[j], acc[i][j]);
    }
    __syncthreads();
  }
  float wl[TJ], bb[TJ], wa8[TJ], wf0[TJ], wf1[TJ];
  #pragma unroll
  for(int j=0;j<TJ;j++){
    wl[j]  = Wt[(size_t)D*D + j0 + j];
    bb[j]  = bt[j0 + j];
    wa8[j] = Wa[j0 + j];
    float2 w2 = ((const float2*)Wf)[j0 + j];
    wf0[j] = w2.x; wf1[j] = w2.y;
  }
  float ba0 = ba[0];
  float mloc = -INFINITY;
  #pragma unroll
  for(int i=0;i<TN;i++){
    int gn = nodeBase + n0 + i;
    float tdv = (gn < n) ? td[gn] : 0.f;
    float s = 0.f, p0 = 0.f, p1 = 0.f;
    #pragma unroll
    for(int j=0;j<TJ;j++){
      float tj = fmaxf(acc[i][j] + tdv*wl[j] + bb[j], 0.f);
      s  = fmaf(tj, wa8[j], s);
      p0 = fmaf(tj, wf0[j], p0);
      p1 = fmaf(tj, wf1[j], p1);
    }
    #pragma unroll
    for(int o=8;o;o>>=1){
      s += __shfl_xor(s, o); p0 += __shfl_xor(p0, o); p1 += __shfl_xor(p1, o);
    }
    if(jg == 0 && gn < n){
      s += ba0;
      s_te[gn] = s; p0_te[gn] = p0; p1_te[gn] = p1;
      mloc = fmaxf(mloc, s);
    }
  }
  __syncthreads();
  if(jg == 0) atomicMax(&mk, fkey(mloc));
  __syncthreads();
  if(t == 0) atomicMax(&maxkey[1], mk);
}

// ---------- aggregation ----------
__global__ void __launch_bounds__(256)
k_agg(const float* __restrict__ h, const int* __restrict__ offsets,
      const int* __restrict__ csr, const float* __restrict__ dinv,
      const float* __restrict__ bias, float* __restrict__ out,
      float* __restrict__ psum, float* __restrict__ psq, int n){
  int lane = threadIdx.x & 63;
  int wid  = (blockIdx.x*blockDim.x + threadIdx.x) >> 6;
  int nw   = (gridDim.x*blockDim.x) >> 6;
  float2 bb = ((const float2*)bias)[lane];
  float cs0 = 0, cs1 = 0, cq0 = 0, cq1 = 0;
  for(int node = wid; node < n; node += nw){
    int off = offsets[node], end = offsets[node+1];
    float di = dinv[node];
    float2 hs = ((const float2*)(h + (size_t)node*D))[lane];
    float a0 = hs.x, a1 = hs.y;
    float b0 = 0.f, b1v = 0.f;
    int e = off;
    for(; e + 1 < end; e += 2){
      int s1 = csr[e], s2 = csr[e+1];
      float2 h1 = ((const float2*)(h + (size_t)s1*D))[lane];
      float2 h2 = ((const float2*)(h + (size_t)s2*D))[lane];
      a0 += h1.x; a1 += h1.y; b0 += h2.x; b1v += h2.y;
    }
    if(e < end){
      int s1 = csr[e];
      float2 h1 = ((const float2*)(h + (size_t)s1*D))[lane];
      a0 += h1.x; a1 += h1.y;
    }
    float r0 = fmaxf(fmaf(di, a0 + b0,  bb.x), 0.f);
    float r1 = fmaxf(fmaf(di, a1 + b1v, bb.y), 0.f);
    ((float2*)(out + (size_t)node*D))[lane] = make_float2(r0, r1);
    cs0 += r0; cs1 += r1; cq0 += r0*r0; cq1 += r1*r1;
  }
  __shared__ float lcs[D], lcq[D];
  for(int i = threadIdx.x; i < D; i += blockDim.x){ lcs[i] = 0.f; lcq[i] = 0.f; }
  __syncthreads();
  atomicAdd(&lcs[2*lane],   cs0); atomicAdd(&lcs[2*lane+1], cs1);
  atomicAdd(&lcq[2*lane],   cq0); atomicAdd(&lcq[2*lane+1], cq1);
  __syncthreads();
  for(int i = threadIdx.x; i < D; i += blockDim.x){
    psum[(size_t)blockIdx.x*D + i] = lcs[i];
    psq [(size_t)blockIdx.x*D + i] = lcq[i];
  }
}

// ---------- BN params ----------
__global__ void k_colreduce(const float* __restrict__ psum, const float* __restrict__ psq,
                            int nb, const float* __restrict__ g, const float* __restrict__ be,
                            float* scale, float* shift, int n){
  int c = blockIdx.x;
  float s = 0, q = 0;
  for(int b = threadIdx.x; b < nb; b += blockDim.x){
    s += psum[(size_t)b*D + c]; q += psq[(size_t)b*D + c];
  }
  for(int o = 32; o; o >>= 1){ s += __shfl_xor(s, o); q += __shfl_xor(q, o); }
  __shared__ float ls[4], lq[4];
  int wv = threadIdx.x >> 6;
  if((threadIdx.x & 63) == 0){ ls[wv] = s; lq[wv] = q; }
  __syncthreads();
  if(threadIdx.x == 0){
    float S = ls[0]+ls[1]+ls[2]+ls[3], Q = lq[0]+lq[1]+lq[2]+lq[3];
    float mean = S / n;
    float var  = fmaxf(Q / n - mean*mean, 0.f);
    float sc   = g[c] * rsqrtf(var + 1e-5f);
    scale[c] = sc;
    shift[c] = fmaf(-mean, sc, be[c]);
  }
}

__global__ void k_fold(const float* __restrict__ W, const float* __restrict__ scale,
                       const float* __restrict__ shift, float* Wmod, float* cconst){
  int j = blockIdx.x, k = threadIdx.x;
  float w = W[k*D + j];
  Wmod[k*D + j] = scale[k] * w;
  float sm = shift[k] * w;
  for(int o = 32; o; o >>= 1) sm += __shfl_xor(sm, o);
  __shared__ float l2[2];
  if((k & 63) == 0) l2[k >> 6] = sm;
  __syncthreads();
  if(k == 0) cconst[j] = l2[0] + l2[1];
}

// ---------- semantic table ----------
__global__ void k_sem(const float* __restrict__ emb, const float* __restrict__ Wa,
                      const float* __restrict__ ba, const float* __restrict__ Wf, float* sem){
  int t = threadIdx.x;
  if(t < 32){
    float s = ba[0], q0 = 0, q1 = 0;
    for(int c = 0; c < D; c++){
      float e = emb[t*D + c];
      s  = fmaf(e, Wa[c],     s);
      q0 = fmaf(e, Wf[2*c],   q0);
      q1 = fmaf(e, Wf[2*c+1], q1);
    }
    sem[t] = s; sem[32 + t] = q0; sem[64 + t] = q1;
  }
}

// ---------- spatial branch scores ----------
__global__ void __launch_bounds__(256)
k_spatial(const float* __restrict__ R, const float* __restrict__ scale,
          const float* __restrict__ shift, const float* __restrict__ Wa,
          const float* __restrict__ ba, const float* __restrict__ Wf,
          const int* __restrict__ tt, const float* __restrict__ sem,
          float* s_sp, float* p0_sp, float* p1_sp, unsigned* maxkey, int n){
  int lane = threadIdx.x & 63;
  int wid  = (blockIdx.x*blockDim.x + threadIdx.x) >> 6;
  int nw   = (gridDim.x*blockDim.x) >> 6;
  float2 sc = ((const float2*)scale)[lane];
  float2 sh = ((const float2*)shift)[lane];
  float2 wa = ((const float2*)Wa)[lane];
  float4 wf = ((const float4*)Wf)[lane];
  float ba0 = ba[0];
  float mloc = -INFINITY, msem = -INFINITY;
  for(int node = wid; node < n; node += nw){
    float2 v = ((const float2*)(R + (size_t)node*D))[lane];
    float v0 = fmaf(v.x, sc.x, sh.x);
    float v1 = fmaf(v.y, sc.y, sh.y);
    float s  = v0*wa.x + v1*wa.y;
    float p0 = v0*wf.x + v1*wf.z;
    float p1 = v0*wf.y + v1*wf.w;
    for(int o = 32; o; o >>= 1){
      s += __shfl_xor(s, o); p0 += __shfl_xor(p0, o); p1 += __shfl_xor(p1, o);
    }
    s += ba0;
    if(lane == 0){ s_sp[node] = s; p0_sp[node] = p0; p1_sp[node] = p1; }
    mloc = fmaxf(mloc, s);
    msem = fmaxf(msem, sem[tt[node]]);
  }
  __shared__ float lm[4], lsm[4];
  int wv = threadIdx.x >> 6;
  if(lane == 0){ lm[wv] = mloc; lsm[wv] = msem; }
  __syncthreads();
  if(threadIdx.x == 0){
    float M  = fmaxf(fmaxf(lm[0], lm[1]),  fmaxf(lm[2], lm[3]));
    float M2 = fmaxf(fmaxf(lsm[0], lsm[1]), fmaxf(lsm[2], lsm[3]));
    atomicMax(&maxkey[0], fkey(M));
    atomicMax(&maxkey[2], fkey(M2));
  }
}

// ---------- softmax denominators ----------
__global__ void k_zsum(const float* __restrict__ s_sp, const float* __restrict__ s_te,
                       const int* __restrict__ tt, const float* __restrict__ sem,
                       Scal* sc, int n){
  float M0 = fdec(sc->maxkey[0]), M1 = fdec(sc->maxkey[1]), M2 = fdec(sc->maxkey[2]);
  int i = blockIdx.x*blockDim.x + threadIdx.x;
  int stride = gridDim.x*blockDim.x;
  float z0 = 0, z1 = 0, z2 = 0;
  for(; i < n; i += stride){
    z0 += expf(s_sp[i] - M0);
    z1 += expf(s_te[i] - M1);
    z2 += expf(sem[tt[i]] - M2);
  }
  for(int o = 32; o; o >>= 1){
    z0 += __shfl_xor(z0, o); z1 += __shfl_xor(z1, o); z2 += __shfl_xor(z2, o);
  }
  __shared__ float l0[4], l1[4], l2[4];
  int wv = threadIdx.x >> 6;
  if((threadIdx.x & 63) == 0){ l0[wv] = z0; l1[wv] = z1; l2[wv] = z2; }
  __syncthreads();
  if(threadIdx.x == 0){
    atomAddF(&sc->Z[0], l0[0]+l0[1]+l0[2]+l0[3]);
    atomAddF(&sc->Z[1], l1[0]+l1[1]+l1[2]+l1[3]);
    atomAddF(&sc->Z[2], l2[0]+l2[1]+l2[2]+l2[3]);
  }
}

// ---------- final combine ----------
__global__ void k_final(const float* __restrict__ s_sp, const float* __restrict__ p0_sp,
                        const float* __restrict__ p1_sp, const float* __restrict__ s_te,
                        const float* __restrict__ p0_te, const float* __restrict__ p1_te,
                        const int* __restrict__ tt, const float* __restrict__ sem,
                        const Scal* sc, const float* __restrict__ bf,
                        float* __restrict__ out, int n){
  int i = blockIdx.x*blockDim.x + threadIdx.x;
  if(i < n){
    float M0 = fdec(sc->maxkey[0]), M1 = fdec(sc->maxkey[1]), M2 = fdec(sc->maxkey[2]);
    float w0 = expf(s_sp[i] - M0) / sc->Z[0];
    float w1 = expf(s_te[i] - M1) / sc->Z[1];
    int t = tt[i];
    float w2 = expf(sem[t] - M2) / sc->Z[2];
    float o0 = w0*p0_sp[i] + w1*p0_te[i] + w2*sem[32 + t] + bf[0];
    float o1 = w0*p1_sp[i] + w1*p1_te[i] + w2*sem[64 + t] + bf[1];
    ((float2*)out)[i] = make_float2(o0, o1);
  }
}

extern "C" void kernel_launch(void* const* d_in, const int* in_sizes, int n_in,
                              void* d_out, int out_size, void* d_ws, size_t ws_size,
                              hipStream_t stream) {
  const int N = in_sizes[5];   // timestamps
  const int E = in_sizes[1];   // src

  const float* x   = (const float*)d_in[0];
  const int*   src = (const int*)  d_in[1];
  const int*   dst = (const int*)  d_in[2];
  const float* ea  = (const float*)d_in[3];
  const int*   tt  = (const int*)  d_in[4];
  const float* W1  = (const float*)d_in[6];  const float* b1 = (const float*)d_in[7];
  const float* W2  = (const float*)d_in[8];  const float* b2 = (const float*)d_in[9];
  const float* W3  = (const float*)d_in[10]; const float* b3 = (const float*)d_in[11];
  const float* Wt  = (const float*)d_in[12]; const float* bt = (const float*)d_in[13];
  const float* emb = (const float*)d_in[14];
  const float* Wa  = (const float*)d_in[15]; const float* ba = (const float*)d_in[16];
  const float* g1  = (const float*)d_in[17]; const float* be1= (const float*)d_in[18];
  const float* g2  = (const float*)d_in[19]; const float* be2= (const float*)d_in[20];
  const float* g3  = (const float*)d_in[21]; const float* be3= (const float*)d_in[22];
  const float* Wf  = (const float*)d_in[23]; const float* bf = (const float*)d_in[24];
  float* out = (float*)d_out;

  char* w = (char*)d_ws;
  size_t off = 0;
  auto take = [&](size_t bytes) -> char* {
    char* p = w + off;
    off = (off + bytes + 255) & ~(size_t)255;
    return p;
  };

  const int NB_AGG = 2048, NB_SP = 2048, NB_Z = 1024, NB_E = 2048;

  float* bufA    = (float*)take((size_t)N*D*4);
  float* bufB    = (float*)take((size_t)N*D*4);
  int*   csr     = (int*)  take((size_t)E*4);
  int*   offsets = (int*)  take((size_t)(N+1)*4);
  float* dinv    = (float*)take((size_t)N*4);
  int*   blockSum= (int*)  take((size_t)SCAN_B*4);
  float* s_sp    = (float*)take((size_t)N*4);
  float* p0_sp   = (float*)take((size_t)N*4);
  float* p1_sp   = (float*)take((size_t)N*4);
  float* s_te    = (float*)take((size_t)N*4);
  float* p0_te   = (float*)take((size_t)N*4);
  float* p1_te   = (float*)take((size_t)N*4);
  float* psum    = (float*)take((size_t)NB_AGG*D*4);
  float* psq     = (float*)take((size_t)NB_AGG*D*4);
  float* Wmod    = (float*)take((size_t)D*D*4);
  float* cconst  = (float*)take((size_t)D*4);
  float* scaleb  = (float*)take((size_t)D*4);
  float* shiftb  = (float*)take((size_t)D*4);
  float* sem     = (float*)take((size_t)96*4);
  // --- zero-init region (contiguous) ---
  Scal* sc     = (Scal*)take(sizeof(Scal));
  int*  indeg  = (int*) take((size_t)N*4);
  int*  outdeg = (int*) take((size_t)N*4);
  int*  cursor = (int*) take((size_t)N*4);
  float* td    = (float*)take((size_t)N*4);
  size_t zbytes = (size_t)((w + off) - (char*)sc);
  hipMemsetAsync(sc, 0, zbytes, stream);

  int gE = (E + 255) / 256;
  int gN = (N + 255) / 256;
  int gT = (N + BN - 1) / BN;   // GEMM tiles

  // graph prep
  k_hist<<<gE, 256, 0, stream>>>(src, dst, indeg, outdeg, E);
  k_scan1<<<SCAN_B, SCAN_T, 0, stream>>>(indeg, blockSum, N);
  k_scan2<<<1, SCAN_B, 0, stream>>>(blockSum);
  k_scan3<<<SCAN_B, SCAN_T, 0, stream>>>(indeg, blockSum, offsets, dinv, N);
  k_fill<<<gE, 256, 0, stream>>>(src, dst, offsets, cursor, csr, E);

  // time diffs
  k_estats<<<NB_E, 256, 0, stream>>>(ea, E, sc);
  k_efin<<<1, 1, 0, stream>>>(sc, E);
  k_td<<<gE, 256, 0, stream>>>(ea, src, dst, sc, td, E);
  k_tdfin<<<gN, 256, 0, stream>>>(td, indeg, outdeg, N);

  // layer 1
  k_gemm<<<gT, 256, 0, stream>>>(x, W1, nullptr, dinv, bufA, N);
  k_agg<<<NB_AGG, 256, 0, stream>>>(bufA, offsets, csr, dinv, b1, bufB, psum, psq, N);
  k_colreduce<<<D, 256, 0, stream>>>(psum, psq, NB_AGG, g1, be1, scaleb, shiftb, N);
  k_fold<<<D, D, 0, stream>>>(W2, scaleb, shiftb, Wmod, cconst);
  // layer 2
  k_gemm<<<gT, 256, 0, stream>>>(bufB, Wmod, cconst, dinv, bufA, N);
  k_agg<<<NB_AGG, 256, 0, stream>>>(bufA, offsets, csr, dinv, b2, bufB, psum, psq, N);
  k_colreduce<<<D, 256, 0, stream>>>(psum, psq, NB_AGG, g2, be2, scaleb, shiftb, N);
  k_fold<<<D, D, 0, stream>>>(W3, scaleb, shiftb, Wmod, cconst);
  // layer 3
  k_gemm<<<gT, 256, 0, stream>>>(bufB, Wmod, cconst, dinv, bufA, N);
  k_agg<<<NB_AGG, 256, 0, stream>>>(bufA, offsets, csr, dinv, b3, bufB, psum, psq, N);
  k_colreduce<<<D, 256, 0, stream>>>(psum, psq, NB_AGG, g3, be3, scaleb, shiftb, N);

  // branches
  k_sem<<<1, 64, 0, stream>>>(emb, Wa, ba, Wf, sem);
  k_spatial<<<NB_SP, 256, 0, stream>>>(bufB, scaleb, shiftb, Wa, ba, Wf, tt, sem,
                                       s_sp, p0_sp, p1_sp, sc->maxkey, N);
  k_temporal<<<gT, 256, 0, stream>>>(x, td, Wt, bt, Wa, ba, Wf,
                                     s_te, p0_te, p1_te, sc->maxkey, N);
  // softmax + combine
  k_zsum<<<NB_Z, 256, 0, stream>>>(s_sp, s_te, tt, sem, sc, N);
  k_final<<<gN, 256, 0, stream>>>(s_sp, p0_sp, p1_sp, s_te, p0_te, p1_te,
                                  tt, sem, sc, bf, out, N);
}

// Round 4
// 1204.345 us; speedup vs baseline: 1.9660x; 1.1281x over previous
//
#include <hip/hip_runtime.h>
#include <math.h>

#define D   128
#define WAVE 64

// GEMM tiling
#define BN  128
#define KP  32
#define TN  8
#define TJ  8
#define XSTR (BN + 4)

// scan config
#define SCAN_B 256
#define SCAN_T 256

#define MASK44 ((1ULL<<44) - 1)

struct Scal {
  double esum, esumsq;     // zero-init
  unsigned maxkey[3];      // zero-init (decodes below all finite)
  float Z[3];              // zero-init
  float emean, einv;       // written by k_efin
};

__device__ __forceinline__ unsigned fkey(float f){
  unsigned b = __float_as_uint(f);
  return (b & 0x80000000u) ? ~b : (b | 0x80000000u);
}
__device__ __forceinline__ float fdec(unsigned k){
  return (k & 0x80000000u) ? __uint_as_float(k & 0x7fffffffu) : __uint_as_float(~k);
}
__device__ __forceinline__ void atomAddF(float* p, float v){
  __hip_atomic_fetch_add(p, v, __ATOMIC_RELAXED, __HIP_MEMORY_SCOPE_AGENT);
}
__device__ __forceinline__ void atomAddD(double* p, double v){
  __hip_atomic_fetch_add(p, v, __ATOMIC_RELAXED, __HIP_MEMORY_SCOPE_AGENT);
}

// ---------- fused edge pass 1: indeg hist + packed out-side (count,sum) + edge stats ----------
__global__ void __launch_bounds__(256)
k_edge1(const int* __restrict__ src, const int* __restrict__ dst,
        const float* __restrict__ ea, int* __restrict__ indeg,
        unsigned long long* __restrict__ outAcc, Scal* sc, int E){
  int i = blockIdx.x*blockDim.x + threadIdx.x;
  int stride = gridDim.x*blockDim.x;
  double s = 0.0, q = 0.0;
  for(; i < E; i += stride){
    float v = fminf(fmaxf(ea[i], -1000.f), 1000.f);
    s += (double)v; q += (double)v * (double)v;
    atomicAdd(&indeg[dst[i]], 1);
    // pack: count in bits 44+, biased fixed-point sum (scale 2^20, bias +1024) in low 44 bits
    unsigned long long pk = (1ULL<<44) +
        (unsigned long long)(long long)((double)(v + 1024.0) * 1048576.0 + 0.5);
    atomicAdd(&outAcc[src[i]], pk);
  }
  for(int o = 32; o; o >>= 1){ s += __shfl_xor(s, o); q += __shfl_xor(q, o); }
  __shared__ double ls[4], lq[4];
  int wv = threadIdx.x >> 6;
  if((threadIdx.x & 63) == 0){ ls[wv] = s; lq[wv] = q; }
  __syncthreads();
  if(threadIdx.x == 0){
    double S = ls[0]+ls[1]+ls[2]+ls[3], Q = lq[0]+lq[1]+lq[2]+lq[3];
    atomAddD(&sc->esum, S); atomAddD(&sc->esumsq, Q);
  }
}

__global__ void k_efin(Scal* sc, int E){
  double mean = sc->esum / E;
  double var  = (sc->esumsq - sc->esum*sc->esum/E) / (double)(E - 1);
  double sd   = sqrt(var > 0.0 ? var : 0.0);
  sc->emean = (float)mean;
  sc->einv  = (float)(1.0 / (sd + 1e-9));
}

// ---------- hierarchical scan ----------
__global__ void __launch_bounds__(SCAN_T)
k_scan1(const int* __restrict__ indeg, int* __restrict__ blockSum, int n){
  int tile  = (n + SCAN_B - 1) / SCAN_B;
  int start = blockIdx.x * tile;
  int end   = min(start + tile, n);
  int s = 0;
  for(int i = start + threadIdx.x; i < end; i += SCAN_T) s += indeg[i];
  #pragma unroll
  for(int o = 32; o; o >>= 1) s += __shfl_xor(s, o);
  __shared__ int ls[4];
  if((threadIdx.x & 63) == 0) ls[threadIdx.x >> 6] = s;
  __syncthreads();
  if(threadIdx.x == 0) blockSum[blockIdx.x] = ls[0]+ls[1]+ls[2]+ls[3];
}

__global__ void __launch_bounds__(SCAN_B)
k_scan2(int* blockSum){
  __shared__ int tmp[SCAN_B];
  int t = threadIdx.x;
  tmp[t] = blockSum[t];
  __syncthreads();
  for(int o = 1; o < SCAN_B; o <<= 1){
    int v = (t >= o) ? tmp[t-o] : 0;
    __syncthreads();
    tmp[t] += v;
    __syncthreads();
  }
  blockSum[t] = (t == 0) ? 0 : tmp[t-1];
}

__global__ void __launch_bounds__(SCAN_T)
k_scan3(const int* __restrict__ indeg, const int* __restrict__ blockSum,
        int* __restrict__ offsets, float* __restrict__ dinv, int n){
  int tile  = (n + SCAN_B - 1) / SCAN_B;
  int start = blockIdx.x * tile;
  int end   = min(start + tile, n);
  int chunk = (tile + SCAN_T - 1) / SCAN_T;
  int t = threadIdx.x;
  int tstart = start + t * chunk;
  int tend   = min(tstart + chunk, end);
  int s = 0;
  for(int i = tstart; i < tend; i++) s += indeg[i];
  __shared__ int tmp[SCAN_T];
  tmp[t] = s;
  __syncthreads();
  for(int o = 1; o < SCAN_T; o <<= 1){
    int v = (t >= o) ? tmp[t-o] : 0;
    __syncthreads();
    tmp[t] += v;
    __syncthreads();
  }
  int run = blockSum[blockIdx.x] + ((t == 0) ? 0 : tmp[t-1]);
  for(int i = tstart; i < tend; i++){
    int dg = indeg[i];
    offsets[i] = run;
    run += dg;
    dinv[i] = rsqrtf((float)(dg + 1));
  }
  if(blockIdx.x == SCAN_B-1 && t == SCAN_T-1) offsets[n] = run;
}

// ---------- CSR fill: src index + clipped edge value ----------
__global__ void k_fill(const int* __restrict__ src, const int* __restrict__ dst,
                       const float* __restrict__ ea,
                       const int* __restrict__ offsets, int* cursor,
                       int* __restrict__ csr, float* __restrict__ csrv, int E){
  int e = blockIdx.x*blockDim.x + threadIdx.x;
  if(e < E){
    int d = dst[e];
    int pos = atomicAdd(&cursor[d], 1);
    int slot = offsets[d] + pos;
    csr[slot]  = src[e];
    csrv[slot] = fminf(fmaxf(ea[e], -1000.f), 1000.f);
  }
}

// ---------- td from CSR gather + packed out accumulator ----------
__global__ void k_td2(const int* __restrict__ offsets, const float* __restrict__ csrv,
                      const unsigned long long* __restrict__ outAcc,
                      const Scal* sc, float* __restrict__ td, int n){
  int i = blockIdx.x*blockDim.x + threadIdx.x;
  if(i < n){
    int o0 = offsets[i], o1 = offsets[i+1];
    float S_in = 0.f;
    for(int e = o0; e < o1; e++) S_in += csrv[e];
    unsigned long long acc = outAcc[i];
    int cout = (int)(acc >> 44);
    double S_out = (double)(acc & MASK44) * (1.0/1048576.0) - 1024.0 * (double)cout;
    int deg = (o1 - o0) + cout;
    float S = S_in + (float)S_out;
    float tdv = (S - sc->emean * (float)deg) * sc->einv / fmaxf((float)deg, 1.f);
    td[i] = tdv;
  }
}

// ---------- register-tiled GEMM: out[node,:] = dinv[node]*(A[node,:]@W + cvec) ----------
__global__ void __launch_bounds__(256)
k_gemm(const float* __restrict__ A, const float* __restrict__ W,
       const float* __restrict__ cvec, const float* __restrict__ dinv,
       float* __restrict__ out, int n){
  __shared__ float xs[KP][XSTR];
  __shared__ float ws[KP][D];
  const int t  = threadIdx.x;
  const int jg = t & 15, ng = t >> 4;
  const int j0 = jg * TJ, n0 = ng * TN;
  const int nodeBase = blockIdx.x * BN;

  float cr[TJ];
  if(cvec){
    float4 c0 = *(const float4*)(cvec + j0);
    float4 c1 = *(const float4*)(cvec + j0 + 4);
    cr[0]=c0.x; cr[1]=c0.y; cr[2]=c0.z; cr[3]=c0.w;
    cr[4]=c1.x; cr[5]=c1.y; cr[6]=c1.z; cr[7]=c1.w;
  } else {
    #pragma unroll
    for(int j=0;j<TJ;j++) cr[j]=0.f;
  }
  float acc[TN][TJ];
  #pragma unroll
  for(int i=0;i<TN;i++)
    #pragma unroll
    for(int j=0;j<TJ;j++) acc[i][j]=cr[j];

  for(int p=0;p<D/KP;p++){
    {
      const float4* Wp = (const float4*)(W + (size_t)p*KP*D);
      float4* ws4 = (float4*)ws;
      ws4[t]       = Wp[t];
      ws4[t + 256] = Wp[t + 256];
      ws4[t + 512] = Wp[t + 512];
      ws4[t + 768] = Wp[t + 768];
    }
    #pragma unroll
    for(int q=0;q<4;q++){
      int idx = t + q*256;
      int node = idx >> 3, kq = idx & 7;
      int gn = nodeBase + node; if(gn >= n) gn = n-1;
      float4 v = *(const float4*)(A + (size_t)gn*D + p*KP + kq*4);
      xs[kq*4+0][node] = v.x; xs[kq*4+1][node] = v.y;
      xs[kq*4+2][node] = v.z; xs[kq*4+3][node] = v.w;
    }
    __syncthreads();
    #pragma unroll 4
    for(int k=0;k<KP;k++){
      float4 xa = *(const float4*)&xs[k][n0];
      float4 xb = *(const float4*)&xs[k][n0+4];
      float4 wa = *(const float4*)&ws[k][j0];
      float4 wb = *(const float4*)&ws[k][j0+4];
      float xv[8] = {xa.x,xa.y,xa.z,xa.w,xb.x,xb.y,xb.z,xb.w};
      float wv[8] = {wa.x,wa.y,wa.z,wa.w,wb.x,wb.y,wb.z,wb.w};
      #pragma unroll
      for(int i=0;i<TN;i++)
        #pragma unroll
        for(int j=0;j<TJ;j++)
          acc[i][j] = fmaf(xv[i], wv[j], acc[i][j]);
    }
    __syncthreads();
  }
  #pragma unroll
  for(int i=0;i<TN;i++){
    int gn = nodeBase + n0 + i;
    if(gn < n){
      float d = dinv[gn];
      float4 o0 = make_float4(acc[i][0]*d, acc[i][1]*d, acc[i][2]*d, acc[i][3]*d);
      float4 o1 = make_float4(acc[i][4]*d, acc[i][5]*d, acc[i][6]*d, acc[i][7]*d);
      *(float4*)(out + (size_t)gn*D + j0)     = o0;
      *(float4*)(out + (size_t)gn*D + j0 + 4) = o1;
    }
  }
}

// ---------- temporal branch ----------
__global__ void __launch_bounds__(256)
k_temporal(const float* __restrict__ x, const float* __restrict__ td,
           const float* __restrict__ Wt, const float* __restrict__ bt,
           const float* __restrict__ Wa, const float* __restrict__ ba,
           const float* __restrict__ Wf,
           float* s_te, float* p0_te, float* p1_te, unsigned* maxkey, int n){
  __shared__ float xs[KP][XSTR];
  __shared__ float ws[KP][D];
  __shared__ unsigned mk;
  const int t  = threadIdx.x;
  const int jg = t & 15, ng = t >> 4;
  const int j0 = jg * TJ, n0 = ng * TN;
  const int nodeBase = blockIdx.x * BN;
  if(t == 0) mk = 0;

  float acc[TN][TJ];
  #pragma unroll
  for(int i=0;i<TN;i++)
    #pragma unroll
    for(int j=0;j<TJ;j++) acc[i][j]=0.f;

  for(int p=0;p<D/KP;p++){
    {
      const float4* Wp = (const float4*)(Wt + (size_t)p*KP*D);
      float4* ws4 = (float4*)ws;
      ws4[t]       = Wp[t];
      ws4[t + 256] = Wp[t + 256];
      ws4[t + 512] = Wp[t + 512];
      ws4[t + 768] = Wp[t + 768];
    }
    #pragma unroll
    for(int q=0;q<4;q++){
      int idx = t + q*256;
      int node = idx >> 3, kq = idx & 7;
      int gn = nodeBase + node; if(gn >= n) gn = n-1;
      float4 v = *(const float4*)(x + (size_t)gn*D + p*KP + kq*4);
      xs[kq*4+0][node] = v.x; xs[kq*4+1][node] = v.y;
      xs[kq*4+2][node] = v.z; xs[kq*4+3][node] = v.w;
    }
    __syncthreads();
    #pragma unroll 4
    for(int k=0;k<KP;k++){
      float4 xa = *(const float4*)&xs[k][n0];
      float4 xb = *(const float4*)&xs[k][n0+4];
      float4 wa = *(const float4*)&ws[k][j0];
      float4 wb = *(const float4*)&ws[k][j0+4];
      float xv[8] = {xa.x,xa.y,xa.z,xa.w,xb.x,xb.y,xb.z,xb.w};
      float wv[8] = {wa.x,wa.y,wa.z,wa.w,wb.x,wb.y,wb.z,wb.w};
      #pragma unroll
      for(int i=0;i<TN;i++)
        #pragma unroll
        for(int j=0;j<TJ;j++)
          acc[i][j] = fmaf(xv[i], wv[j], acc[i][j]);
    }
    __syncthreads();
  }
  float wl[TJ], bb[TJ], wa8[TJ], wf0[TJ], wf1[TJ];
  #pragma unroll
  for(int j=0;j<TJ;j++){
    wl[j]  = Wt[(size_t)D*D + j0 + j];
    bb[j]  = bt[j0 + j];
    wa8[j] = Wa[j0 + j];
    float2 w2 = ((const float2*)Wf)[j0 + j];
    wf0[j] = w2.x; wf1[j] = w2.y;
  }
  float ba0 = ba[0];
  float mloc = -INFINITY;
  #pragma unroll
  for(int i=0;i<TN;i++){
    int gn = nodeBase + n0 + i;
    float tdv = (gn < n) ? td[gn] : 0.f;
    float s = 0.f, p0 = 0.f, p1 = 0.f;
    #pragma unroll
    for(int j=0;j<TJ;j++){
      float tj = fmaxf(acc[i][j] + tdv*wl[j] + bb[j], 0.f);
      s  = fmaf(tj, wa8[j], s);
      p0 = fmaf(tj, wf0[j], p0);
      p1 = fmaf(tj, wf1[j], p1);
    }
    #pragma unroll
    for(int o=8;o;o>>=1){
      s += __shfl_xor(s, o); p0 += __shfl_xor(p0, o); p1 += __shfl_xor(p1, o);
    }
    if(jg == 0 && gn < n){
      s += ba0;
      s_te[gn] = s; p0_te[gn] = p0; p1_te[gn] = p1;
      mloc = fmaxf(mloc, s);
    }
  }
  __syncthreads();
  if(jg == 0) atomicMax(&mk, fkey(mloc));
  __syncthreads();
  if(t == 0) atomicMax(&maxkey[1], mk);
}

// ---------- aggregation ----------
__global__ void __launch_bounds__(256)
k_agg(const float* __restrict__ h, const int* __restrict__ offsets,
      const int* __restrict__ csr, const float* __restrict__ dinv,
      const float* __restrict__ bias, float* __restrict__ out,
      float* __restrict__ psum, float* __restrict__ psq, int n){
  int lane = threadIdx.x & 63;
  int wid  = (blockIdx.x*blockDim.x + threadIdx.x) >> 6;
  int nw   = (gridDim.x*blockDim.x) >> 6;
  float2 bb = ((const float2*)bias)[lane];
  float cs0 = 0, cs1 = 0, cq0 = 0, cq1 = 0;
  for(int node = wid; node < n; node += nw){
    int off = offsets[node], end = offsets[node+1];
    float di = dinv[node];
    float2 hs = ((const float2*)(h + (size_t)node*D))[lane];
    float a0 = hs.x, a1 = hs.y;
    float b0 = 0.f, b1v = 0.f;
    int e = off;
    for(; e + 1 < end; e += 2){
      int s1 = csr[e], s2 = csr[e+1];
      float2 h1 = ((const float2*)(h + (size_t)s1*D))[lane];
      float2 h2 = ((const float2*)(h + (size_t)s2*D))[lane];
      a0 += h1.x; a1 += h1.y; b0 += h2.x; b1v += h2.y;
    }
    if(e < end){
      int s1 = csr[e];
      float2 h1 = ((const float2*)(h + (size_t)s1*D))[lane];
      a0 += h1.x; a1 += h1.y;
    }
    float r0 = fmaxf(fmaf(di, a0 + b0,  bb.x), 0.f);
    float r1 = fmaxf(fmaf(di, a1 + b1v, bb.y), 0.f);
    ((float2*)(out + (size_t)node*D))[lane] = make_float2(r0, r1);
    cs0 += r0; cs1 += r1; cq0 += r0*r0; cq1 += r1*r1;
  }
  __shared__ float lcs[D], lcq[D];
  for(int i = threadIdx.x; i < D; i += blockDim.x){ lcs[i] = 0.f; lcq[i] = 0.f; }
  __syncthreads();
  atomicAdd(&lcs[2*lane],   cs0); atomicAdd(&lcs[2*lane+1], cs1);
  atomicAdd(&lcq[2*lane],   cq0); atomicAdd(&lcq[2*lane+1], cq1);
  __syncthreads();
  for(int i = threadIdx.x; i < D; i += blockDim.x){
    psum[(size_t)blockIdx.x*D + i] = lcs[i];
    psq [(size_t)blockIdx.x*D + i] = lcq[i];
  }
}

// ---------- BN params ----------
__global__ void k_colreduce(const float* __restrict__ psum, const float* __restrict__ psq,
                            int nb, const float* __restrict__ g, const float* __restrict__ be,
                            float* scale, float* shift, int n){
  int c = blockIdx.x;
  float s = 0, q = 0;
  for(int b = threadIdx.x; b < nb; b += blockDim.x){
    s += psum[(size_t)b*D + c]; q += psq[(size_t)b*D + c];
  }
  for(int o = 32; o; o >>= 1){ s += __shfl_xor(s, o); q += __shfl_xor(q, o); }
  __shared__ float ls[4], lq[4];
  int wv = threadIdx.x >> 6;
  if((threadIdx.x & 63) == 0){ ls[wv] = s; lq[wv] = q; }
  __syncthreads();
  if(threadIdx.x == 0){
    float S = ls[0]+ls[1]+ls[2]+ls[3], Q = lq[0]+lq[1]+lq[2]+lq[3];
    float mean = S / n;
    float var  = fmaxf(Q / n - mean*mean, 0.f);
    float sc   = g[c] * rsqrtf(var + 1e-5f);
    scale[c] = sc;
    shift[c] = fmaf(-mean, sc, be[c]);
  }
}

__global__ void k_fold(const float* __restrict__ W, const float* __restrict__ scale,
                       const float* __restrict__ shift, float* Wmod, float* cconst){
  int j = blockIdx.x, k = threadIdx.x;
  float w = W[k*D + j];
  Wmod[k*D + j] = scale[k] * w;
  float sm = shift[k] * w;
  for(int o = 32; o; o >>= 1) sm += __shfl_xor(sm, o);
  __shared__ float l2[2];
  if((k & 63) == 0) l2[k >> 6] = sm;
  __syncthreads();
  if(k == 0) cconst[j] = l2[0] + l2[1];
}

// ---------- semantic table ----------
__global__ void k_sem(const float* __restrict__ emb, const float* __restrict__ Wa,
                      const float* __restrict__ ba, const float* __restrict__ Wf, float* sem){
  int t = threadIdx.x;
  if(t < 32){
    float s = ba[0], q0 = 0, q1 = 0;
    for(int c = 0; c < D; c++){
      float e = emb[t*D + c];
      s  = fmaf(e, Wa[c],     s);
      q0 = fmaf(e, Wf[2*c],   q0);
      q1 = fmaf(e, Wf[2*c+1], q1);
    }
    sem[t] = s; sem[32 + t] = q0; sem[64 + t] = q1;
  }
}

// ---------- spatial branch scores ----------
__global__ void __launch_bounds__(256)
k_spatial(const float* __restrict__ R, const float* __restrict__ scale,
          const float* __restrict__ shift, const float* __restrict__ Wa,
          const float* __restrict__ ba, const float* __restrict__ Wf,
          const int* __restrict__ tt, const float* __restrict__ sem,
          float* s_sp, float* p0_sp, float* p1_sp, unsigned* maxkey, int n){
  int lane = threadIdx.x & 63;
  int wid  = (blockIdx.x*blockDim.x + threadIdx.x) >> 6;
  int nw   = (gridDim.x*blockDim.x) >> 6;
  float2 sc = ((const float2*)scale)[lane];
  float2 sh = ((const float2*)shift)[lane];
  float2 wa = ((const float2*)Wa)[lane];
  float4 wf = ((const float4*)Wf)[lane];
  float ba0 = ba[0];
  float mloc = -INFINITY, msem = -INFINITY;
  for(int node = wid; node < n; node += nw){
    float2 v = ((const float2*)(R + (size_t)node*D))[lane];
    float v0 = fmaf(v.x, sc.x, sh.x);
    float v1 = fmaf(v.y, sc.y, sh.y);
    float s  = v0*wa.x + v1*wa.y;
    float p0 = v0*wf.x + v1*wf.z;
    float p1 = v0*wf.y + v1*wf.w;
    for(int o = 32; o; o >>= 1){
      s += __shfl_xor(s, o); p0 += __shfl_xor(p0, o); p1 += __shfl_xor(p1, o);
    }
    s += ba0;
    if(lane == 0){ s_sp[node] = s; p0_sp[node] = p0; p1_sp[node] = p1; }
    mloc = fmaxf(mloc, s);
    msem = fmaxf(msem, sem[tt[node]]);
  }
  __shared__ float lm[4], lsm[4];
  int wv = threadIdx.x >> 6;
  if(lane == 0){ lm[wv] = mloc; lsm[wv] = msem; }
  __syncthreads();
  if(threadIdx.x == 0){
    float M  = fmaxf(fmaxf(lm[0], lm[1]),  fmaxf(lm[2], lm[3]));
    float M2 = fmaxf(fmaxf(lsm[0], lsm[1]), fmaxf(lsm[2], lsm[3]));
    atomicMax(&maxkey[0], fkey(M));
    atomicMax(&maxkey[2], fkey(M2));
  }
}

// ---------- softmax denominators ----------
__global__ void k_zsum(const float* __restrict__ s_sp, const float* __restrict__ s_te,
                       const int* __restrict__ tt, const float* __restrict__ sem,
                       Scal* sc, int n){
  float M0 = fdec(sc->maxkey[0]), M1 = fdec(sc->maxkey[1]), M2 = fdec(sc->maxkey[2]);
  int i = blockIdx.x*blockDim.x + threadIdx.x;
  int stride = gridDim.x*blockDim.x;
  float z0 = 0, z1 = 0, z2 = 0;
  for(; i < n; i += stride){
    z0 += expf(s_sp[i] - M0);
    z1 += expf(s_te[i] - M1);
    z2 += expf(sem[tt[i]] - M2);
  }
  for(int o = 32; o; o >>= 1){
    z0 += __shfl_xor(z0, o); z1 += __shfl_xor(z1, o); z2 += __shfl_xor(z2, o);
  }
  __shared__ float l0[4], l1[4], l2[4];
  int wv = threadIdx.x >> 6;
  if((threadIdx.x & 63) == 0){ l0[wv] = z0; l1[wv] = z1; l2[wv] = z2; }
  __syncthreads();
  if(threadIdx.x == 0){
    atomAddF(&sc->Z[0], l0[0]+l0[1]+l0[2]+l0[3]);
    atomAddF(&sc->Z[1], l1[0]+l1[1]+l1[2]+l1[3]);
    atomAddF(&sc->Z[2], l2[0]+l2[1]+l2[2]+l2[3]);
  }
}

// ---------- final combine ----------
__global__ void k_final(const float* __restrict__ s_sp, const float* __restrict__ p0_sp,
                        const float* __restrict__ p1_sp, const float* __restrict__ s_te,
                        const float* __restrict__ p0_te, const float* __restrict__ p1_te,
                        const int* __restrict__ tt, const float* __restrict__ sem,
                        const Scal* sc, const float* __restrict__ bf,
                        float* __restrict__ out, int n){
  int i = blockIdx.x*blockDim.x + threadIdx.x;
  if(i < n){
    float M0 = fdec(sc->maxkey[0]), M1 = fdec(sc->maxkey[1]), M2 = fdec(sc->maxkey[2]);
    float w0 = expf(s_sp[i] - M0) / sc->Z[0];
    float w1 = expf(s_te[i] - M1) / sc->Z[1];
    int t = tt[i];
    float w2 = expf(sem[t] - M2) / sc->Z[2];
    float o0 = w0*p0_sp[i] + w1*p0_te[i] + w2*sem[32 + t] + bf[0];
    float o1 = w0*p1_sp[i] + w1*p1_te[i] + w2*sem[64 + t] + bf[1];
    ((float2*)out)[i] = make_float2(o0, o1);
  }
}

extern "C" void kernel_launch(void* const* d_in, const int* in_sizes, int n_in,
                              void* d_out, int out_size, void* d_ws, size_t ws_size,
                              hipStream_t stream) {
  const int N = in_sizes[5];   // timestamps
  const int E = in_sizes[1];   // src

  const float* x   = (const float*)d_in[0];
  const int*   src = (const int*)  d_in[1];
  const int*   dst = (const int*)  d_in[2];
  const float* ea  = (const float*)d_in[3];
  const int*   tt  = (const int*)  d_in[4];
  const float* W1  = (const float*)d_in[6];  const float* b1 = (const float*)d_in[7];
  const float* W2  = (const float*)d_in[8];  const float* b2 = (const float*)d_in[9];
  const float* W3  = (const float*)d_in[10]; const float* b3 = (const float*)d_in[11];
  const float* Wt  = (const float*)d_in[12]; const float* bt = (const float*)d_in[13];
  const float* emb = (const float*)d_in[14];
  const float* Wa  = (const float*)d_in[15]; const float* ba = (const float*)d_in[16];
  const float* g1  = (const float*)d_in[17]; const float* be1= (const float*)d_in[18];
  const float* g2  = (const float*)d_in[19]; const float* be2= (const float*)d_in[20];
  const float* g3  = (const float*)d_in[21]; const float* be3= (const float*)d_in[22];
  const float* Wf  = (const float*)d_in[23]; const float* bf = (const float*)d_in[24];
  float* out = (float*)d_out;

  char* w = (char*)d_ws;
  size_t off = 0;
  auto take = [&](size_t bytes) -> char* {
    char* p = w + off;
    off = (off + bytes + 255) & ~(size_t)255;
    return p;
  };

  const int NB_AGG = 2048, NB_SP = 2048, NB_Z = 1024, NB_E = 2048;

  float* bufA    = (float*)take((size_t)N*D*4);
  float* bufB    = (float*)take((size_t)N*D*4);
  int*   csr     = (int*)  take((size_t)E*4);
  float* csrv    = (float*)take((size_t)E*4);
  int*   offsets = (int*)  take((size_t)(N+1)*4);
  float* dinv    = (float*)take((size_t)N*4);
  int*   blockSum= (int*)  take((size_t)SCAN_B*4);
  float* s_sp    = (float*)take((size_t)N*4);
  float* p0_sp   = (float*)take((size_t)N*4);
  float* p1_sp   = (float*)take((size_t)N*4);
  float* s_te    = (float*)take((size_t)N*4);
  float* p0_te   = (float*)take((size_t)N*4);
  float* p1_te   = (float*)take((size_t)N*4);
  float* td      = (float*)take((size_t)N*4);
  float* psum    = (float*)take((size_t)NB_AGG*D*4);
  float* psq     = (float*)take((size_t)NB_AGG*D*4);
  float* Wmod    = (float*)take((size_t)D*D*4);
  float* cconst  = (float*)take((size_t)D*4);
  float* scaleb  = (float*)take((size_t)D*4);
  float* shiftb  = (float*)take((size_t)D*4);
  float* sem     = (float*)take((size_t)96*4);
  // --- zero-init region (contiguous) ---
  Scal* sc     = (Scal*)take(sizeof(Scal));
  int*  indeg  = (int*) take((size_t)N*4);
  int*  cursor = (int*) take((size_t)N*4);
  unsigned long long* outAcc = (unsigned long long*)take((size_t)N*8);
  size_t zbytes = (size_t)((w + off) - (char*)sc);
  hipMemsetAsync(sc, 0, zbytes, stream);

  int gE = (E + 255) / 256;
  int gN = (N + 255) / 256;
  int gT = (N + BN - 1) / BN;

  // fused edge pass: indeg hist + out-side packed (count,sum) + edge stats
  k_edge1<<<NB_E, 256, 0, stream>>>(src, dst, ea, indeg, outAcc, sc, E);
  k_efin<<<1, 1, 0, stream>>>(sc, E);
  // offsets + dinv
  k_scan1<<<SCAN_B, SCAN_T, 0, stream>>>(indeg, blockSum, N);
  k_scan2<<<1, SCAN_B, 0, stream>>>(blockSum);
  k_scan3<<<SCAN_B, SCAN_T, 0, stream>>>(indeg, blockSum, offsets, dinv, N);
  // CSR fill (index + value)
  k_fill<<<gE, 256, 0, stream>>>(src, dst, ea, offsets, cursor, csr, csrv, E);
  // td gather
  k_td2<<<gN, 256, 0, stream>>>(offsets, csrv, outAcc, sc, td, N);

  // layer 1
  k_gemm<<<gT, 256, 0, stream>>>(x, W1, nullptr, dinv, bufA, N);
  k_agg<<<NB_AGG, 256, 0, stream>>>(bufA, offsets, csr, dinv, b1, bufB, psum, psq, N);
  k_colreduce<<<D, 256, 0, stream>>>(psum, psq, NB_AGG, g1, be1, scaleb, shiftb, N);
  k_fold<<<D, D, 0, stream>>>(W2, scaleb, shiftb, Wmod, cconst);
  // layer 2
  k_gemm<<<gT, 256, 0, stream>>>(bufB, Wmod, cconst, dinv, bufA, N);
  k_agg<<<NB_AGG, 256, 0, stream>>>(bufA, offsets, csr, dinv, b2, bufB, psum, psq, N);
  k_colreduce<<<D, 256, 0, stream>>>(psum, psq, NB_AGG, g2, be2, scaleb, shiftb, N);
  k_fold<<<D, D, 0, stream>>>(W3, scaleb, shiftb, Wmod, cconst);
  // layer 3
  k_gemm<<<gT, 256, 0, stream>>>(bufB, Wmod, cconst, dinv, bufA, N);
  k_agg<<<NB_AGG, 256, 0, stream>>>(bufA, offsets, csr, dinv, b3, bufB, psum, psq, N);
  k_colreduce<<<D, 256, 0, stream>>>(psum, psq, NB_AGG, g3, be3, scaleb, shiftb, N);

  // branches
  k_sem<<<1, 64, 0, stream>>>(emb, Wa, ba, Wf, sem);
  k_spatial<<<NB_SP, 256, 0, stream>>>(bufB, scaleb, shiftb, Wa, ba, Wf, tt, sem,
                                       s_sp, p0_sp, p1_sp, sc->maxkey, N);
  k_temporal<<<gT, 256, 0, stream>>>(x, td, Wt, bt, Wa, ba, Wf,
                                     s_te, p0_te, p1_te, sc->maxkey, N);
  // softmax + combine
  k_zsum<<<NB_Z, 256, 0, stream>>>(s_sp, s_te, tt, sem, sc, N);
  k_final<<<gN, 256, 0, stream>>>(s_sp, p0_sp, p1_sp, s_te, p0_te, p1_te,
                                  tt, sem, sc, bf, out, N);
}

// Round 6
// 1136.367 us; speedup vs baseline: 2.0836x; 1.0598x over previous
//
#include <hip/hip_runtime.h>
#include <math.h>

#define D   128
#define WAVE 64

// GEMM tiling
#define BN  128
#define KP  32
#define TN  8
#define TJ  8
#define XSTR (BN + 4)

// scan config
#define SCAN_B 256
#define SCAN_T 256

#define MASK44 ((1ULL<<44) - 1)

struct Scal {
  double esum, esumsq;     // zero-init
  unsigned maxkey[3];      // zero-init (decodes below all finite)
  float Z[3];              // zero-init
  float emean, einv;       // written by k_efin
};

__device__ __forceinline__ unsigned fkey(float f){
  unsigned b = __float_as_uint(f);
  return (b & 0x80000000u) ? ~b : (b | 0x80000000u);
}
__device__ __forceinline__ float fdec(unsigned k){
  return (k & 0x80000000u) ? __uint_as_float(k & 0x7fffffffu) : __uint_as_float(~k);
}
__device__ __forceinline__ void atomAddF(float* p, float v){
  __hip_atomic_fetch_add(p, v, __ATOMIC_RELAXED, __HIP_MEMORY_SCOPE_AGENT);
}
__device__ __forceinline__ void atomAddD(double* p, double v){
  __hip_atomic_fetch_add(p, v, __ATOMIC_RELAXED, __HIP_MEMORY_SCOPE_AGENT);
}

// ---------- fused edge pass 1: indeg hist + packed out-side (count,sum) + edge stats ----------
__global__ void __launch_bounds__(256)
k_edge1(const int* __restrict__ src, const int* __restrict__ dst,
        const float* __restrict__ ea, int* __restrict__ indeg,
        unsigned long long* __restrict__ outAcc, Scal* sc, int E){
  int i = blockIdx.x*blockDim.x + threadIdx.x;
  int stride = gridDim.x*blockDim.x;
  double s = 0.0, q = 0.0;
  for(; i < E; i += stride){
    float v = fminf(fmaxf(ea[i], -1000.f), 1000.f);
    s += (double)v; q += (double)v * (double)v;
    atomicAdd(&indeg[dst[i]], 1);
    unsigned long long pk = (1ULL<<44) +
        (unsigned long long)(long long)((double)(v + 1024.0) * 1048576.0 + 0.5);
    atomicAdd(&outAcc[src[i]], pk);
  }
  for(int o = 32; o; o >>= 1){ s += __shfl_xor(s, o); q += __shfl_xor(q, o); }
  __shared__ double ls[4], lq[4];
  int wv = threadIdx.x >> 6;
  if((threadIdx.x & 63) == 0){ ls[wv] = s; lq[wv] = q; }
  __syncthreads();
  if(threadIdx.x == 0){
    double S = ls[0]+ls[1]+ls[2]+ls[3], Q = lq[0]+lq[1]+lq[2]+lq[3];
    atomAddD(&sc->esum, S); atomAddD(&sc->esumsq, Q);
  }
}

__global__ void k_efin(Scal* sc, int E){
  double mean = sc->esum / E;
  double var  = (sc->esumsq - sc->esum*sc->esum/E) / (double)(E - 1);
  double sd   = sqrt(var > 0.0 ? var : 0.0);
  sc->emean = (float)mean;
  sc->einv  = (float)(1.0 / (sd + 1e-9));
}

// ---------- hierarchical scan ----------
__global__ void __launch_bounds__(SCAN_T)
k_scan1(const int* __restrict__ indeg, int* __restrict__ blockSum, int n){
  int tile  = (n + SCAN_B - 1) / SCAN_B;
  int start = blockIdx.x * tile;
  int end   = min(start + tile, n);
  int s = 0;
  for(int i = start + threadIdx.x; i < end; i += SCAN_T) s += indeg[i];
  #pragma unroll
  for(int o = 32; o; o >>= 1) s += __shfl_xor(s, o);
  __shared__ int ls[4];
  if((threadIdx.x & 63) == 0) ls[threadIdx.x >> 6] = s;
  __syncthreads();
  if(threadIdx.x == 0) blockSum[blockIdx.x] = ls[0]+ls[1]+ls[2]+ls[3];
}

__global__ void __launch_bounds__(SCAN_B)
k_scan2(int* blockSum){
  __shared__ int tmp[SCAN_B];
  int t = threadIdx.x;
  tmp[t] = blockSum[t];
  __syncthreads();
  for(int o = 1; o < SCAN_B; o <<= 1){
    int v = (t >= o) ? tmp[t-o] : 0;
    __syncthreads();
    tmp[t] += v;
    __syncthreads();
  }
  blockSum[t] = (t == 0) ? 0 : tmp[t-1];
}

__global__ void __launch_bounds__(SCAN_T)
k_scan3(const int* __restrict__ indeg, const int* __restrict__ blockSum,
        int* __restrict__ offsets, float* __restrict__ dinv, int n){
  int tile  = (n + SCAN_B - 1) / SCAN_B;
  int start = blockIdx.x * tile;
  int end   = min(start + tile, n);
  int chunk = (tile + SCAN_T - 1) / SCAN_T;
  int t = threadIdx.x;
  int tstart = start + t * chunk;
  int tend   = min(tstart + chunk, end);
  int s = 0;
  for(int i = tstart; i < tend; i++) s += indeg[i];
  __shared__ int tmp[SCAN_T];
  tmp[t] = s;
  __syncthreads();
  for(int o = 1; o < SCAN_T; o <<= 1){
    int v = (t >= o) ? tmp[t-o] : 0;
    __syncthreads();
    tmp[t] += v;
    __syncthreads();
  }
  int run = blockSum[blockIdx.x] + ((t == 0) ? 0 : tmp[t-1]);
  for(int i = tstart; i < tend; i++){
    int dg = indeg[i];
    offsets[i] = run;
    run += dg;
    dinv[i] = rsqrtf((float)(dg + 1));
  }
  if(blockIdx.x == SCAN_B-1 && t == SCAN_T-1) offsets[n] = run;
}

// ---------- CSR fill: src index + clipped edge value ----------
__global__ void k_fill(const int* __restrict__ src, const int* __restrict__ dst,
                       const float* __restrict__ ea,
                       const int* __restrict__ offsets, int* cursor,
                       int* __restrict__ csr, float* __restrict__ csrv, int E){
  int e = blockIdx.x*blockDim.x + threadIdx.x;
  if(e < E){
    int d = dst[e];
    int pos = atomicAdd(&cursor[d], 1);
    int slot = offsets[d] + pos;
    csr[slot]  = src[e];
    csrv[slot] = fminf(fmaxf(ea[e], -1000.f), 1000.f);
  }
}

// ---------- td from CSR gather + packed out accumulator ----------
__global__ void k_td2(const int* __restrict__ offsets, const float* __restrict__ csrv,
                      const unsigned long long* __restrict__ outAcc,
                      const Scal* sc, float* __restrict__ td, int n){
  int i = blockIdx.x*blockDim.x + threadIdx.x;
  if(i < n){
    int o0 = offsets[i], o1 = offsets[i+1];
    float S_in = 0.f;
    for(int e = o0; e < o1; e++) S_in += csrv[e];
    unsigned long long acc = outAcc[i];
    int cout = (int)(acc >> 44);
    double S_out = (double)(acc & MASK44) * (1.0/1048576.0) - 1024.0 * (double)cout;
    int deg = (o1 - o0) + cout;
    float S = S_in + (float)S_out;
    float tdv = (S - sc->emean * (float)deg) * sc->einv / fmaxf((float)deg, 1.f);
    td[i] = tdv;
  }
}

// ---------- register-tiled GEMM: out[node,:] = dinv[node]*(A[node,:]@W + cvec) ----------
__global__ void __launch_bounds__(256)
k_gemm(const float* __restrict__ A, const float* __restrict__ W,
       const float* __restrict__ cvec, const float* __restrict__ dinv,
       float* __restrict__ out, int n){
  __shared__ float xs[KP][XSTR];
  __shared__ float ws[KP][D];
  const int t  = threadIdx.x;
  const int jg = t & 15, ng = t >> 4;
  const int j0 = jg * TJ, n0 = ng * TN;
  const int nodeBase = blockIdx.x * BN;

  float cr[TJ];
  if(cvec){
    float4 c0 = *(const float4*)(cvec + j0);
    float4 c1 = *(const float4*)(cvec + j0 + 4);
    cr[0]=c0.x; cr[1]=c0.y; cr[2]=c0.z; cr[3]=c0.w;
    cr[4]=c1.x; cr[5]=c1.y; cr[6]=c1.z; cr[7]=c1.w;
  } else {
    #pragma unroll
    for(int j=0;j<TJ;j++) cr[j]=0.f;
  }
  float acc[TN][TJ];
  #pragma unroll
  for(int i=0;i<TN;i++)
    #pragma unroll
    for(int j=0;j<TJ;j++) acc[i][j]=cr[j];

  for(int p=0;p<D/KP;p++){
    {
      const float4* Wp = (const float4*)(W + (size_t)p*KP*D);
      float4* ws4 = (float4*)ws;
      ws4[t]       = Wp[t];
      ws4[t + 256] = Wp[t + 256];
      ws4[t + 512] = Wp[t + 512];
      ws4[t + 768] = Wp[t + 768];
    }
    #pragma unroll
    for(int q=0;q<4;q++){
      int idx = t + q*256;
      int node = idx >> 3, kq = idx & 7;
      int gn = nodeBase + node; if(gn >= n) gn = n-1;
      float4 v = *(const float4*)(A + (size_t)gn*D + p*KP + kq*4);
      xs[kq*4+0][node] = v.x; xs[kq*4+1][node] = v.y;
      xs[kq*4+2][node] = v.z; xs[kq*4+3][node] = v.w;
    }
    __syncthreads();
    #pragma unroll 4
    for(int k=0;k<KP;k++){
      float4 xa = *(const float4*)&xs[k][n0];
      float4 xb = *(const float4*)&xs[k][n0+4];
      float4 wa = *(const float4*)&ws[k][j0];
      float4 wb = *(const float4*)&ws[k][j0+4];
      float xv[8] = {xa.x,xa.y,xa.z,xa.w,xb.x,xb.y,xb.z,xb.w};
      float wv[8] = {wa.x,wa.y,wa.z,wa.w,wb.x,wb.y,wb.z,wb.w};
      #pragma unroll
      for(int i=0;i<TN;i++)
        #pragma unroll
        for(int j=0;j<TJ;j++)
          acc[i][j] = fmaf(xv[i], wv[j], acc[i][j]);
    }
    __syncthreads();
  }
  #pragma unroll
  for(int i=0;i<TN;i++){
    int gn = nodeBase + n0 + i;
    if(gn < n){
      float d = dinv[gn];
      float4 o0 = make_float4(acc[i][0]*d, acc[i][1]*d, acc[i][2]*d, acc[i][3]*d);
      float4 o1 = make_float4(acc[i][4]*d, acc[i][5]*d, acc[i][6]*d, acc[i][7]*d);
      *(float4*)(out + (size_t)gn*D + j0)     = o0;
      *(float4*)(out + (size_t)gn*D + j0 + 4) = o1;
    }
  }
}

// ---------- temporal branch ----------
__global__ void __launch_bounds__(256)
k_temporal(const float* __restrict__ x, const float* __restrict__ td,
           const float* __restrict__ Wt, const float* __restrict__ bt,
           const float* __restrict__ Wa, const float* __restrict__ ba,
           const float* __restrict__ Wf,
           float* s_te, float* p0_te, float* p1_te, unsigned* maxkey, int n){
  __shared__ float xs[KP][XSTR];
  __shared__ float ws[KP][D];
  __shared__ unsigned mk;
  const int t  = threadIdx.x;
  const int jg = t & 15, ng = t >> 4;
  const int j0 = jg * TJ, n0 = ng * TN;
  const int nodeBase = blockIdx.x * BN;
  if(t == 0) mk = 0;

  float acc[TN][TJ];
  #pragma unroll
  for(int i=0;i<TN;i++)
    #pragma unroll
    for(int j=0;j<TJ;j++) acc[i][j]=0.f;

  for(int p=0;p<D/KP;p++){
    {
      const float4* Wp = (const float4*)(Wt + (size_t)p*KP*D);
      float4* ws4 = (float4*)ws;
      ws4[t]       = Wp[t];
      ws4[t + 256] = Wp[t + 256];
      ws4[t + 512] = Wp[t + 512];
      ws4[t + 768] = Wp[t + 768];
    }
    #pragma unroll
    for(int q=0;q<4;q++){
      int idx = t + q*256;
      int node = idx >> 3, kq = idx & 7;
      int gn = nodeBase + node; if(gn >= n) gn = n-1;
      float4 v = *(const float4*)(x + (size_t)gn*D + p*KP + kq*4);
      xs[kq*4+0][node] = v.x; xs[kq*4+1][node] = v.y;
      xs[kq*4+2][node] = v.z; xs[kq*4+3][node] = v.w;
    }
    __syncthreads();
    #pragma unroll 4
    for(int k=0;k<KP;k++){
      float4 xa = *(const float4*)&xs[k][n0];
      float4 xb = *(const float4*)&xs[k][n0+4];
      float4 wa = *(const float4*)&ws[k][j0];
      float4 wb = *(const float4*)&ws[k][j0+4];
      float xv[8] = {xa.x,xa.y,xa.z,xa.w,xb.x,xb.y,xb.z,xb.w};
      float wv[8] = {wa.x,wa.y,wa.z,wa.w,wb.x,wb.y,wb.z,wb.w};
      #pragma unroll
      for(int i=0;i<TN;i++)
        #pragma unroll
        for(int j=0;j<TJ;j++)
          acc[i][j] = fmaf(xv[i], wv[j], acc[i][j]);
    }
    __syncthreads();
  }
  float wl[TJ], bb[TJ], wa8[TJ], wf0[TJ], wf1[TJ];
  #pragma unroll
  for(int j=0;j<TJ;j++){
    wl[j]  = Wt[(size_t)D*D + j0 + j];
    bb[j]  = bt[j0 + j];
    wa8[j] = Wa[j0 + j];
    float2 w2 = ((const float2*)Wf)[j0 + j];
    wf0[j] = w2.x; wf1[j] = w2.y;
  }
  float ba0 = ba[0];
  float mloc = -INFINITY;
  #pragma unroll
  for(int i=0;i<TN;i++){
    int gn = nodeBase + n0 + i;
    float tdv = (gn < n) ? td[gn] : 0.f;
    float s = 0.f, p0 = 0.f, p1 = 0.f;
    #pragma unroll
    for(int j=0;j<TJ;j++){
      float tj = fmaxf(acc[i][j] + tdv*wl[j] + bb[j], 0.f);
      s  = fmaf(tj, wa8[j], s);
      p0 = fmaf(tj, wf0[j], p0);
      p1 = fmaf(tj, wf1[j], p1);
    }
    #pragma unroll
    for(int o=8;o;o>>=1){
      s += __shfl_xor(s, o); p0 += __shfl_xor(p0, o); p1 += __shfl_xor(p1, o);
    }
    if(jg == 0 && gn < n){
      s += ba0;
      s_te[gn] = s; p0_te[gn] = p0; p1_te[gn] = p1;
      mloc = fmaxf(mloc, s);
    }
  }
  __syncthreads();
  if(jg == 0) atomicMax(&mk, fkey(mloc));
  __syncthreads();
  if(t == 0) atomicMax(&maxkey[1], mk);
}

// ---------- aggregation: 16 lanes per node, 4 nodes/wave, 4-way MLP ----------
__global__ void __launch_bounds__(256)
k_agg(const float* __restrict__ h, const int* __restrict__ offsets,
      const int* __restrict__ csr, const float* __restrict__ dinv,
      const float* __restrict__ bias, float* __restrict__ out,
      float* __restrict__ psum, float* __restrict__ psq, int n){
  const int l   = threadIdx.x & 15;        // lane within group
  const int grp = threadIdx.x >> 4;        // group within block (0..15)
  const int gg  = blockIdx.x * 16 + grp;   // global group id
  const int ngg = gridDim.x * 16;
  const int c0  = l * 8;                   // first owned channel

  float4 bb0 = *(const float4*)(bias + c0);
  float4 bb1 = *(const float4*)(bias + c0 + 4);
  float bbv[8] = {bb0.x,bb0.y,bb0.z,bb0.w,bb1.x,bb1.y,bb1.z,bb1.w};

  float bs[8] = {0,0,0,0,0,0,0,0};
  float bq[8] = {0,0,0,0,0,0,0,0};

  for(int node = gg; node < n; node += ngg){
    int off = offsets[node], end = offsets[node+1];
    float di = dinv[node];
    const float* hr = h + (size_t)node*D + c0;
    float4 s0 = *(const float4*)hr;
    float4 s1 = *(const float4*)(hr+4);
    float aa[8] = {s0.x,s0.y,s0.z,s0.w,s1.x,s1.y,s1.z,s1.w};
    float ab[8] = {0,0,0,0,0,0,0,0};
    float ac[8] = {0,0,0,0,0,0,0,0};
    float ad[8] = {0,0,0,0,0,0,0,0};
    int e = off;
    for(; e + 3 < end; e += 4){
      const float* h0 = h + (size_t)csr[e]*D   + c0;
      const float* h1 = h + (size_t)csr[e+1]*D + c0;
      const float* h2 = h + (size_t)csr[e+2]*D + c0;
      const float* h3 = h + (size_t)csr[e+3]*D + c0;
      float4 v00 = *(const float4*)h0, v01 = *(const float4*)(h0+4);
      float4 v10 = *(const float4*)h1, v11 = *(const float4*)(h1+4);
      float4 v20 = *(const float4*)h2, v21 = *(const float4*)(h2+4);
      float4 v30 = *(const float4*)h3, v31 = *(const float4*)(h3+4);
      aa[0]+=v00.x; aa[1]+=v00.y; aa[2]+=v00.z; aa[3]+=v00.w;
      aa[4]+=v01.x; aa[5]+=v01.y; aa[6]+=v01.z; aa[7]+=v01.w;
      ab[0]+=v10.x; ab[1]+=v10.y; ab[2]+=v10.z; ab[3]+=v10.w;
      ab[4]+=v11.x; ab[5]+=v11.y; ab[6]+=v11.z; ab[7]+=v11.w;
      ac[0]+=v20.x; ac[1]+=v20.y; ac[2]+=v20.z; ac[3]+=v20.w;
      ac[4]+=v21.x; ac[5]+=v21.y; ac[6]+=v21.z; ac[7]+=v21.w;
      ad[0]+=v30.x; ad[1]+=v30.y; ad[2]+=v30.z; ad[3]+=v30.w;
      ad[4]+=v31.x; ad[5]+=v31.y; ad[6]+=v31.z; ad[7]+=v31.w;
    }
    for(; e < end; e++){
      const float* h0 = h + (size_t)csr[e]*D + c0;
      float4 v00 = *(const float4*)h0, v01 = *(const float4*)(h0+4);
      aa[0]+=v00.x; aa[1]+=v00.y; aa[2]+=v00.z; aa[3]+=v00.w;
      aa[4]+=v01.x; aa[5]+=v01.y; aa[6]+=v01.z; aa[7]+=v01.w;
    }
    float r[8];
    #pragma unroll
    for(int j=0;j<8;j++){
      r[j] = fmaxf(fmaf(di, aa[j]+ab[j]+ac[j]+ad[j], bbv[j]), 0.f);
      bs[j] += r[j];
      bq[j] += r[j]*r[j];
    }
    float* orow = out + (size_t)node*D + c0;
    *(float4*)orow     = make_float4(r[0],r[1],r[2],r[3]);
    *(float4*)(orow+4) = make_float4(r[4],r[5],r[6],r[7]);
  }

  // block-level BN partial reduce: 16 groups x 128 channels
  __shared__ float red[16][D];
  #pragma unroll
  for(int j=0;j<8;j++) red[grp][c0+j] = bs[j];
  __syncthreads();
  if(threadIdx.x < D){
    float s = 0.f;
    #pragma unroll
    for(int g=0;g<16;g++) s += red[g][threadIdx.x];
    psum[(size_t)blockIdx.x*D + threadIdx.x] = s;
  }
  __syncthreads();
  #pragma unroll
  for(int j=0;j<8;j++) red[grp][c0+j] = bq[j];
  __syncthreads();
  if(threadIdx.x < D){
    float s = 0.f;
    #pragma unroll
    for(int g=0;g<16;g++) s += red[g][threadIdx.x];
    psq[(size_t)blockIdx.x*D + threadIdx.x] = s;
  }
}

// ---------- BN params ----------
__global__ void k_colreduce(const float* __restrict__ psum, const float* __restrict__ psq,
                            int nb, const float* __restrict__ g, const float* __restrict__ be,
                            float* scale, float* shift, int n){
  int c = blockIdx.x;
  float s = 0, q = 0;
  for(int b = threadIdx.x; b < nb; b += blockDim.x){
    s += psum[(size_t)b*D + c]; q += psq[(size_t)b*D + c];
  }
  for(int o = 32; o; o >>= 1){ s += __shfl_xor(s, o); q += __shfl_xor(q, o); }
  __shared__ float ls[4], lq[4];
  int wv = threadIdx.x >> 6;
  if((threadIdx.x & 63) == 0){ ls[wv] = s; lq[wv] = q; }
  __syncthreads();
  if(threadIdx.x == 0){
    float S = ls[0]+ls[1]+ls[2]+ls[3], Q = lq[0]+lq[1]+lq[2]+lq[3];
    float mean = S / n;
    float var  = fmaxf(Q / n - mean*mean, 0.f);
    float sc   = g[c] * rsqrtf(var + 1e-5f);
    scale[c] = sc;
    shift[c] = fmaf(-mean, sc, be[c]);
  }
}

__global__ void k_fold(const float* __restrict__ W, const float* __restrict__ scale,
                       const float* __restrict__ shift, float* Wmod, float* cconst){
  int j = blockIdx.x, k = threadIdx.x;
  float w = W[k*D + j];
  Wmod[k*D + j] = scale[k] * w;
  float sm = shift[k] * w;
  for(int o = 32; o; o >>= 1) sm += __shfl_xor(sm, o);
  __shared__ float l2[2];
  if((k & 63) == 0) l2[k >> 6] = sm;
  __syncthreads();
  if(k == 0) cconst[j] = l2[0] + l2[1];
}

// ---------- semantic table ----------
__global__ void k_sem(const float* __restrict__ emb, const float* __restrict__ Wa,
                      const float* __restrict__ ba, const float* __restrict__ Wf, float* sem){
  int t = threadIdx.x;
  if(t < 32){
    float s = ba[0], q0 = 0, q1 = 0;
    for(int c = 0; c < D; c++){
      float e = emb[t*D + c];
      s  = fmaf(e, Wa[c],     s);
      q0 = fmaf(e, Wf[2*c],   q0);
      q1 = fmaf(e, Wf[2*c+1], q1);
    }
    sem[t] = s; sem[32 + t] = q0; sem[64 + t] = q1;
  }
}

// ---------- spatial branch scores ----------
__global__ void __launch_bounds__(256)
k_spatial(const float* __restrict__ R, const float* __restrict__ scale,
          const float* __restrict__ shift, const float* __restrict__ Wa,
          const float* __restrict__ ba, const float* __restrict__ Wf,
          const int* __restrict__ tt, const float* __restrict__ sem,
          float* s_sp, float* p0_sp, float* p1_sp, unsigned* maxkey, int n){
  int lane = threadIdx.x & 63;
  int wid  = (blockIdx.x*blockDim.x + threadIdx.x) >> 6;
  int nw   = (gridDim.x*blockDim.x) >> 6;
  float2 sc = ((const float2*)scale)[lane];
  float2 sh = ((const float2*)shift)[lane];
  float2 wa = ((const float2*)Wa)[lane];
  float4 wf = ((const float4*)Wf)[lane];
  float ba0 = ba[0];
  float mloc = -INFINITY, msem = -INFINITY;
  for(int node = wid; node < n; node += nw){
    float2 v = ((const float2*)(R + (size_t)node*D))[lane];
    float v0 = fmaf(v.x, sc.x, sh.x);
    float v1 = fmaf(v.y, sc.y, sh.y);
    float s  = v0*wa.x + v1*wa.y;
    float p0 = v0*wf.x + v1*wf.z;
    float p1 = v0*wf.y + v1*wf.w;
    for(int o = 32; o; o >>= 1){
      s += __shfl_xor(s, o); p0 += __shfl_xor(p0, o); p1 += __shfl_xor(p1, o);
    }
    s += ba0;
    if(lane == 0){ s_sp[node] = s; p0_sp[node] = p0; p1_sp[node] = p1; }
    mloc = fmaxf(mloc, s);
    msem = fmaxf(msem, sem[tt[node]]);
  }
  __shared__ float lm[4], lsm[4];
  int wv = threadIdx.x >> 6;
  if(lane == 0){ lm[wv] = mloc; lsm[wv] = msem; }
  __syncthreads();
  if(threadIdx.x == 0){
    float M  = fmaxf(fmaxf(lm[0], lm[1]),  fmaxf(lm[2], lm[3]));
    float M2 = fmaxf(fmaxf(lsm[0], lsm[1]), fmaxf(lsm[2], lsm[3]));
    atomicMax(&maxkey[0], fkey(M));
    atomicMax(&maxkey[2], fkey(M2));
  }
}

// ---------- softmax denominators ----------
__global__ void k_zsum(const float* __restrict__ s_sp, const float* __restrict__ s_te,
                       const int* __restrict__ tt, const float* __restrict__ sem,
                       Scal* sc, int n){
  float M0 = fdec(sc->maxkey[0]), M1 = fdec(sc->maxkey[1]), M2 = fdec(sc->maxkey[2]);
  int i = blockIdx.x*blockDim.x + threadIdx.x;
  int stride = gridDim.x*blockDim.x;
  float z0 = 0, z1 = 0, z2 = 0;
  for(; i < n; i += stride){
    z0 += expf(s_sp[i] - M0);
    z1 += expf(s_te[i] - M1);
    z2 += expf(sem[tt[i]] - M2);
  }
  for(int o = 32; o; o >>= 1){
    z0 += __shfl_xor(z0, o); z1 += __shfl_xor(z1, o); z2 += __shfl_xor(z2, o);
  }
  __shared__ float l0[4], l1[4], l2[4];
  int wv = threadIdx.x >> 6;
  if((threadIdx.x & 63) == 0){ l0[wv] = z0; l1[wv] = z1; l2[wv] = z2; }
  __syncthreads();
  if(threadIdx.x == 0){
    atomAddF(&sc->Z[0], l0[0]+l0[1]+l0[2]+l0[3]);
    atomAddF(&sc->Z[1], l1[0]+l1[1]+l1[2]+l1[3]);
    atomAddF(&sc->Z[2], l2[0]+l2[1]+l2[2]+l2[3]);
  }
}

// ---------- final combine ----------
__global__ void k_final(const float* __restrict__ s_sp, const float* __restrict__ p0_sp,
                        const float* __restrict__ p1_sp, const float* __restrict__ s_te,
                        const float* __restrict__ p0_te, const float* __restrict__ p1_te,
                        const int* __restrict__ tt, const float* __restrict__ sem,
                        const Scal* sc, const float* __restrict__ bf,
                        float* __restrict__ out, int n){
  int i = blockIdx.x*blockDim.x + threadIdx.x;
  if(i < n){
    float M0 = fdec(sc->maxkey[0]), M1 = fdec(sc->maxkey[1]), M2 = fdec(sc->maxkey[2]);
    float w0 = expf(s_sp[i] - M0) / sc->Z[0];
    float w1 = expf(s_te[i] - M1) / sc->Z[1];
    int t = tt[i];
    float w2 = expf(sem[t] - M2) / sc->Z[2];
    float o0 = w0*p0_sp[i] + w1*p0_te[i] + w2*sem[32 + t] + bf[0];
    float o1 = w0*p1_sp[i] + w1*p1_te[i] + w2*sem[64 + t] + bf[1];
    ((float2*)out)[i] = make_float2(o0, o1);
  }
}

extern "C" void kernel_launch(void* const* d_in, const int* in_sizes, int n_in,
                              void* d_out, int out_size, void* d_ws, size_t ws_size,
                              hipStream_t stream) {
  const int N = in_sizes[5];   // timestamps
  const int E = in_sizes[1];   // src

  const float* x   = (const float*)d_in[0];
  const int*   src = (const int*)  d_in[1];
  const int*   dst = (const int*)  d_in[2];
  const float* ea  = (const float*)d_in[3];
  const int*   tt  = (const int*)  d_in[4];
  const float* W1  = (const float*)d_in[6];  const float* b1 = (const float*)d_in[7];
  const float* W2  = (const float*)d_in[8];  const float* b2 = (const float*)d_in[9];
  const float* W3  = (const float*)d_in[10]; const float* b3 = (const float*)d_in[11];
  const float* Wt  = (const float*)d_in[12]; const float* bt = (const float*)d_in[13];
  const float* emb = (const float*)d_in[14];
  const float* Wa  = (const float*)d_in[15]; const float* ba = (const float*)d_in[16];
  const float* g1  = (const float*)d_in[17]; const float* be1= (const float*)d_in[18];
  const float* g2  = (const float*)d_in[19]; const float* be2= (const float*)d_in[20];
  const float* g3  = (const float*)d_in[21]; const float* be3= (const float*)d_in[22];
  const float* Wf  = (const float*)d_in[23]; const float* bf = (const float*)d_in[24];
  float* out = (float*)d_out;

  char* w = (char*)d_ws;
  size_t off = 0;
  auto take = [&](size_t bytes) -> char* {
    char* p = w + off;
    off = (off + bytes + 255) & ~(size_t)255;
    return p;
  };

  const int NB_AGG = 2048, NB_SP = 2048, NB_Z = 1024, NB_E = 2048;

  float* bufA    = (float*)take((size_t)N*D*4);
  float* bufB    = (float*)take((size_t)N*D*4);
  int*   csr     = (int*)  take((size_t)E*4);
  float* csrv    = (float*)take((size_t)E*4);
  int*   offsets = (int*)  take((size_t)(N+1)*4);
  float* dinv    = (float*)take((size_t)N*4);
  int*   blockSum= (int*)  take((size_t)SCAN_B*4);
  float* s_sp    = (float*)take((size_t)N*4);
  float* p0_sp   = (float*)take((size_t)N*4);
  float* p1_sp   = (float*)take((size_t)N*4);
  float* s_te    = (float*)take((size_t)N*4);
  float* p0_te   = (float*)take((size_t)N*4);
  float* p1_te   = (float*)take((size_t)N*4);
  float* td      = (float*)take((size_t)N*4);
  float* psum    = (float*)take((size_t)NB_AGG*D*4);
  float* psq     = (float*)take((size_t)NB_AGG*D*4);
  float* Wmod    = (float*)take((size_t)D*D*4);
  float* cconst  = (float*)take((size_t)D*4);
  float* scaleb  = (float*)take((size_t)D*4);
  float* shiftb  = (float*)take((size_t)D*4);
  float* sem     = (float*)take((size_t)96*4);
  // --- zero-init region (contiguous) ---
  Scal* sc     = (Scal*)take(sizeof(Scal));
  int*  indeg  = (int*) take((size_t)N*4);
  int*  cursor = (int*) take((size_t)N*4);
  unsigned long long* outAcc = (unsigned long long*)take((size_t)N*8);
  size_t zbytes = (size_t)((w + off) - (char*)sc);
  hipMemsetAsync(sc, 0, zbytes, stream);

  int gE = (E + 255) / 256;
  int gN = (N + 255) / 256;
  int gT = (N + BN - 1) / BN;

  // fused edge pass: indeg hist + out-side packed (count,sum) + edge stats
  k_edge1<<<NB_E, 256, 0, stream>>>(src, dst, ea, indeg, outAcc, sc, E);
  k_efin<<<1, 1, 0, stream>>>(sc, E);
  // offsets + dinv
  k_scan1<<<SCAN_B, SCAN_T, 0, stream>>>(indeg, blockSum, N);
  k_scan2<<<1, SCAN_B, 0, stream>>>(blockSum);
  k_scan3<<<SCAN_B, SCAN_T, 0, stream>>>(indeg, blockSum, offsets, dinv, N);
  // CSR fill (index + value)
  k_fill<<<gE, 256, 0, stream>>>(src, dst, ea, offsets, cursor, csr, csrv, E);
  // td gather
  k_td2<<<gN, 256, 0, stream>>>(offsets, csrv, outAcc, sc, td, N);

  // layer 1
  k_gemm<<<gT, 256, 0, stream>>>(x, W1, nullptr, dinv, bufA, N);
  k_agg<<<NB_AGG, 256, 0, stream>>>(bufA, offsets, csr, dinv, b1, bufB, psum, psq, N);
  k_colreduce<<<D, 256, 0, stream>>>(psum, psq, NB_AGG, g1, be1, scaleb, shiftb, N);
  k_fold<<<D, D, 0, stream>>>(W2, scaleb, shiftb, Wmod, cconst);
  // layer 2
  k_gemm<<<gT, 256, 0, stream>>>(bufB, Wmod, cconst, dinv, bufA, N);
  k_agg<<<NB_AGG, 256, 0, stream>>>(bufA, offsets, csr, dinv, b2, bufB, psum, psq, N);
  k_colreduce<<<D, 256, 0, stream>>>(psum, psq, NB_AGG, g2, be2, scaleb, shiftb, N);
  k_fold<<<D, D, 0, stream>>>(W3, scaleb, shiftb, Wmod, cconst);
  // layer 3
  k_gemm<<<gT, 256, 0, stream>>>(bufB, Wmod, cconst, dinv, bufA, N);
  k_agg<<<NB_AGG, 256, 0, stream>>>(bufA, offsets, csr, dinv, b3, bufB, psum, psq, N);
  k_colreduce<<<D, 256, 0, stream>>>(psum, psq, NB_AGG, g3, be3, scaleb, shiftb, N);

  // branches
  k_sem<<<1, 64, 0, stream>>>(emb, Wa, ba, Wf, sem);
  k_spatial<<<NB_SP, 256, 0, stream>>>(bufB, scaleb, shiftb, Wa, ba, Wf, tt, sem,
                                       s_sp, p0_sp, p1_sp, sc->maxkey, N);
  k_temporal<<<gT, 256, 0, stream>>>(x, td, Wt, bt, Wa, ba, Wf,
                                     s_te, p0_te, p1_te, sc->maxkey, N);
  // softmax + combine
  k_zsum<<<NB_Z, 256, 0, stream>>>(s_sp, s_te, tt, sem, sc, N);
  k_final<<<gN, 256, 0, stream>>>(s_sp, p0_sp, p1_sp, s_te, p0_te, p1_te,
                                  tt, sem, sc, bf, out, N);
}

// Round 7
// 1056.044 us; speedup vs baseline: 2.2420x; 1.0761x over previous
//
#include <hip/hip_runtime.h>
#include <math.h>

#define D   128
#define WAVE 64

// GEMM tiling
#define BN  128
#define KP  32
#define TN  8
#define TJ  8
#define XSTR (BN + 4)

// scan config
#define SCAN_B 256
#define SCAN_T 256

#define MASK44 ((1ULL<<44) - 1)

struct Scal {
  double esum, esumsq;     // zero-init
  unsigned maxkey[3];      // zero-init (decodes below all finite)
  float Z[3];              // zero-init
  float emean, einv;       // written in k_scan2 tail
};

__device__ __forceinline__ unsigned fkey(float f){
  unsigned b = __float_as_uint(f);
  return (b & 0x80000000u) ? ~b : (b | 0x80000000u);
}
__device__ __forceinline__ float fdec(unsigned k){
  return (k & 0x80000000u) ? __uint_as_float(k & 0x7fffffffu) : __uint_as_float(~k);
}
__device__ __forceinline__ void atomAddF(float* p, float v){
  __hip_atomic_fetch_add(p, v, __ATOMIC_RELAXED, __HIP_MEMORY_SCOPE_AGENT);
}
__device__ __forceinline__ void atomAddD(double* p, double v){
  __hip_atomic_fetch_add(p, v, __ATOMIC_RELAXED, __HIP_MEMORY_SCOPE_AGENT);
}

// ---------- fused edge pass 1: indeg hist (returns pos) + packed out-side + edge stats ----------
__global__ void __launch_bounds__(256)
k_edge1(const int* __restrict__ src, const int* __restrict__ dst,
        const float* __restrict__ ea, int* __restrict__ indeg,
        unsigned long long* __restrict__ outAcc, int* __restrict__ pos,
        Scal* sc, int E){
  int i = blockIdx.x*blockDim.x + threadIdx.x;
  int stride = gridDim.x*blockDim.x;
  double s = 0.0, q = 0.0;
  for(; i < E; i += stride){
    float v = fminf(fmaxf(ea[i], -1000.f), 1000.f);
    s += (double)v; q += (double)v * (double)v;
    pos[i] = atomicAdd(&indeg[dst[i]], 1);          // position within dst bucket
    unsigned long long pk = (1ULL<<44) +
        (unsigned long long)(long long)((double)(v + 1024.0) * 1048576.0 + 0.5);
    atomicAdd(&outAcc[src[i]], pk);
  }
  for(int o = 32; o; o >>= 1){ s += __shfl_xor(s, o); q += __shfl_xor(q, o); }
  __shared__ double ls[4], lq[4];
  int wv = threadIdx.x >> 6;
  if((threadIdx.x & 63) == 0){ ls[wv] = s; lq[wv] = q; }
  __syncthreads();
  if(threadIdx.x == 0){
    double S = ls[0]+ls[1]+ls[2]+ls[3], Q = lq[0]+lq[1]+lq[2]+lq[3];
    atomAddD(&sc->esum, S); atomAddD(&sc->esumsq, Q);
  }
}

// ---------- hierarchical scan ----------
__global__ void __launch_bounds__(SCAN_T)
k_scan1(const int* __restrict__ indeg, int* __restrict__ blockSum, int n){
  int tile  = (n + SCAN_B - 1) / SCAN_B;
  int start = blockIdx.x * tile;
  int end   = min(start + tile, n);
  int s = 0;
  for(int i = start + threadIdx.x; i < end; i += SCAN_T) s += indeg[i];
  #pragma unroll
  for(int o = 32; o; o >>= 1) s += __shfl_xor(s, o);
  __shared__ int ls[4];
  if((threadIdx.x & 63) == 0) ls[threadIdx.x >> 6] = s;
  __syncthreads();
  if(threadIdx.x == 0) blockSum[blockIdx.x] = ls[0]+ls[1]+ls[2]+ls[3];
}

// scan of block sums; thread 0 also finalizes edge stats (was k_efin)
__global__ void __launch_bounds__(SCAN_B)
k_scan2(int* blockSum, Scal* sc, int E){
  __shared__ int tmp[SCAN_B];
  int t = threadIdx.x;
  tmp[t] = blockSum[t];
  __syncthreads();
  for(int o = 1; o < SCAN_B; o <<= 1){
    int v = (t >= o) ? tmp[t-o] : 0;
    __syncthreads();
    tmp[t] += v;
    __syncthreads();
  }
  blockSum[t] = (t == 0) ? 0 : tmp[t-1];
  if(t == 0){
    double mean = sc->esum / E;
    double var  = (sc->esumsq - sc->esum*sc->esum/E) / (double)(E - 1);
    double sd   = sqrt(var > 0.0 ? var : 0.0);
    sc->emean = (float)mean;
    sc->einv  = (float)(1.0 / (sd + 1e-9));
  }
}

__global__ void __launch_bounds__(SCAN_T)
k_scan3(const int* __restrict__ indeg, const int* __restrict__ blockSum,
        int* __restrict__ offsets, float* __restrict__ dinv, int n){
  int tile  = (n + SCAN_B - 1) / SCAN_B;
  int start = blockIdx.x * tile;
  int end   = min(start + tile, n);
  int chunk = (tile + SCAN_T - 1) / SCAN_T;
  int t = threadIdx.x;
  int tstart = start + t * chunk;
  int tend   = min(tstart + chunk, end);
  int s = 0;
  for(int i = tstart; i < tend; i++) s += indeg[i];
  __shared__ int tmp[SCAN_T];
  tmp[t] = s;
  __syncthreads();
  for(int o = 1; o < SCAN_T; o <<= 1){
    int v = (t >= o) ? tmp[t-o] : 0;
    __syncthreads();
    tmp[t] += v;
    __syncthreads();
  }
  int run = blockSum[blockIdx.x] + ((t == 0) ? 0 : tmp[t-1]);
  for(int i = tstart; i < tend; i++){
    int dg = indeg[i];
    offsets[i] = run;
    run += dg;
    dinv[i] = rsqrtf((float)(dg + 1));
  }
  if(blockIdx.x == SCAN_B-1 && t == SCAN_T-1) offsets[n] = run;
}

// ---------- CSR fill: NO atomics (uses pos from k_edge1); packed (src, val) ----------
__global__ void k_fill(const int* __restrict__ src, const int* __restrict__ dst,
                       const float* __restrict__ ea, const int* __restrict__ offsets,
                       const int* __restrict__ pos, int2* __restrict__ csrE, int E){
  int e = blockIdx.x*blockDim.x + threadIdx.x;
  if(e < E){
    int slot = offsets[dst[e]] + pos[e];
    float v = fminf(fmaxf(ea[e], -1000.f), 1000.f);
    csrE[slot] = make_int2(src[e], __float_as_int(v));
  }
}

// ---------- td from CSR gather + packed out accumulator ----------
__global__ void k_td2(const int* __restrict__ offsets, const int2* __restrict__ csrE,
                      const unsigned long long* __restrict__ outAcc,
                      const Scal* sc, float* __restrict__ td, int n){
  int i = blockIdx.x*blockDim.x + threadIdx.x;
  if(i < n){
    int o0 = offsets[i], o1 = offsets[i+1];
    float S_in = 0.f;
    for(int e = o0; e < o1; e++) S_in += __int_as_float(csrE[e].y);
    unsigned long long acc = outAcc[i];
    int cout = (int)(acc >> 44);
    double S_out = (double)(acc & MASK44) * (1.0/1048576.0) - 1024.0 * (double)cout;
    int deg = (o1 - o0) + cout;
    float S = S_in + (float)S_out;
    float tdv = (S - sc->emean * (float)deg) * sc->einv / fmaxf((float)deg, 1.f);
    td[i] = tdv;
  }
}

// ---------- register-tiled GEMM: out[node,:] = dinv[node]*(A[node,:]@W + cvec) ----------
__global__ void __launch_bounds__(256)
k_gemm(const float* __restrict__ A, const float* __restrict__ W,
       const float* __restrict__ cvec, const float* __restrict__ dinv,
       float* __restrict__ out, int n){
  __shared__ float xs[KP][XSTR];
  __shared__ float ws[KP][D];
  const int t  = threadIdx.x;
  const int jg = t & 15, ng = t >> 4;
  const int j0 = jg * TJ, n0 = ng * TN;
  const int nodeBase = blockIdx.x * BN;

  float cr[TJ];
  {
    float4 c0 = *(const float4*)(cvec + j0);
    float4 c1 = *(const float4*)(cvec + j0 + 4);
    cr[0]=c0.x; cr[1]=c0.y; cr[2]=c0.z; cr[3]=c0.w;
    cr[4]=c1.x; cr[5]=c1.y; cr[6]=c1.z; cr[7]=c1.w;
  }
  float acc[TN][TJ];
  #pragma unroll
  for(int i=0;i<TN;i++)
    #pragma unroll
    for(int j=0;j<TJ;j++) acc[i][j]=cr[j];

  for(int p=0;p<D/KP;p++){
    {
      const float4* Wp = (const float4*)(W + (size_t)p*KP*D);
      float4* ws4 = (float4*)ws;
      ws4[t]       = Wp[t];
      ws4[t + 256] = Wp[t + 256];
      ws4[t + 512] = Wp[t + 512];
      ws4[t + 768] = Wp[t + 768];
    }
    #pragma unroll
    for(int q=0;q<4;q++){
      int idx = t + q*256;
      int node = idx >> 3, kq = idx & 7;
      int gn = nodeBase + node; if(gn >= n) gn = n-1;
      float4 v = *(const float4*)(A + (size_t)gn*D + p*KP + kq*4);
      xs[kq*4+0][node] = v.x; xs[kq*4+1][node] = v.y;
      xs[kq*4+2][node] = v.z; xs[kq*4+3][node] = v.w;
    }
    __syncthreads();
    #pragma unroll 4
    for(int k=0;k<KP;k++){
      float4 xa = *(const float4*)&xs[k][n0];
      float4 xb = *(const float4*)&xs[k][n0+4];
      float4 wa = *(const float4*)&ws[k][j0];
      float4 wb = *(const float4*)&ws[k][j0+4];
      float xv[8] = {xa.x,xa.y,xa.z,xa.w,xb.x,xb.y,xb.z,xb.w};
      float wv[8] = {wa.x,wa.y,wa.z,wa.w,wb.x,wb.y,wb.z,wb.w};
      #pragma unroll
      for(int i=0;i<TN;i++)
        #pragma unroll
        for(int j=0;j<TJ;j++)
          acc[i][j] = fmaf(xv[i], wv[j], acc[i][j]);
    }
    __syncthreads();
  }
  #pragma unroll
  for(int i=0;i<TN;i++){
    int gn = nodeBase + n0 + i;
    if(gn < n){
      float d = dinv[gn];
      float4 o0 = make_float4(acc[i][0]*d, acc[i][1]*d, acc[i][2]*d, acc[i][3]*d);
      float4 o1 = make_float4(acc[i][4]*d, acc[i][5]*d, acc[i][6]*d, acc[i][7]*d);
      *(float4*)(out + (size_t)gn*D + j0)     = o0;
      *(float4*)(out + (size_t)gn*D + j0 + 4) = o1;
    }
  }
}

// ---------- fused layer-1 GEMM + temporal branch (both read x) ----------
__global__ void __launch_bounds__(256)
k_gemmT(const float* __restrict__ x, const float* __restrict__ W1,
        const float* __restrict__ dinv, float* __restrict__ h1,
        const float* __restrict__ td, const float* __restrict__ Wt,
        const float* __restrict__ bt, const float* __restrict__ Wa,
        const float* __restrict__ ba, const float* __restrict__ Wf,
        float* s_te, float* p0_te, float* p1_te, unsigned* maxkey, int n){
  __shared__ float xs[KP][XSTR];
  __shared__ float ws1[KP][D];
  __shared__ float wst[KP][D];
  __shared__ unsigned mk;
  const int t  = threadIdx.x;
  const int jg = t & 15, ng = t >> 4;
  const int j0 = jg * TJ, n0 = ng * TN;
  const int nodeBase = blockIdx.x * BN;
  if(t == 0) mk = 0;

  float acc1[TN][TJ], accT[TN][TJ];
  #pragma unroll
  for(int i=0;i<TN;i++)
    #pragma unroll
    for(int j=0;j<TJ;j++){ acc1[i][j]=0.f; accT[i][j]=0.f; }

  for(int p=0;p<D/KP;p++){
    {
      const float4* Wp = (const float4*)(W1 + (size_t)p*KP*D);
      const float4* Tp = (const float4*)(Wt + (size_t)p*KP*D);
      float4* w14 = (float4*)ws1;
      float4* wt4 = (float4*)wst;
      w14[t]       = Wp[t];       wt4[t]       = Tp[t];
      w14[t + 256] = Wp[t + 256]; wt4[t + 256] = Tp[t + 256];
      w14[t + 512] = Wp[t + 512]; wt4[t + 512] = Tp[t + 512];
      w14[t + 768] = Wp[t + 768]; wt4[t + 768] = Tp[t + 768];
    }
    #pragma unroll
    for(int q=0;q<4;q++){
      int idx = t + q*256;
      int node = idx >> 3, kq = idx & 7;
      int gn = nodeBase + node; if(gn >= n) gn = n-1;
      float4 v = *(const float4*)(x + (size_t)gn*D + p*KP + kq*4);
      xs[kq*4+0][node] = v.x; xs[kq*4+1][node] = v.y;
      xs[kq*4+2][node] = v.z; xs[kq*4+3][node] = v.w;
    }
    __syncthreads();
    #pragma unroll 2
    for(int k=0;k<KP;k++){
      float4 xa = *(const float4*)&xs[k][n0];
      float4 xb = *(const float4*)&xs[k][n0+4];
      float4 wa = *(const float4*)&ws1[k][j0];
      float4 wb = *(const float4*)&ws1[k][j0+4];
      float4 wc = *(const float4*)&wst[k][j0];
      float4 wd = *(const float4*)&wst[k][j0+4];
      float xv[8] = {xa.x,xa.y,xa.z,xa.w,xb.x,xb.y,xb.z,xb.w};
      float wv[8] = {wa.x,wa.y,wa.z,wa.w,wb.x,wb.y,wb.z,wb.w};
      float tv[8] = {wc.x,wc.y,wc.z,wc.w,wd.x,wd.y,wd.z,wd.w};
      #pragma unroll
      for(int i=0;i<TN;i++)
        #pragma unroll
        for(int j=0;j<TJ;j++){
          acc1[i][j] = fmaf(xv[i], wv[j], acc1[i][j]);
          accT[i][j] = fmaf(xv[i], tv[j], accT[i][j]);
        }
    }
    __syncthreads();
  }
  // epilogue 1: h1 = dinv * (x@W1)
  #pragma unroll
  for(int i=0;i<TN;i++){
    int gn = nodeBase + n0 + i;
    if(gn < n){
      float d = dinv[gn];
      float4 o0 = make_float4(acc1[i][0]*d, acc1[i][1]*d, acc1[i][2]*d, acc1[i][3]*d);
      float4 o1 = make_float4(acc1[i][4]*d, acc1[i][5]*d, acc1[i][6]*d, acc1[i][7]*d);
      *(float4*)(h1 + (size_t)gn*D + j0)     = o0;
      *(float4*)(h1 + (size_t)gn*D + j0 + 4) = o1;
    }
  }
  // epilogue 2: temporal scores
  float wl[TJ], bb[TJ], wa8[TJ], wf0[TJ], wf1[TJ];
  #pragma unroll
  for(int j=0;j<TJ;j++){
    wl[j]  = Wt[(size_t)D*D + j0 + j];
    bb[j]  = bt[j0 + j];
    wa8[j] = Wa[j0 + j];
    float2 w2 = ((const float2*)Wf)[j0 + j];
    wf0[j] = w2.x; wf1[j] = w2.y;
  }
  float ba0 = ba[0];
  float mloc = -INFINITY;
  #pragma unroll
  for(int i=0;i<TN;i++){
    int gn = nodeBase + n0 + i;
    float tdv = (gn < n) ? td[gn] : 0.f;
    float s = 0.f, p0 = 0.f, p1 = 0.f;
    #pragma unroll
    for(int j=0;j<TJ;j++){
      float tj = fmaxf(accT[i][j] + tdv*wl[j] + bb[j], 0.f);
      s  = fmaf(tj, wa8[j], s);
      p0 = fmaf(tj, wf0[j], p0);
      p1 = fmaf(tj, wf1[j], p1);
    }
    #pragma unroll
    for(int o=8;o;o>>=1){
      s += __shfl_xor(s, o); p0 += __shfl_xor(p0, o); p1 += __shfl_xor(p1, o);
    }
    if(jg == 0 && gn < n){
      s += ba0;
      s_te[gn] = s; p0_te[gn] = p0; p1_te[gn] = p1;
      mloc = fmaxf(mloc, s);
    }
  }
  __syncthreads();
  if(jg == 0) atomicMax(&mk, fkey(mloc));
  __syncthreads();
  if(t == 0) atomicMax(&maxkey[1], mk);
}

// ---------- aggregation: 16 lanes per node, 4 nodes/wave, 4-way MLP ----------
__global__ void __launch_bounds__(256)
k_agg(const float* __restrict__ h, const int* __restrict__ offsets,
      const int2* __restrict__ csrE, const float* __restrict__ dinv,
      const float* __restrict__ bias, float* __restrict__ out,
      float* __restrict__ psum, float* __restrict__ psq, int n){
  const int l   = threadIdx.x & 15;
  const int grp = threadIdx.x >> 4;
  const int gg  = blockIdx.x * 16 + grp;
  const int ngg = gridDim.x * 16;
  const int c0  = l * 8;

  float4 bb0 = *(const float4*)(bias + c0);
  float4 bb1 = *(const float4*)(bias + c0 + 4);
  float bbv[8] = {bb0.x,bb0.y,bb0.z,bb0.w,bb1.x,bb1.y,bb1.z,bb1.w};

  float bs[8] = {0,0,0,0,0,0,0,0};
  float bq[8] = {0,0,0,0,0,0,0,0};

  for(int node = gg; node < n; node += ngg){
    int off = offsets[node], end = offsets[node+1];
    float di = dinv[node];
    const float* hr = h + (size_t)node*D + c0;
    float4 s0 = *(const float4*)hr;
    float4 s1 = *(const float4*)(hr+4);
    float aa[8] = {s0.x,s0.y,s0.z,s0.w,s1.x,s1.y,s1.z,s1.w};
    float ab[8] = {0,0,0,0,0,0,0,0};
    float ac[8] = {0,0,0,0,0,0,0,0};
    float ad[8] = {0,0,0,0,0,0,0,0};
    int e = off;
    for(; e + 3 < end; e += 4){
      const float* h0 = h + (size_t)csrE[e].x*D   + c0;
      const float* h1 = h + (size_t)csrE[e+1].x*D + c0;
      const float* h2 = h + (size_t)csrE[e+2].x*D + c0;
      const float* h3 = h + (size_t)csrE[e+3].x*D + c0;
      float4 v00 = *(const float4*)h0, v01 = *(const float4*)(h0+4);
      float4 v10 = *(const float4*)h1, v11 = *(const float4*)(h1+4);
      float4 v20 = *(const float4*)h2, v21 = *(const float4*)(h2+4);
      float4 v30 = *(const float4*)h3, v31 = *(const float4*)(h3+4);
      aa[0]+=v00.x; aa[1]+=v00.y; aa[2]+=v00.z; aa[3]+=v00.w;
      aa[4]+=v01.x; aa[5]+=v01.y; aa[6]+=v01.z; aa[7]+=v01.w;
      ab[0]+=v10.x; ab[1]+=v10.y; ab[2]+=v10.z; ab[3]+=v10.w;
      ab[4]+=v11.x; ab[5]+=v11.y; ab[6]+=v11.z; ab[7]+=v11.w;
      ac[0]+=v20.x; ac[1]+=v20.y; ac[2]+=v20.z; ac[3]+=v20.w;
      ac[4]+=v21.x; ac[5]+=v21.y; ac[6]+=v21.z; ac[7]+=v21.w;
      ad[0]+=v30.x; ad[1]+=v30.y; ad[2]+=v30.z; ad[3]+=v30.w;
      ad[4]+=v31.x; ad[5]+=v31.y; ad[6]+=v31.z; ad[7]+=v31.w;
    }
    for(; e < end; e++){
      const float* h0 = h + (size_t)csrE[e].x*D + c0;
      float4 v00 = *(const float4*)h0, v01 = *(const float4*)(h0+4);
      aa[0]+=v00.x; aa[1]+=v00.y; aa[2]+=v00.z; aa[3]+=v00.w;
      aa[4]+=v01.x; aa[5]+=v01.y; aa[6]+=v01.z; aa[7]+=v01.w;
    }
    float r[8];
    #pragma unroll
    for(int j=0;j<8;j++){
      r[j] = fmaxf(fmaf(di, aa[j]+ab[j]+ac[j]+ad[j], bbv[j]), 0.f);
      bs[j] += r[j];
      bq[j] += r[j]*r[j];
    }
    float* orow = out + (size_t)node*D + c0;
    *(float4*)orow     = make_float4(r[0],r[1],r[2],r[3]);
    *(float4*)(orow+4) = make_float4(r[4],r[5],r[6],r[7]);
  }

  __shared__ float red[16][D];
  #pragma unroll
  for(int j=0;j<8;j++) red[grp][c0+j] = bs[j];
  __syncthreads();
  if(threadIdx.x < D){
    float s = 0.f;
    #pragma unroll
    for(int g=0;g<16;g++) s += red[g][threadIdx.x];
    psum[(size_t)blockIdx.x*D + threadIdx.x] = s;
  }
  __syncthreads();
  #pragma unroll
  for(int j=0;j<8;j++) red[grp][c0+j] = bq[j];
  __syncthreads();
  if(threadIdx.x < D){
    float s = 0.f;
    #pragma unroll
    for(int g=0;g<16;g++) s += red[g][threadIdx.x];
    psq[(size_t)blockIdx.x*D + threadIdx.x] = s;
  }
}

// ---------- BN params ----------
__global__ void k_colreduce(const float* __restrict__ psum, const float* __restrict__ psq,
                            int nb, const float* __restrict__ g, const float* __restrict__ be,
                            float* scale, float* shift, int n){
  int c = blockIdx.x;
  float s = 0, q = 0;
  for(int b = threadIdx.x; b < nb; b += blockDim.x){
    s += psum[(size_t)b*D + c]; q += psq[(size_t)b*D + c];
  }
  for(int o = 32; o; o >>= 1){ s += __shfl_xor(s, o); q += __shfl_xor(q, o); }
  __shared__ float ls[4], lq[4];
  int wv = threadIdx.x >> 6;
  if((threadIdx.x & 63) == 0){ ls[wv] = s; lq[wv] = q; }
  __syncthreads();
  if(threadIdx.x == 0){
    float S = ls[0]+ls[1]+ls[2]+ls[3], Q = lq[0]+lq[1]+lq[2]+lq[3];
    float mean = S / n;
    float var  = fmaxf(Q / n - mean*mean, 0.f);
    float sc   = g[c] * rsqrtf(var + 1e-5f);
    scale[c] = sc;
    shift[c] = fmaf(-mean, sc, be[c]);
  }
}

__global__ void k_fold(const float* __restrict__ W, const float* __restrict__ scale,
                       const float* __restrict__ shift, float* Wmod, float* cconst){
  int j = blockIdx.x, k = threadIdx.x;
  float w = W[k*D + j];
  Wmod[k*D + j] = scale[k] * w;
  float sm = shift[k] * w;
  for(int o = 32; o; o >>= 1) sm += __shfl_xor(sm, o);
  __shared__ float l2[2];
  if((k & 63) == 0) l2[k >> 6] = sm;
  __syncthreads();
  if(k == 0) cconst[j] = l2[0] + l2[1];
}

// ---------- semantic table ----------
__global__ void k_sem(const float* __restrict__ emb, const float* __restrict__ Wa,
                      const float* __restrict__ ba, const float* __restrict__ Wf, float* sem){
  int t = threadIdx.x;
  if(t < 32){
    float s = ba[0], q0 = 0, q1 = 0;
    for(int c = 0; c < D; c++){
      float e = emb[t*D + c];
      s  = fmaf(e, Wa[c],     s);
      q0 = fmaf(e, Wf[2*c],   q0);
      q1 = fmaf(e, Wf[2*c+1], q1);
    }
    sem[t] = s; sem[32 + t] = q0; sem[64 + t] = q1;
  }
}

// ---------- spatial branch scores ----------
__global__ void __launch_bounds__(256)
k_spatial(const float* __restrict__ R, const float* __restrict__ scale,
          const float* __restrict__ shift, const float* __restrict__ Wa,
          const float* __restrict__ ba, const float* __restrict__ Wf,
          const int* __restrict__ tt, const float* __restrict__ sem,
          float* s_sp, float* p0_sp, float* p1_sp, unsigned* maxkey, int n){
  int lane = threadIdx.x & 63;
  int wid  = (blockIdx.x*blockDim.x + threadIdx.x) >> 6;
  int nw   = (gridDim.x*blockDim.x) >> 6;
  float2 sc = ((const float2*)scale)[lane];
  float2 sh = ((const float2*)shift)[lane];
  float2 wa = ((const float2*)Wa)[lane];
  float4 wf = ((const float4*)Wf)[lane];
  float ba0 = ba[0];
  float mloc = -INFINITY, msem = -INFINITY;
  for(int node = wid; node < n; node += nw){
    float2 v = ((const float2*)(R + (size_t)node*D))[lane];
    float v0 = fmaf(v.x, sc.x, sh.x);
    float v1 = fmaf(v.y, sc.y, sh.y);
    float s  = v0*wa.x + v1*wa.y;
    float p0 = v0*wf.x + v1*wf.z;
    float p1 = v0*wf.y + v1*wf.w;
    for(int o = 32; o; o >>= 1){
      s += __shfl_xor(s, o); p0 += __shfl_xor(p0, o); p1 += __shfl_xor(p1, o);
    }
    s += ba0;
    if(lane == 0){ s_sp[node] = s; p0_sp[node] = p0; p1_sp[node] = p1; }
    mloc = fmaxf(mloc, s);
    msem = fmaxf(msem, sem[tt[node]]);
  }
  __shared__ float lm[4], lsm[4];
  int wv = threadIdx.x >> 6;
  if(lane == 0){ lm[wv] = mloc; lsm[wv] = msem; }
  __syncthreads();
  if(threadIdx.x == 0){
    float M  = fmaxf(fmaxf(lm[0], lm[1]),  fmaxf(lm[2], lm[3]));
    float M2 = fmaxf(fmaxf(lsm[0], lsm[1]), fmaxf(lsm[2], lsm[3]));
    atomicMax(&maxkey[0], fkey(M));
    atomicMax(&maxkey[2], fkey(M2));
  }
}

// ---------- softmax denominators ----------
__global__ void k_zsum(const float* __restrict__ s_sp, const float* __restrict__ s_te,
                       const int* __restrict__ tt, const float* __restrict__ sem,
                       Scal* sc, int n){
  float M0 = fdec(sc->maxkey[0]), M1 = fdec(sc->maxkey[1]), M2 = fdec(sc->maxkey[2]);
  int i = blockIdx.x*blockDim.x + threadIdx.x;
  int stride = gridDim.x*blockDim.x;
  float z0 = 0, z1 = 0, z2 = 0;
  for(; i < n; i += stride){
    z0 += expf(s_sp[i] - M0);
    z1 += expf(s_te[i] - M1);
    z2 += expf(sem[tt[i]] - M2);
  }
  for(int o = 32; o; o >>= 1){
    z0 += __shfl_xor(z0, o); z1 += __shfl_xor(z1, o); z2 += __shfl_xor(z2, o);
  }
  __shared__ float l0[4], l1[4], l2[4];
  int wv = threadIdx.x >> 6;
  if((threadIdx.x & 63) == 0){ l0[wv] = z0; l1[wv] = z1; l2[wv] = z2; }
  __syncthreads();
  if(threadIdx.x == 0){
    atomAddF(&sc->Z[0], l0[0]+l0[1]+l0[2]+l0[3]);
    atomAddF(&sc->Z[1], l1[0]+l1[1]+l1[2]+l1[3]);
    atomAddF(&sc->Z[2], l2[0]+l2[1]+l2[2]+l2[3]);
  }
}

// ---------- final combine ----------
__global__ void k_final(const float* __restrict__ s_sp, const float* __restrict__ p0_sp,
                        const float* __restrict__ p1_sp, const float* __restrict__ s_te,
                        const float* __restrict__ p0_te, const float* __restrict__ p1_te,
                        const int* __restrict__ tt, const float* __restrict__ sem,
                        const Scal* sc, const float* __restrict__ bf,
                        float* __restrict__ out, int n){
  int i = blockIdx.x*blockDim.x + threadIdx.x;
  if(i < n){
    float M0 = fdec(sc->maxkey[0]), M1 = fdec(sc->maxkey[1]), M2 = fdec(sc->maxkey[2]);
    float w0 = expf(s_sp[i] - M0) / sc->Z[0];
    float w1 = expf(s_te[i] - M1) / sc->Z[1];
    int t = tt[i];
    float w2 = expf(sem[t] - M2) / sc->Z[2];
    float o0 = w0*p0_sp[i] + w1*p0_te[i] + w2*sem[32 + t] + bf[0];
    float o1 = w0*p1_sp[i] + w1*p1_te[i] + w2*sem[64 + t] + bf[1];
    ((float2*)out)[i] = make_float2(o0, o1);
  }
}

extern "C" void kernel_launch(void* const* d_in, const int* in_sizes, int n_in,
                              void* d_out, int out_size, void* d_ws, size_t ws_size,
                              hipStream_t stream) {
  const int N = in_sizes[5];   // timestamps
  const int E = in_sizes[1];   // src

  const float* x   = (const float*)d_in[0];
  const int*   src = (const int*)  d_in[1];
  const int*   dst = (const int*)  d_in[2];
  const float* ea  = (const float*)d_in[3];
  const int*   tt  = (const int*)  d_in[4];
  const float* W1  = (const float*)d_in[6];  const float* b1 = (const float*)d_in[7];
  const float* W2  = (const float*)d_in[8];  const float* b2 = (const float*)d_in[9];
  const float* W3  = (const float*)d_in[10]; const float* b3 = (const float*)d_in[11];
  const float* Wt  = (const float*)d_in[12]; const float* bt = (const float*)d_in[13];
  const float* emb = (const float*)d_in[14];
  const float* Wa  = (const float*)d_in[15]; const float* ba = (const float*)d_in[16];
  const float* g1  = (const float*)d_in[17]; const float* be1= (const float*)d_in[18];
  const float* g2  = (const float*)d_in[19]; const float* be2= (const float*)d_in[20];
  const float* g3  = (const float*)d_in[21]; const float* be3= (const float*)d_in[22];
  const float* Wf  = (const float*)d_in[23]; const float* bf = (const float*)d_in[24];
  float* out = (float*)d_out;

  char* w = (char*)d_ws;
  size_t off = 0;
  auto take = [&](size_t bytes) -> char* {
    char* p = w + off;
    off = (off + bytes + 255) & ~(size_t)255;
    return p;
  };

  const int NB_AGG = 2048, NB_SP = 2048, NB_Z = 1024, NB_E = 2048;

  float* bufA    = (float*)take((size_t)N*D*4);
  float* bufB    = (float*)take((size_t)N*D*4);
  int2*  csrE    = (int2*) take((size_t)E*8);
  int*   pos     = (int*)  take((size_t)E*4);
  int*   offsets = (int*)  take((size_t)(N+1)*4);
  float* dinv    = (float*)take((size_t)N*4);
  int*   blockSum= (int*)  take((size_t)SCAN_B*4);
  float* s_sp    = (float*)take((size_t)N*4);
  float* p0_sp   = (float*)take((size_t)N*4);
  float* p1_sp   = (float*)take((size_t)N*4);
  float* s_te    = (float*)take((size_t)N*4);
  float* p0_te   = (float*)take((size_t)N*4);
  float* p1_te   = (float*)take((size_t)N*4);
  float* td      = (float*)take((size_t)N*4);
  float* psum    = (float*)take((size_t)NB_AGG*D*4);
  float* psq     = (float*)take((size_t)NB_AGG*D*4);
  float* Wmod    = (float*)take((size_t)D*D*4);
  float* cconst  = (float*)take((size_t)D*4);
  float* scaleb  = (float*)take((size_t)D*4);
  float* shiftb  = (float*)take((size_t)D*4);
  float* sem     = (float*)take((size_t)96*4);
  float* zeros   = (float*)take((size_t)D*4);   // zero bias for layer-1 gemm (in zero region? no) 
  // --- zero-init region (contiguous) ---
  Scal* sc     = (Scal*)take(sizeof(Scal));
  int*  indeg  = (int*) take((size_t)N*4);
  unsigned long long* outAcc = (unsigned long long*)take((size_t)N*8);
  size_t zbytes = (size_t)((w + off) - (char*)sc);
  hipMemsetAsync(sc, 0, zbytes, stream);
  hipMemsetAsync(zeros, 0, (size_t)D*4, stream);

  int gE = (E + 255) / 256;
  int gN = (N + 255) / 256;
  int gT = (N + BN - 1) / BN;

  // fused edge pass: indeg hist (w/ pos) + out-side packed (count,sum) + edge stats
  k_edge1<<<NB_E, 256, 0, stream>>>(src, dst, ea, indeg, outAcc, pos, sc, E);
  // offsets + dinv (scan2 also finalizes edge stats)
  k_scan1<<<SCAN_B, SCAN_T, 0, stream>>>(indeg, blockSum, N);
  k_scan2<<<1, SCAN_B, 0, stream>>>(blockSum, sc, E);
  k_scan3<<<SCAN_B, SCAN_T, 0, stream>>>(indeg, blockSum, offsets, dinv, N);
  // CSR fill (no atomics)
  k_fill<<<gE, 256, 0, stream>>>(src, dst, ea, offsets, pos, csrE, E);
  // td gather
  k_td2<<<gN, 256, 0, stream>>>(offsets, csrE, outAcc, sc, td, N);

  // fused layer-1 GEMM + temporal branch
  k_gemmT<<<gT, 256, 0, stream>>>(x, W1, dinv, bufA, td, Wt, bt, Wa, ba, Wf,
                                  s_te, p0_te, p1_te, sc->maxkey, N);
  k_agg<<<NB_AGG, 256, 0, stream>>>(bufA, offsets, csrE, dinv, b1, bufB, psum, psq, N);
  k_colreduce<<<D, 256, 0, stream>>>(psum, psq, NB_AGG, g1, be1, scaleb, shiftb, N);
  k_fold<<<D, D, 0, stream>>>(W2, scaleb, shiftb, Wmod, cconst);
  // layer 2
  k_gemm<<<gT, 256, 0, stream>>>(bufB, Wmod, cconst, dinv, bufA, N);
  k_agg<<<NB_AGG, 256, 0, stream>>>(bufA, offsets, csrE, dinv, b2, bufB, psum, psq, N);
  k_colreduce<<<D, 256, 0, stream>>>(psum, psq, NB_AGG, g2, be2, scaleb, shiftb, N);
  k_fold<<<D, D, 0, stream>>>(W3, scaleb, shiftb, Wmod, cconst);
  // layer 3
  k_gemm<<<gT, 256, 0, stream>>>(bufB, Wmod, cconst, dinv, bufA, N);
  k_agg<<<NB_AGG, 256, 0, stream>>>(bufA, offsets, csrE, dinv, b3, bufB, psum, psq, N);
  k_colreduce<<<D, 256, 0, stream>>>(psum, psq, NB_AGG, g3, be3, scaleb, shiftb, N);

  // branches
  k_sem<<<1, 64, 0, stream>>>(emb, Wa, ba, Wf, sem);
  k_spatial<<<NB_SP, 256, 0, stream>>>(bufB, scaleb, shiftb, Wa, ba, Wf, tt, sem,
                                       s_sp, p0_sp, p1_sp, sc->maxkey, N);
  // softmax + combine
  k_zsum<<<NB_Z, 256, 0, stream>>>(s_sp, s_te, tt, sem, sc, N);
  k_final<<<gN, 256, 0, stream>>>(s_sp, p0_sp, p1_sp, s_te, p0_te, p1_te,
                                  tt, sem, sc, bf, out, N);
}

// Round 8
// 1000.945 us; speedup vs baseline: 2.3655x; 1.0550x over previous
//
#include <hip/hip_runtime.h>
#include <math.h>

#define D   128
#define WAVE 64

// GEMM tiling
#define BN  128
#define KP  32
#define TN  8
#define TJ  8
#define XSTR (BN + 4)

// scan config
#define SCAN_B 256
#define SCAN_T 256

// mega-kernel role interleave: period 7 = 4 edge + 3 gemm blocks
#define MEGA_EB 1024
#define MEGA_GB 768
#define MEGA_GRID 1792

#define MASK44 ((1ULL<<44) - 1)

struct Scal {
  double esum, esumsq;     // zero-init
  unsigned maxkey[3];      // zero-init (decodes below all finite)
  float Z[3];              // zero-init
  float emean, einv;       // written in k_scan2 tail
};

__device__ __forceinline__ unsigned fkey(float f){
  unsigned b = __float_as_uint(f);
  return (b & 0x80000000u) ? ~b : (b | 0x80000000u);
}
__device__ __forceinline__ float fdec(unsigned k){
  return (k & 0x80000000u) ? __uint_as_float(k & 0x7fffffffu) : __uint_as_float(~k);
}
__device__ __forceinline__ void atomAddF(float* p, float v){
  __hip_atomic_fetch_add(p, v, __ATOMIC_RELAXED, __HIP_MEMORY_SCOPE_AGENT);
}
__device__ __forceinline__ void atomAddD(double* p, double v){
  __hip_atomic_fetch_add(p, v, __ATOMIC_RELAXED, __HIP_MEMORY_SCOPE_AGENT);
}

// ---------- mega kernel: edge pass (atomic-bound) + layer-1/temporal dual GEMM (VALU-bound) ----------
__global__ void __launch_bounds__(256)
k_mega(const int* __restrict__ src, const int* __restrict__ dst,
       const float* __restrict__ ea, int* __restrict__ indeg,
       unsigned long long* __restrict__ outAcc, int* __restrict__ pos,
       Scal* sc, int E,
       const float* __restrict__ x, const float* __restrict__ W1,
       const float* __restrict__ Wt,
       float* __restrict__ h1, float* __restrict__ accT, int n){
  __shared__ float xs[KP][XSTR];
  __shared__ float ws[KP][D];
  __shared__ double ls[4], lq[4];
  const int grp  = blockIdx.x / 7;
  const int role = blockIdx.x % 7;

  if(role < 4){
    // ---- edge role ----
    int bid = grp*4 + role;
    int i = bid*256 + threadIdx.x;
    const int stride = MEGA_EB*256;
    double s = 0.0, q = 0.0;
    for(; i < E; i += stride){
      float v = fminf(fmaxf(ea[i], -1000.f), 1000.f);
      s += (double)v; q += (double)v * (double)v;
      pos[i] = atomicAdd(&indeg[dst[i]], 1);
      unsigned long long pk = (1ULL<<44) +
          (unsigned long long)(long long)((double)(v + 1024.0) * 1048576.0 + 0.5);
      atomicAdd(&outAcc[src[i]], pk);
    }
    for(int o = 32; o; o >>= 1){ s += __shfl_xor(s, o); q += __shfl_xor(q, o); }
    int wv = threadIdx.x >> 6;
    if((threadIdx.x & 63) == 0){ ls[wv] = s; lq[wv] = q; }
    __syncthreads();
    if(threadIdx.x == 0){
      atomAddD(&sc->esum,   ls[0]+ls[1]+ls[2]+ls[3]);
      atomAddD(&sc->esumsq, lq[0]+lq[1]+lq[2]+lq[3]);
    }
  } else {
    // ---- dual-GEMM role: h1 = x@W1 (unscaled), accT = x@Wt ----
    int gIdx = grp*3 + (role - 4);
    const int t  = threadIdx.x;
    const int jg = t & 15, ng = t >> 4;
    const int j0 = jg * TJ, n0 = ng * TN;
    const int nTiles = (n + BN - 1) / BN;
    for(int tile = gIdx; tile < nTiles; tile += MEGA_GB){
      const int nodeBase = tile * BN;
      float acc1[TN][TJ], acc2[TN][TJ];
      #pragma unroll
      for(int i=0;i<TN;i++)
        #pragma unroll
        for(int j=0;j<TJ;j++){ acc1[i][j]=0.f; acc2[i][j]=0.f; }

      for(int p=0;p<D/KP;p++){
        // stage x panel (transposed) + W1 panel
        #pragma unroll
        for(int q2=0;q2<4;q2++){
          int idx = t + q2*256;
          int node = idx >> 3, kq = idx & 7;
          int gn = nodeBase + node; if(gn >= n) gn = n-1;
          float4 v = *(const float4*)(x + (size_t)gn*D + p*KP + kq*4);
          xs[kq*4+0][node] = v.x; xs[kq*4+1][node] = v.y;
          xs[kq*4+2][node] = v.z; xs[kq*4+3][node] = v.w;
        }
        {
          const float4* Wp = (const float4*)(W1 + (size_t)p*KP*D);
          float4* w4 = (float4*)ws;
          w4[t]       = Wp[t];
          w4[t + 256] = Wp[t + 256];
          w4[t + 512] = Wp[t + 512];
          w4[t + 768] = Wp[t + 768];
        }
        __syncthreads();
        #pragma unroll 4
        for(int k=0;k<KP;k++){
          float4 xa = *(const float4*)&xs[k][n0];
          float4 xb = *(const float4*)&xs[k][n0+4];
          float4 wa = *(const float4*)&ws[k][j0];
          float4 wb = *(const float4*)&ws[k][j0+4];
          float xv[8] = {xa.x,xa.y,xa.z,xa.w,xb.x,xb.y,xb.z,xb.w};
          float wv[8] = {wa.x,wa.y,wa.z,wa.w,wb.x,wb.y,wb.z,wb.w};
          #pragma unroll
          for(int i=0;i<TN;i++)
            #pragma unroll
            for(int j=0;j<TJ;j++)
              acc1[i][j] = fmaf(xv[i], wv[j], acc1[i][j]);
        }
        __syncthreads();
        {
          const float4* Wp = (const float4*)(Wt + (size_t)p*KP*D);
          float4* w4 = (float4*)ws;
          w4[t]       = Wp[t];
          w4[t + 256] = Wp[t + 256];
          w4[t + 512] = Wp[t + 512];
          w4[t + 768] = Wp[t + 768];
        }
        __syncthreads();
        #pragma unroll 4
        for(int k=0;k<KP;k++){
          float4 xa = *(const float4*)&xs[k][n0];
          float4 xb = *(const float4*)&xs[k][n0+4];
          float4 wa = *(const float4*)&ws[k][j0];
          float4 wb = *(const float4*)&ws[k][j0+4];
          float xv[8] = {xa.x,xa.y,xa.z,xa.w,xb.x,xb.y,xb.z,xb.w};
          float wv[8] = {wa.x,wa.y,wa.z,wa.w,wb.x,wb.y,wb.z,wb.w};
          #pragma unroll
          for(int i=0;i<TN;i++)
            #pragma unroll
            for(int j=0;j<TJ;j++)
              acc2[i][j] = fmaf(xv[i], wv[j], acc2[i][j]);
        }
        __syncthreads();
      }
      #pragma unroll
      for(int i=0;i<TN;i++){
        int gn = nodeBase + n0 + i;
        if(gn < n){
          *(float4*)(h1  + (size_t)gn*D + j0)     = make_float4(acc1[i][0],acc1[i][1],acc1[i][2],acc1[i][3]);
          *(float4*)(h1  + (size_t)gn*D + j0 + 4) = make_float4(acc1[i][4],acc1[i][5],acc1[i][6],acc1[i][7]);
          *(float4*)(accT+ (size_t)gn*D + j0)     = make_float4(acc2[i][0],acc2[i][1],acc2[i][2],acc2[i][3]);
          *(float4*)(accT+ (size_t)gn*D + j0 + 4) = make_float4(acc2[i][4],acc2[i][5],acc2[i][6],acc2[i][7]);
        }
      }
    }
  }
}

// ---------- hierarchical scan ----------
__global__ void __launch_bounds__(SCAN_T)
k_scan1(const int* __restrict__ indeg, int* __restrict__ blockSum, int n){
  int tile  = (n + SCAN_B - 1) / SCAN_B;
  int start = blockIdx.x * tile;
  int end   = min(start + tile, n);
  int s = 0;
  for(int i = start + threadIdx.x; i < end; i += SCAN_T) s += indeg[i];
  #pragma unroll
  for(int o = 32; o; o >>= 1) s += __shfl_xor(s, o);
  __shared__ int ls[4];
  if((threadIdx.x & 63) == 0) ls[threadIdx.x >> 6] = s;
  __syncthreads();
  if(threadIdx.x == 0) blockSum[blockIdx.x] = ls[0]+ls[1]+ls[2]+ls[3];
}

__global__ void __launch_bounds__(SCAN_B)
k_scan2(int* blockSum, Scal* sc, int E){
  __shared__ int tmp[SCAN_B];
  int t = threadIdx.x;
  tmp[t] = blockSum[t];
  __syncthreads();
  for(int o = 1; o < SCAN_B; o <<= 1){
    int v = (t >= o) ? tmp[t-o] : 0;
    __syncthreads();
    tmp[t] += v;
    __syncthreads();
  }
  blockSum[t] = (t == 0) ? 0 : tmp[t-1];
  if(t == 0){
    double mean = sc->esum / E;
    double var  = (sc->esumsq - sc->esum*sc->esum/E) / (double)(E - 1);
    double sd   = sqrt(var > 0.0 ? var : 0.0);
    sc->emean = (float)mean;
    sc->einv  = (float)(1.0 / (sd + 1e-9));
  }
}

__global__ void __launch_bounds__(SCAN_T)
k_scan3(const int* __restrict__ indeg, const int* __restrict__ blockSum,
        int* __restrict__ offsets, float* __restrict__ dinv, int n){
  int tile  = (n + SCAN_B - 1) / SCAN_B;
  int start = blockIdx.x * tile;
  int end   = min(start + tile, n);
  int chunk = (tile + SCAN_T - 1) / SCAN_T;
  int t = threadIdx.x;
  int tstart = start + t * chunk;
  int tend   = min(tstart + chunk, end);
  int s = 0;
  for(int i = tstart; i < tend; i++) s += indeg[i];
  __shared__ int tmp[SCAN_T];
  tmp[t] = s;
  __syncthreads();
  for(int o = 1; o < SCAN_T; o <<= 1){
    int v = (t >= o) ? tmp[t-o] : 0;
    __syncthreads();
    tmp[t] += v;
    __syncthreads();
  }
  int run = blockSum[blockIdx.x] + ((t == 0) ? 0 : tmp[t-1]);
  for(int i = tstart; i < tend; i++){
    int dg = indeg[i];
    offsets[i] = run;
    run += dg;
    dinv[i] = rsqrtf((float)(dg + 1));
  }
  if(blockIdx.x == SCAN_B-1 && t == SCAN_T-1) offsets[n] = run;
}

// ---------- CSR fill: no atomics; packed (src, val) ----------
__global__ void k_fill(const int* __restrict__ src, const int* __restrict__ dst,
                       const float* __restrict__ ea, const int* __restrict__ offsets,
                       const int* __restrict__ pos, int2* __restrict__ csrE, int E){
  int e = blockIdx.x*blockDim.x + threadIdx.x;
  if(e < E){
    int slot = offsets[dst[e]] + pos[e];
    float v = fminf(fmaxf(ea[e], -1000.f), 1000.f);
    csrE[slot] = make_int2(src[e], __float_as_int(v));
  }
}

// ---------- temporal finish: td inline + scores from accT ----------
__global__ void __launch_bounds__(256)
k_tempfin(const float* __restrict__ accT, const int* __restrict__ offsets,
          const int2* __restrict__ csrE, const unsigned long long* __restrict__ outAcc,
          const Scal* sc, const float* __restrict__ Wt, const float* __restrict__ bt,
          const float* __restrict__ Wa, const float* __restrict__ ba,
          const float* __restrict__ Wf,
          float* s_te, float* p0_te, float* p1_te, unsigned* maxkey, int n){
  int lane = threadIdx.x & 63;
  int wid  = (blockIdx.x*blockDim.x + threadIdx.x) >> 6;
  int nw   = (gridDim.x*blockDim.x) >> 6;
  float2 wl = ((const float2*)(Wt + (size_t)D*D))[lane];
  float2 bb = ((const float2*)bt)[lane];
  float2 wa = ((const float2*)Wa)[lane];
  float4 wf = ((const float4*)Wf)[lane];
  float ba0 = ba[0];
  float emean = sc->emean, einv = sc->einv;
  float mloc = -INFINITY;
  for(int node = wid; node < n; node += nw){
    int o0 = offsets[node], o1 = offsets[node+1];
    float sv = 0.f;
    for(int e = o0 + lane; e < o1; e += 64) sv += __int_as_float(csrE[e].y);
    for(int o = 32; o; o >>= 1) sv += __shfl_xor(sv, o);
    unsigned long long acc = outAcc[node];
    int cout = (int)(acc >> 44);
    double S_out = (double)(acc & MASK44) * (1.0/1048576.0) - 1024.0 * (double)cout;
    int deg = (o1 - o0) + cout;
    float S = sv + (float)S_out;
    float td = (S - emean * (float)deg) * einv / fmaxf((float)deg, 1.f);
    float2 v = ((const float2*)(accT + (size_t)node*D))[lane];
    float t0 = fmaxf(v.x + td*wl.x + bb.x, 0.f);
    float t1 = fmaxf(v.y + td*wl.y + bb.y, 0.f);
    float s  = t0*wa.x + t1*wa.y;
    float p0 = t0*wf.x + t1*wf.z;
    float p1 = t0*wf.y + t1*wf.w;
    for(int o = 32; o; o >>= 1){
      s += __shfl_xor(s, o); p0 += __shfl_xor(p0, o); p1 += __shfl_xor(p1, o);
    }
    s += ba0;
    if(lane == 0){
      s_te[node] = s; p0_te[node] = p0; p1_te[node] = p1;
      mloc = fmaxf(mloc, s);
    }
  }
  __shared__ float lm[4];
  int wv = threadIdx.x >> 6;
  if(lane == 0) lm[wv] = mloc;
  __syncthreads();
  if(threadIdx.x == 0){
    float M = fmaxf(fmaxf(lm[0], lm[1]), fmaxf(lm[2], lm[3]));
    atomicMax(&maxkey[1], fkey(M));
  }
}

// ---------- register-tiled GEMM (layers 2-3): out = A@Wmod + cconst (unscaled) ----------
__global__ void __launch_bounds__(256)
k_gemm(const float* __restrict__ A, const float* __restrict__ W,
       const float* __restrict__ cvec, float* __restrict__ out, int n){
  __shared__ float xs[KP][XSTR];
  __shared__ float ws[KP][D];
  const int t  = threadIdx.x;
  const int jg = t & 15, ng = t >> 4;
  const int j0 = jg * TJ, n0 = ng * TN;
  const int nodeBase = blockIdx.x * BN;

  float cr[TJ];
  {
    float4 c0 = *(const float4*)(cvec + j0);
    float4 c1 = *(const float4*)(cvec + j0 + 4);
    cr[0]=c0.x; cr[1]=c0.y; cr[2]=c0.z; cr[3]=c0.w;
    cr[4]=c1.x; cr[5]=c1.y; cr[6]=c1.z; cr[7]=c1.w;
  }
  float acc[TN][TJ];
  #pragma unroll
  for(int i=0;i<TN;i++)
    #pragma unroll
    for(int j=0;j<TJ;j++) acc[i][j]=cr[j];

  for(int p=0;p<D/KP;p++){
    {
      const float4* Wp = (const float4*)(W + (size_t)p*KP*D);
      float4* ws4 = (float4*)ws;
      ws4[t]       = Wp[t];
      ws4[t + 256] = Wp[t + 256];
      ws4[t + 512] = Wp[t + 512];
      ws4[t + 768] = Wp[t + 768];
    }
    #pragma unroll
    for(int q=0;q<4;q++){
      int idx = t + q*256;
      int node = idx >> 3, kq = idx & 7;
      int gn = nodeBase + node; if(gn >= n) gn = n-1;
      float4 v = *(const float4*)(A + (size_t)gn*D + p*KP + kq*4);
      xs[kq*4+0][node] = v.x; xs[kq*4+1][node] = v.y;
      xs[kq*4+2][node] = v.z; xs[kq*4+3][node] = v.w;
    }
    __syncthreads();
    #pragma unroll 4
    for(int k=0;k<KP;k++){
      float4 xa = *(const float4*)&xs[k][n0];
      float4 xb = *(const float4*)&xs[k][n0+4];
      float4 wa = *(const float4*)&ws[k][j0];
      float4 wb = *(const float4*)&ws[k][j0+4];
      float xv[8] = {xa.x,xa.y,xa.z,xa.w,xb.x,xb.y,xb.z,xb.w};
      float wv[8] = {wa.x,wa.y,wa.z,wa.w,wb.x,wb.y,wb.z,wb.w};
      #pragma unroll
      for(int i=0;i<TN;i++)
        #pragma unroll
        for(int j=0;j<TJ;j++)
          acc[i][j] = fmaf(xv[i], wv[j], acc[i][j]);
    }
    __syncthreads();
  }
  #pragma unroll
  for(int i=0;i<TN;i++){
    int gn = nodeBase + n0 + i;
    if(gn < n){
      *(float4*)(out + (size_t)gn*D + j0)     = make_float4(acc[i][0],acc[i][1],acc[i][2],acc[i][3]);
      *(float4*)(out + (size_t)gn*D + j0 + 4) = make_float4(acc[i][4],acc[i][5],acc[i][6],acc[i][7]);
    }
  }
}

// ---------- aggregation: h unscaled; dinv gathered per edge (L2-resident) ----------
__global__ void __launch_bounds__(256)
k_agg(const float* __restrict__ h, const int* __restrict__ offsets,
      const int2* __restrict__ csrE, const float* __restrict__ dinv,
      const float* __restrict__ bias, float* __restrict__ out,
      float* __restrict__ psum, float* __restrict__ psq, int n){
  const int l   = threadIdx.x & 15;
  const int grp = threadIdx.x >> 4;
  const int gg  = blockIdx.x * 16 + grp;
  const int ngg = gridDim.x * 16;
  const int c0  = l * 8;

  float4 bb0 = *(const float4*)(bias + c0);
  float4 bb1 = *(const float4*)(bias + c0 + 4);
  float bbv[8] = {bb0.x,bb0.y,bb0.z,bb0.w,bb1.x,bb1.y,bb1.z,bb1.w};

  float bs[8] = {0,0,0,0,0,0,0,0};
  float bq[8] = {0,0,0,0,0,0,0,0};

  for(int node = gg; node < n; node += ngg){
    int off = offsets[node], end = offsets[node+1];
    float di = dinv[node];
    const float* hr = h + (size_t)node*D + c0;
    float4 s0 = *(const float4*)hr;
    float4 s1 = *(const float4*)(hr+4);
    float aa[8] = {di*s0.x,di*s0.y,di*s0.z,di*s0.w,di*s1.x,di*s1.y,di*s1.z,di*s1.w};
    float ab[8] = {0,0,0,0,0,0,0,0};
    float ac[8] = {0,0,0,0,0,0,0,0};
    float ad[8] = {0,0,0,0,0,0,0,0};
    int e = off;
    for(; e + 3 < end; e += 4){
      int i0 = csrE[e].x,   i1 = csrE[e+1].x, i2 = csrE[e+2].x, i3 = csrE[e+3].x;
      float d0 = dinv[i0], d1 = dinv[i1], d2 = dinv[i2], d3 = dinv[i3];
      const float* h0 = h + (size_t)i0*D + c0;
      const float* h1 = h + (size_t)i1*D + c0;
      const float* h2 = h + (size_t)i2*D + c0;
      const float* h3 = h + (size_t)i3*D + c0;
      float4 v00 = *(const float4*)h0, v01 = *(const float4*)(h0+4);
      float4 v10 = *(const float4*)h1, v11 = *(const float4*)(h1+4);
      float4 v20 = *(const float4*)h2, v21 = *(const float4*)(h2+4);
      float4 v30 = *(const float4*)h3, v31 = *(const float4*)(h3+4);
      aa[0]=fmaf(d0,v00.x,aa[0]); aa[1]=fmaf(d0,v00.y,aa[1]); aa[2]=fmaf(d0,v00.z,aa[2]); aa[3]=fmaf(d0,v00.w,aa[3]);
      aa[4]=fmaf(d0,v01.x,aa[4]); aa[5]=fmaf(d0,v01.y,aa[5]); aa[6]=fmaf(d0,v01.z,aa[6]); aa[7]=fmaf(d0,v01.w,aa[7]);
      ab[0]=fmaf(d1,v10.x,ab[0]); ab[1]=fmaf(d1,v10.y,ab[1]); ab[2]=fmaf(d1,v10.z,ab[2]); ab[3]=fmaf(d1,v10.w,ab[3]);
      ab[4]=fmaf(d1,v11.x,ab[4]); ab[5]=fmaf(d1,v11.y,ab[5]); ab[6]=fmaf(d1,v11.z,ab[6]); ab[7]=fmaf(d1,v11.w,ab[7]);
      ac[0]=fmaf(d2,v20.x,ac[0]); ac[1]=fmaf(d2,v20.y,ac[1]); ac[2]=fmaf(d2,v20.z,ac[2]); ac[3]=fmaf(d2,v20.w,ac[3]);
      ac[4]=fmaf(d2,v21.x,ac[4]); ac[5]=fmaf(d2,v21.y,ac[5]); ac[6]=fmaf(d2,v21.z,ac[6]); ac[7]=fmaf(d2,v21.w,ac[7]);
      ad[0]=fmaf(d3,v30.x,ad[0]); ad[1]=fmaf(d3,v30.y,ad[1]); ad[2]=fmaf(d3,v30.z,ad[2]); ad[3]=fmaf(d3,v30.w,ad[3]);
      ad[4]=fmaf(d3,v31.x,ad[4]); ad[5]=fmaf(d3,v31.y,ad[5]); ad[6]=fmaf(d3,v31.z,ad[6]); ad[7]=fmaf(d3,v31.w,ad[7]);
    }
    for(; e < end; e++){
      int i0 = csrE[e].x;
      float d0 = dinv[i0];
      const float* h0 = h + (size_t)i0*D + c0;
      float4 v00 = *(const float4*)h0, v01 = *(const float4*)(h0+4);
      aa[0]=fmaf(d0,v00.x,aa[0]); aa[1]=fmaf(d0,v00.y,aa[1]); aa[2]=fmaf(d0,v00.z,aa[2]); aa[3]=fmaf(d0,v00.w,aa[3]);
      aa[4]=fmaf(d0,v01.x,aa[4]); aa[5]=fmaf(d0,v01.y,aa[5]); aa[6]=fmaf(d0,v01.z,aa[6]); aa[7]=fmaf(d0,v01.w,aa[7]);
    }
    float r[8];
    #pragma unroll
    for(int j=0;j<8;j++){
      r[j] = fmaxf(fmaf(di, aa[j]+ab[j]+ac[j]+ad[j], bbv[j]), 0.f);
      bs[j] += r[j];
      bq[j] += r[j]*r[j];
    }
    float* orow = out + (size_t)node*D + c0;
    *(float4*)orow     = make_float4(r[0],r[1],r[2],r[3]);
    *(float4*)(orow+4) = make_float4(r[4],r[5],r[6],r[7]);
  }

  __shared__ float red[16][D];
  #pragma unroll
  for(int j=0;j<8;j++) red[grp][c0+j] = bs[j];
  __syncthreads();
  if(threadIdx.x < D){
    float s = 0.f;
    #pragma unroll
    for(int g=0;g<16;g++) s += red[g][threadIdx.x];
    psum[(size_t)blockIdx.x*D + threadIdx.x] = s;
  }
  __syncthreads();
  #pragma unroll
  for(int j=0;j<8;j++) red[grp][c0+j] = bq[j];
  __syncthreads();
  if(threadIdx.x < D){
    float s = 0.f;
    #pragma unroll
    for(int g=0;g<16;g++) s += red[g][threadIdx.x];
    psq[(size_t)blockIdx.x*D + threadIdx.x] = s;
  }
}

// ---------- BN params ----------
__global__ void k_colreduce(const float* __restrict__ psum, const float* __restrict__ psq,
                            int nb, const float* __restrict__ g, const float* __restrict__ be,
                            float* scale, float* shift, int n){
  int c = blockIdx.x;
  float s = 0, q = 0;
  for(int b = threadIdx.x; b < nb; b += blockDim.x){
    s += psum[(size_t)b*D + c]; q += psq[(size_t)b*D + c];
  }
  for(int o = 32; o; o >>= 1){ s += __shfl_xor(s, o); q += __shfl_xor(q, o); }
  __shared__ float ls[4], lq[4];
  int wv = threadIdx.x >> 6;
  if((threadIdx.x & 63) == 0){ ls[wv] = s; lq[wv] = q; }
  __syncthreads();
  if(threadIdx.x == 0){
    float S = ls[0]+ls[1]+ls[2]+ls[3], Q = lq[0]+lq[1]+lq[2]+lq[3];
    float mean = S / n;
    float var  = fmaxf(Q / n - mean*mean, 0.f);
    float sc   = g[c] * rsqrtf(var + 1e-5f);
    scale[c] = sc;
    shift[c] = fmaf(-mean, sc, be[c]);
  }
}

__global__ void k_fold(const float* __restrict__ W, const float* __restrict__ scale,
                       const float* __restrict__ shift, float* Wmod, float* cconst){
  int j = blockIdx.x, k = threadIdx.x;
  float w = W[k*D + j];
  Wmod[k*D + j] = scale[k] * w;
  float sm = shift[k] * w;
  for(int o = 32; o; o >>= 1) sm += __shfl_xor(sm, o);
  __shared__ float l2[2];
  if((k & 63) == 0) l2[k >> 6] = sm;
  __syncthreads();
  if(k == 0) cconst[j] = l2[0] + l2[1];
}

// ---------- semantic table ----------
__global__ void k_sem(const float* __restrict__ emb, const float* __restrict__ Wa,
                      const float* __restrict__ ba, const float* __restrict__ Wf, float* sem){
  int t = threadIdx.x;
  if(t < 32){
    float s = ba[0], q0 = 0, q1 = 0;
    for(int c = 0; c < D; c++){
      float e = emb[t*D + c];
      s  = fmaf(e, Wa[c],     s);
      q0 = fmaf(e, Wf[2*c],   q0);
      q1 = fmaf(e, Wf[2*c+1], q1);
    }
    sem[t] = s; sem[32 + t] = q0; sem[64 + t] = q1;
  }
}

// ---------- spatial branch scores ----------
__global__ void __launch_bounds__(256)
k_spatial(const float* __restrict__ R, const float* __restrict__ scale,
          const float* __restrict__ shift, const float* __restrict__ Wa,
          const float* __restrict__ ba, const float* __restrict__ Wf,
          const int* __restrict__ tt, const float* __restrict__ sem,
          float* s_sp, float* p0_sp, float* p1_sp, unsigned* maxkey, int n){
  int lane = threadIdx.x & 63;
  int wid  = (blockIdx.x*blockDim.x + threadIdx.x) >> 6;
  int nw   = (gridDim.x*blockDim.x) >> 6;
  float2 sc = ((const float2*)scale)[lane];
  float2 sh = ((const float2*)shift)[lane];
  float2 wa = ((const float2*)Wa)[lane];
  float4 wf = ((const float4*)Wf)[lane];
  float ba0 = ba[0];
  float mloc = -INFINITY, msem = -INFINITY;
  for(int node = wid; node < n; node += nw){
    float2 v = ((const float2*)(R + (size_t)node*D))[lane];
    float v0 = fmaf(v.x, sc.x, sh.x);
    float v1 = fmaf(v.y, sc.y, sh.y);
    float s  = v0*wa.x + v1*wa.y;
    float p0 = v0*wf.x + v1*wf.z;
    float p1 = v0*wf.y + v1*wf.w;
    for(int o = 32; o; o >>= 1){
      s += __shfl_xor(s, o); p0 += __shfl_xor(p0, o); p1 += __shfl_xor(p1, o);
    }
    s += ba0;
    if(lane == 0){ s_sp[node] = s; p0_sp[node] = p0; p1_sp[node] = p1; }
    mloc = fmaxf(mloc, s);
    msem = fmaxf(msem, sem[tt[node]]);
  }
  __shared__ float lm[4], lsm[4];
  int wv = threadIdx.x >> 6;
  if(lane == 0){ lm[wv] = mloc; lsm[wv] = msem; }
  __syncthreads();
  if(threadIdx.x == 0){
    float M  = fmaxf(fmaxf(lm[0], lm[1]),  fmaxf(lm[2], lm[3]));
    float M2 = fmaxf(fmaxf(lsm[0], lsm[1]), fmaxf(lsm[2], lsm[3]));
    atomicMax(&maxkey[0], fkey(M));
    atomicMax(&maxkey[2], fkey(M2));
  }
}

// ---------- softmax denominators ----------
__global__ void k_zsum(const float* __restrict__ s_sp, const float* __restrict__ s_te,
                       const int* __restrict__ tt, const float* __restrict__ sem,
                       Scal* sc, int n){
  float M0 = fdec(sc->maxkey[0]), M1 = fdec(sc->maxkey[1]), M2 = fdec(sc->maxkey[2]);
  int i = blockIdx.x*blockDim.x + threadIdx.x;
  int stride = gridDim.x*blockDim.x;
  float z0 = 0, z1 = 0, z2 = 0;
  for(; i < n; i += stride){
    z0 += expf(s_sp[i] - M0);
    z1 += expf(s_te[i] - M1);
    z2 += expf(sem[tt[i]] - M2);
  }
  for(int o = 32; o; o >>= 1){
    z0 += __shfl_xor(z0, o); z1 += __shfl_xor(z1, o); z2 += __shfl_xor(z2, o);
  }
  __shared__ float l0[4], l1[4], l2[4];
  int wv = threadIdx.x >> 6;
  if((threadIdx.x & 63) == 0){ l0[wv] = z0; l1[wv] = z1; l2[wv] = z2; }
  __syncthreads();
  if(threadIdx.x == 0){
    atomAddF(&sc->Z[0], l0[0]+l0[1]+l0[2]+l0[3]);
    atomAddF(&sc->Z[1], l1[0]+l1[1]+l1[2]+l1[3]);
    atomAddF(&sc->Z[2], l2[0]+l2[1]+l2[2]+l2[3]);
  }
}

// ---------- final combine ----------
__global__ void k_final(const float* __restrict__ s_sp, const float* __restrict__ p0_sp,
                        const float* __restrict__ p1_sp, const float* __restrict__ s_te,
                        const float* __restrict__ p0_te, const float* __restrict__ p1_te,
                        const int* __restrict__ tt, const float* __restrict__ sem,
                        const Scal* sc, const float* __restrict__ bf,
                        float* __restrict__ out, int n){
  int i = blockIdx.x*blockDim.x + threadIdx.x;
  if(i < n){
    float M0 = fdec(sc->maxkey[0]), M1 = fdec(sc->maxkey[1]), M2 = fdec(sc->maxkey[2]);
    float w0 = expf(s_sp[i] - M0) / sc->Z[0];
    float w1 = expf(s_te[i] - M1) / sc->Z[1];
    int t = tt[i];
    float w2 = expf(sem[t] - M2) / sc->Z[2];
    float o0 = w0*p0_sp[i] + w1*p0_te[i] + w2*sem[32 + t] + bf[0];
    float o1 = w0*p1_sp[i] + w1*p1_te[i] + w2*sem[64 + t] + bf[1];
    ((float2*)out)[i] = make_float2(o0, o1);
  }
}

extern "C" void kernel_launch(void* const* d_in, const int* in_sizes, int n_in,
                              void* d_out, int out_size, void* d_ws, size_t ws_size,
                              hipStream_t stream) {
  const int N = in_sizes[5];   // timestamps
  const int E = in_sizes[1];   // src

  const float* x   = (const float*)d_in[0];
  const int*   src = (const int*)  d_in[1];
  const int*   dst = (const int*)  d_in[2];
  const float* ea  = (const float*)d_in[3];
  const int*   tt  = (const int*)  d_in[4];
  const float* W1  = (const float*)d_in[6];  const float* b1 = (const float*)d_in[7];
  const float* W2  = (const float*)d_in[8];  const float* b2 = (const float*)d_in[9];
  const float* W3  = (const float*)d_in[10]; const float* b3 = (const float*)d_in[11];
  const float* Wt  = (const float*)d_in[12]; const float* bt = (const float*)d_in[13];
  const float* emb = (const float*)d_in[14];
  const float* Wa  = (const float*)d_in[15]; const float* ba = (const float*)d_in[16];
  const float* g1  = (const float*)d_in[17]; const float* be1= (const float*)d_in[18];
  const float* g2  = (const float*)d_in[19]; const float* be2= (const float*)d_in[20];
  const float* g3  = (const float*)d_in[21]; const float* be3= (const float*)d_in[22];
  const float* Wf  = (const float*)d_in[23]; const float* bf = (const float*)d_in[24];
  float* out = (float*)d_out;

  char* w = (char*)d_ws;
  size_t off = 0;
  auto take = [&](size_t bytes) -> char* {
    char* p = w + off;
    off = (off + bytes + 255) & ~(size_t)255;
    return p;
  };

  const int NB_AGG = 2048, NB_SP = 2048, NB_Z = 1024, NB_TF = 1024;

  float* bufA    = (float*)take((size_t)N*D*4);   // h (unscaled)
  float* bufB    = (float*)take((size_t)N*D*4);   // accT, then agg outputs
  int2*  csrE    = (int2*) take((size_t)E*8);
  int*   pos     = (int*)  take((size_t)E*4);
  int*   offsets = (int*)  take((size_t)(N+1)*4);
  float* dinv    = (float*)take((size_t)N*4);
  int*   blockSum= (int*)  take((size_t)SCAN_B*4);
  float* s_sp    = (float*)take((size_t)N*4);
  float* p0_sp   = (float*)take((size_t)N*4);
  float* p1_sp   = (float*)take((size_t)N*4);
  float* s_te    = (float*)take((size_t)N*4);
  float* p0_te   = (float*)take((size_t)N*4);
  float* p1_te   = (float*)take((size_t)N*4);
  float* psum    = (float*)take((size_t)NB_AGG*D*4);
  float* psq     = (float*)take((size_t)NB_AGG*D*4);
  float* Wmod    = (float*)take((size_t)D*D*4);
  float* cconst  = (float*)take((size_t)D*4);
  float* scaleb  = (float*)take((size_t)D*4);
  float* shiftb  = (float*)take((size_t)D*4);
  float* sem     = (float*)take((size_t)96*4);
  // --- zero-init region (contiguous) ---
  Scal* sc     = (Scal*)take(sizeof(Scal));
  int*  indeg  = (int*) take((size_t)N*4);
  unsigned long long* outAcc = (unsigned long long*)take((size_t)N*8);
  size_t zbytes = (size_t)((w + off) - (char*)sc);
  hipMemsetAsync(sc, 0, zbytes, stream);

  int gE = (E + 255) / 256;
  int gN = (N + 255) / 256;
  int gT = (N + BN - 1) / BN;

  // mega: edge pass (atomics) overlapped with layer-1 + temporal GEMMs
  k_mega<<<MEGA_GRID, 256, 0, stream>>>(src, dst, ea, indeg, outAcc, pos, sc, E,
                                        x, W1, Wt, bufA, bufB, N);
  // offsets + dinv (scan2 also finalizes edge stats)
  k_scan1<<<SCAN_B, SCAN_T, 0, stream>>>(indeg, blockSum, N);
  k_scan2<<<1, SCAN_B, 0, stream>>>(blockSum, sc, E);
  k_scan3<<<SCAN_B, SCAN_T, 0, stream>>>(indeg, blockSum, offsets, dinv, N);
  // CSR fill (no atomics)
  k_fill<<<gE, 256, 0, stream>>>(src, dst, ea, offsets, pos, csrE, E);
  // temporal finish (td inline; reads accT=bufB BEFORE agg1 overwrites it)
  k_tempfin<<<NB_TF, 256, 0, stream>>>(bufB, offsets, csrE, outAcc, sc, Wt, bt,
                                       Wa, ba, Wf, s_te, p0_te, p1_te, sc->maxkey, N);
  // layer 1
  k_agg<<<NB_AGG, 256, 0, stream>>>(bufA, offsets, csrE, dinv, b1, bufB, psum, psq, N);
  k_colreduce<<<D, 256, 0, stream>>>(psum, psq, NB_AGG, g1, be1, scaleb, shiftb, N);
  k_fold<<<D, D, 0, stream>>>(W2, scaleb, shiftb, Wmod, cconst);
  // layer 2
  k_gemm<<<gT, 256, 0, stream>>>(bufB, Wmod, cconst, bufA, N);
  k_agg<<<NB_AGG, 256, 0, stream>>>(bufA, offsets, csrE, dinv, b2, bufB, psum, psq, N);
  k_colreduce<<<D, 256, 0, stream>>>(psum, psq, NB_AGG, g2, be2, scaleb, shiftb, N);
  k_fold<<<D, D, 0, stream>>>(W3, scaleb, shiftb, Wmod, cconst);
  // layer 3
  k_gemm<<<gT, 256, 0, stream>>>(bufB, Wmod, cconst, bufA, N);
  k_agg<<<NB_AGG, 256, 0, stream>>>(bufA, offsets, csrE, dinv, b3, bufB, psum, psq, N);
  k_colreduce<<<D, 256, 0, stream>>>(psum, psq, NB_AGG, g3, be3, scaleb, shiftb, N);

  // branches
  k_sem<<<1, 64, 0, stream>>>(emb, Wa, ba, Wf, sem);
  k_spatial<<<NB_SP, 256, 0, stream>>>(bufB, scaleb, shiftb, Wa, ba, Wf, tt, sem,
                                       s_sp, p0_sp, p1_sp, sc->maxkey, N);
  // softmax + combine
  k_zsum<<<NB_Z, 256, 0, stream>>>(s_sp, s_te, tt, sem, sc, N);
  k_final<<<gN, 256, 0, stream>>>(s_sp, p0_sp, p1_sp, s_te, p0_te, p1_te,
                                  tt, sem, sc, bf, out, N);
}

// Round 9
// 998.011 us; speedup vs baseline: 2.3724x; 1.0029x over previous
//
#include <hip/hip_runtime.h>
#include <math.h>

#define D   128
#define WAVE 64

// GEMM tiling
#define BN  128
#define KP  32
#define TN  8
#define TJ  8
#define XSTR (BN + 4)

// scan config
#define SCAN_B 256
#define SCAN_T 256

// mega-kernel role interleave: period 7 = 4 edge + 3 gemm blocks
#define MEGA_EB 1024
#define MEGA_GB 768
#define MEGA_GRID 1792

#define MASK44 ((1ULL<<44) - 1)

struct Scal {
  double esum, esumsq;     // zero-init
  unsigned maxkey[3];      // zero-init (decodes below all finite)
  float Z[3];              // zero-init
  float emean, einv;       // written in k_scan2 tail
};

__device__ __forceinline__ unsigned fkey(float f){
  unsigned b = __float_as_uint(f);
  return (b & 0x80000000u) ? ~b : (b | 0x80000000u);
}
__device__ __forceinline__ float fdec(unsigned k){
  return (k & 0x80000000u) ? __uint_as_float(k & 0x7fffffffu) : __uint_as_float(~k);
}
__device__ __forceinline__ void atomAddF(float* p, float v){
  __hip_atomic_fetch_add(p, v, __ATOMIC_RELAXED, __HIP_MEMORY_SCOPE_AGENT);
}
__device__ __forceinline__ void atomAddD(double* p, double v){
  __hip_atomic_fetch_add(p, v, __ATOMIC_RELAXED, __HIP_MEMORY_SCOPE_AGENT);
}

// ---------- mega kernel: edge pass (atomic-bound) + layer-1/temporal dual GEMM (VALU-bound) ----------
__global__ void __launch_bounds__(256)
k_mega(const int* __restrict__ src, const int* __restrict__ dst,
       const float* __restrict__ ea, int* __restrict__ indeg,
       unsigned long long* __restrict__ outAcc, int* __restrict__ pos,
       Scal* sc, int E,
       const float* __restrict__ x, const float* __restrict__ W1,
       const float* __restrict__ Wt,
       float* __restrict__ h1, float* __restrict__ accT, int n){
  __shared__ float xs[KP][XSTR];
  __shared__ float ws[KP][D];
  __shared__ double ls[4], lq[4];
  const int grp  = blockIdx.x / 7;
  const int role = blockIdx.x % 7;

  if(role < 4){
    // ---- edge role ----
    int bid = grp*4 + role;
    int i = bid*256 + threadIdx.x;
    const int stride = MEGA_EB*256;
    double s = 0.0, q = 0.0;
    for(; i < E; i += stride){
      float v = fminf(fmaxf(ea[i], -1000.f), 1000.f);
      s += (double)v; q += (double)v * (double)v;
      pos[i] = atomicAdd(&indeg[dst[i]], 1);
      unsigned long long pk = (1ULL<<44) +
          (unsigned long long)(long long)((double)(v + 1024.0) * 1048576.0 + 0.5);
      atomicAdd(&outAcc[src[i]], pk);
    }
    for(int o = 32; o; o >>= 1){ s += __shfl_xor(s, o); q += __shfl_xor(q, o); }
    int wv = threadIdx.x >> 6;
    if((threadIdx.x & 63) == 0){ ls[wv] = s; lq[wv] = q; }
    __syncthreads();
    if(threadIdx.x == 0){
      atomAddD(&sc->esum,   ls[0]+ls[1]+ls[2]+ls[3]);
      atomAddD(&sc->esumsq, lq[0]+lq[1]+lq[2]+lq[3]);
    }
  } else {
    // ---- dual-GEMM role: h1 = x@W1 (unscaled), accT = x@Wt ----
    int gIdx = grp*3 + (role - 4);
    const int t  = threadIdx.x;
    const int jg = t & 15, ng = t >> 4;
    const int j0 = jg * TJ, n0 = ng * TN;
    const int nTiles = (n + BN - 1) / BN;
    for(int tile = gIdx; tile < nTiles; tile += MEGA_GB){
      const int nodeBase = tile * BN;
      float acc1[TN][TJ], acc2[TN][TJ];
      #pragma unroll
      for(int i=0;i<TN;i++)
        #pragma unroll
        for(int j=0;j<TJ;j++){ acc1[i][j]=0.f; acc2[i][j]=0.f; }

      for(int p=0;p<D/KP;p++){
        // stage x panel (transposed) + W1 panel
        #pragma unroll
        for(int q2=0;q2<4;q2++){
          int idx = t + q2*256;
          int node = idx >> 3, kq = idx & 7;
          int gn = nodeBase + node; if(gn >= n) gn = n-1;
          float4 v = *(const float4*)(x + (size_t)gn*D + p*KP + kq*4);
          xs[kq*4+0][node] = v.x; xs[kq*4+1][node] = v.y;
          xs[kq*4+2][node] = v.z; xs[kq*4+3][node] = v.w;
        }
        {
          const float4* Wp = (const float4*)(W1 + (size_t)p*KP*D);
          float4* w4 = (float4*)ws;
          w4[t]       = Wp[t];
          w4[t + 256] = Wp[t + 256];
          w4[t + 512] = Wp[t + 512];
          w4[t + 768] = Wp[t + 768];
        }
        __syncthreads();
        #pragma unroll 4
        for(int k=0;k<KP;k++){
          float4 xa = *(const float4*)&xs[k][n0];
          float4 xb = *(const float4*)&xs[k][n0+4];
          float4 wa = *(const float4*)&ws[k][j0];
          float4 wb = *(const float4*)&ws[k][j0+4];
          float xv[8] = {xa.x,xa.y,xa.z,xa.w,xb.x,xb.y,xb.z,xb.w};
          float wv[8] = {wa.x,wa.y,wa.z,wa.w,wb.x,wb.y,wb.z,wb.w};
          #pragma unroll
          for(int i=0;i<TN;i++)
            #pragma unroll
            for(int j=0;j<TJ;j++)
              acc1[i][j] = fmaf(xv[i], wv[j], acc1[i][j]);
        }
        __syncthreads();
        {
          const float4* Wp = (const float4*)(Wt + (size_t)p*KP*D);
          float4* w4 = (float4*)ws;
          w4[t]       = Wp[t];
          w4[t + 256] = Wp[t + 256];
          w4[t + 512] = Wp[t + 512];
          w4[t + 768] = Wp[t + 768];
        }
        __syncthreads();
        #pragma unroll 4
        for(int k=0;k<KP;k++){
          float4 xa = *(const float4*)&xs[k][n0];
          float4 xb = *(const float4*)&xs[k][n0+4];
          float4 wa = *(const float4*)&ws[k][j0];
          float4 wb = *(const float4*)&ws[k][j0+4];
          float xv[8] = {xa.x,xa.y,xa.z,xa.w,xb.x,xb.y,xb.z,xb.w};
          float wv[8] = {wa.x,wa.y,wa.z,wa.w,wb.x,wb.y,wb.z,wb.w};
          #pragma unroll
          for(int i=0;i<TN;i++)
            #pragma unroll
            for(int j=0;j<TJ;j++)
              acc2[i][j] = fmaf(xv[i], wv[j], acc2[i][j]);
        }
        __syncthreads();
      }
      #pragma unroll
      for(int i=0;i<TN;i++){
        int gn = nodeBase + n0 + i;
        if(gn < n){
          *(float4*)(h1  + (size_t)gn*D + j0)     = make_float4(acc1[i][0],acc1[i][1],acc1[i][2],acc1[i][3]);
          *(float4*)(h1  + (size_t)gn*D + j0 + 4) = make_float4(acc1[i][4],acc1[i][5],acc1[i][6],acc1[i][7]);
          *(float4*)(accT+ (size_t)gn*D + j0)     = make_float4(acc2[i][0],acc2[i][1],acc2[i][2],acc2[i][3]);
          *(float4*)(accT+ (size_t)gn*D + j0 + 4) = make_float4(acc2[i][4],acc2[i][5],acc2[i][6],acc2[i][7]);
        }
      }
    }
  }
}

// ---------- hierarchical scan ----------
__global__ void __launch_bounds__(SCAN_T)
k_scan1(const int* __restrict__ indeg, int* __restrict__ blockSum, int n){
  int tile  = (n + SCAN_B - 1) / SCAN_B;
  int start = blockIdx.x * tile;
  int end   = min(start + tile, n);
  int s = 0;
  for(int i = start + threadIdx.x; i < end; i += SCAN_T) s += indeg[i];
  #pragma unroll
  for(int o = 32; o; o >>= 1) s += __shfl_xor(s, o);
  __shared__ int ls[4];
  if((threadIdx.x & 63) == 0) ls[threadIdx.x >> 6] = s;
  __syncthreads();
  if(threadIdx.x == 0) blockSum[blockIdx.x] = ls[0]+ls[1]+ls[2]+ls[3];
}

__global__ void __launch_bounds__(SCAN_B)
k_scan2(int* blockSum, Scal* sc, int E){
  __shared__ int tmp[SCAN_B];
  int t = threadIdx.x;
  tmp[t] = blockSum[t];
  __syncthreads();
  for(int o = 1; o < SCAN_B; o <<= 1){
    int v = (t >= o) ? tmp[t-o] : 0;
    __syncthreads();
    tmp[t] += v;
    __syncthreads();
  }
  blockSum[t] = (t == 0) ? 0 : tmp[t-1];
  if(t == 0){
    double mean = sc->esum / E;
    double var  = (sc->esumsq - sc->esum*sc->esum/E) / (double)(E - 1);
    double sd   = sqrt(var > 0.0 ? var : 0.0);
    sc->emean = (float)mean;
    sc->einv  = (float)(1.0 / (sd + 1e-9));
  }
}

__global__ void __launch_bounds__(SCAN_T)
k_scan3(const int* __restrict__ indeg, const int* __restrict__ blockSum,
        int* __restrict__ offsets, float* __restrict__ dinv, int n){
  int tile  = (n + SCAN_B - 1) / SCAN_B;
  int start = blockIdx.x * tile;
  int end   = min(start + tile, n);
  int chunk = (tile + SCAN_T - 1) / SCAN_T;
  int t = threadIdx.x;
  int tstart = start + t * chunk;
  int tend   = min(tstart + chunk, end);
  int s = 0;
  for(int i = tstart; i < tend; i++) s += indeg[i];
  __shared__ int tmp[SCAN_T];
  tmp[t] = s;
  __syncthreads();
  for(int o = 1; o < SCAN_T; o <<= 1){
    int v = (t >= o) ? tmp[t-o] : 0;
    __syncthreads();
    tmp[t] += v;
    __syncthreads();
  }
  int run = blockSum[blockIdx.x] + ((t == 0) ? 0 : tmp[t-1]);
  for(int i = tstart; i < tend; i++){
    int dg = indeg[i];
    offsets[i] = run;
    run += dg;
    dinv[i] = rsqrtf((float)(dg + 1));
  }
  if(blockIdx.x == SCAN_B-1 && t == SCAN_T-1) offsets[n] = run;
}

// ---------- CSR fill: no atomics; 4 edges/thread, vectorized ----------
__global__ void __launch_bounds__(256)
k_fill(const int* __restrict__ src, const int* __restrict__ dst,
       const float* __restrict__ ea, const int* __restrict__ offsets,
       const int* __restrict__ pos, int2* __restrict__ csrE, int E){
  int q = blockIdx.x*blockDim.x + threadIdx.x;
  int e0 = q*4;
  if(e0 + 3 < E){
    int4   s = *(const int4*)(src+e0);
    int4   d = *(const int4*)(dst+e0);
    int4   p = *(const int4*)(pos+e0);
    float4 v = *(const float4*)(ea+e0);
    csrE[offsets[d.x]+p.x] = make_int2(s.x, __float_as_int(fminf(fmaxf(v.x,-1000.f),1000.f)));
    csrE[offsets[d.y]+p.y] = make_int2(s.y, __float_as_int(fminf(fmaxf(v.y,-1000.f),1000.f)));
    csrE[offsets[d.z]+p.z] = make_int2(s.z, __float_as_int(fminf(fmaxf(v.z,-1000.f),1000.f)));
    csrE[offsets[d.w]+p.w] = make_int2(s.w, __float_as_int(fminf(fmaxf(v.w,-1000.f),1000.f)));
  } else if(e0 < E){
    for(int e = e0; e < E; e++){
      float v = fminf(fmaxf(ea[e], -1000.f), 1000.f);
      csrE[offsets[dst[e]] + pos[e]] = make_int2(src[e], __float_as_int(v));
    }
  }
}

// ---------- temporal finish: 16 lanes/node, td inline + scores from accT ----------
__global__ void __launch_bounds__(256)
k_tempfin(const float* __restrict__ accT, const int* __restrict__ offsets,
          const int2* __restrict__ csrE, const unsigned long long* __restrict__ outAcc,
          const Scal* sc, const float* __restrict__ Wt, const float* __restrict__ bt,
          const float* __restrict__ Wa, const float* __restrict__ ba,
          const float* __restrict__ Wf,
          float* s_te, float* p0_te, float* p1_te, unsigned* maxkey, int n){
  const int l   = threadIdx.x & 15;
  const int grp = threadIdx.x >> 4;
  const int gg  = blockIdx.x*16 + grp;
  const int ngg = gridDim.x*16;
  const int c0  = l*8;
  float wl[8], bb[8], wa8[8], wf0[8], wf1[8];
  #pragma unroll
  for(int j=0;j<8;j++){
    wl[j]  = Wt[(size_t)D*D + c0 + j];
    bb[j]  = bt[c0+j];
    wa8[j] = Wa[c0+j];
    float2 w2 = ((const float2*)Wf)[c0+j];
    wf0[j]=w2.x; wf1[j]=w2.y;
  }
  float ba0 = ba[0];
  float emean = sc->emean, einv = sc->einv;
  float mloc = -INFINITY;
  for(int node = gg; node < n; node += ngg){
    int o0 = offsets[node], o1 = offsets[node+1];
    float sv = 0.f;
    for(int e = o0 + l; e < o1; e += 16) sv += __int_as_float(csrE[e].y);
    sv += __shfl_xor(sv,1); sv += __shfl_xor(sv,2);
    sv += __shfl_xor(sv,4); sv += __shfl_xor(sv,8);
    unsigned long long acc = outAcc[node];
    int cout = (int)(acc >> 44);
    double S_out = (double)(acc & MASK44)*(1.0/1048576.0) - 1024.0*(double)cout;
    int deg = (o1-o0) + cout;
    float S = sv + (float)S_out;
    float td = (S - emean*(float)deg)*einv / fmaxf((float)deg,1.f);
    const float* ar = accT + (size_t)node*D + c0;
    float4 v0 = *(const float4*)ar, v1 = *(const float4*)(ar+4);
    float av[8] = {v0.x,v0.y,v0.z,v0.w,v1.x,v1.y,v1.z,v1.w};
    float s=0.f, p0=0.f, p1=0.f;
    #pragma unroll
    for(int j=0;j<8;j++){
      float tv = fmaxf(av[j] + td*wl[j] + bb[j], 0.f);
      s  = fmaf(tv, wa8[j], s);
      p0 = fmaf(tv, wf0[j], p0);
      p1 = fmaf(tv, wf1[j], p1);
    }
    #pragma unroll
    for(int o=1;o<16;o<<=1){
      s += __shfl_xor(s,o); p0 += __shfl_xor(p0,o); p1 += __shfl_xor(p1,o);
    }
    if(l == 0){
      s += ba0;
      s_te[node] = s; p0_te[node] = p0; p1_te[node] = p1;
      mloc = fmaxf(mloc, s);
    }
  }
  __shared__ float lm[16];
  if(l == 0) lm[grp] = mloc;
  __syncthreads();
  if(threadIdx.x == 0){
    float M = -INFINITY;
    #pragma unroll
    for(int g=0;g<16;g++) M = fmaxf(M, lm[g]);
    atomicMax(&maxkey[1], fkey(M));
  }
}

// ---------- register-tiled GEMM (layers 2-3), panel prefetch into regs ----------
__global__ void __launch_bounds__(256, 4)
k_gemm(const float* __restrict__ A, const float* __restrict__ W,
       const float* __restrict__ cvec, float* __restrict__ out, int n){
  __shared__ float xs[KP][XSTR];
  __shared__ float ws[KP][D];
  const int t  = threadIdx.x;
  const int jg = t & 15, ng = t >> 4;
  const int j0 = jg * TJ, n0 = ng * TN;
  const int nodeBase = blockIdx.x * BN;

  auto loadx = [&](int p, float4* r){
    #pragma unroll
    for(int q=0;q<4;q++){
      int idx = t + q*256;
      int node = idx >> 3, kq = idx & 7;
      int gn = nodeBase + node; if(gn >= n) gn = n-1;
      r[q] = *(const float4*)(A + (size_t)gn*D + p*KP + kq*4);
    }
  };
  auto loadw = [&](int p, float4* r){
    const float4* Wp = (const float4*)(W + (size_t)p*KP*D);
    r[0] = Wp[t]; r[1] = Wp[t+256]; r[2] = Wp[t+512]; r[3] = Wp[t+768];
  };

  float cr[TJ];
  {
    float4 c0 = *(const float4*)(cvec + j0);
    float4 c1 = *(const float4*)(cvec + j0 + 4);
    cr[0]=c0.x; cr[1]=c0.y; cr[2]=c0.z; cr[3]=c0.w;
    cr[4]=c1.x; cr[5]=c1.y; cr[6]=c1.z; cr[7]=c1.w;
  }
  float acc[TN][TJ];
  #pragma unroll
  for(int i=0;i<TN;i++)
    #pragma unroll
    for(int j=0;j<TJ;j++) acc[i][j]=cr[j];

  float4 px[4], pw[4];
  loadx(0, px); loadw(0, pw);

  for(int p=0;p<D/KP;p++){
    // write staged regs to LDS
    {
      float4* ws4 = (float4*)ws;
      ws4[t] = pw[0]; ws4[t+256] = pw[1]; ws4[t+512] = pw[2]; ws4[t+768] = pw[3];
      #pragma unroll
      for(int q=0;q<4;q++){
        int idx = t + q*256;
        int node = idx >> 3, kq = idx & 7;
        float4 v = px[q];
        xs[kq*4+0][node] = v.x; xs[kq*4+1][node] = v.y;
        xs[kq*4+2][node] = v.z; xs[kq*4+3][node] = v.w;
      }
    }
    __syncthreads();
    if(p+1 < D/KP){ loadx(p+1, px); loadw(p+1, pw); }   // latency hides under compute
    #pragma unroll 4
    for(int k=0;k<KP;k++){
      float4 xa = *(const float4*)&xs[k][n0];
      float4 xb = *(const float4*)&xs[k][n0+4];
      float4 wa = *(const float4*)&ws[k][j0];
      float4 wb = *(const float4*)&ws[k][j0+4];
      float xv[8] = {xa.x,xa.y,xa.z,xa.w,xb.x,xb.y,xb.z,xb.w};
      float wv[8] = {wa.x,wa.y,wa.z,wa.w,wb.x,wb.y,wb.z,wb.w};
      #pragma unroll
      for(int i=0;i<TN;i++)
        #pragma unroll
        for(int j=0;j<TJ;j++)
          acc[i][j] = fmaf(xv[i], wv[j], acc[i][j]);
    }
    __syncthreads();
  }
  #pragma unroll
  for(int i=0;i<TN;i++){
    int gn = nodeBase + n0 + i;
    if(gn < n){
      *(float4*)(out + (size_t)gn*D + j0)     = make_float4(acc[i][0],acc[i][1],acc[i][2],acc[i][3]);
      *(float4*)(out + (size_t)gn*D + j0 + 4) = make_float4(acc[i][4],acc[i][5],acc[i][6],acc[i][7]);
    }
  }
}

// ---------- aggregation: h unscaled; dinv gathered per edge (L2-resident) ----------
__global__ void __launch_bounds__(256)
k_agg(const float* __restrict__ h, const int* __restrict__ offsets,
      const int2* __restrict__ csrE, const float* __restrict__ dinv,
      const float* __restrict__ bias, float* __restrict__ out,
      float* __restrict__ psum, float* __restrict__ psq, int n){
  const int l   = threadIdx.x & 15;
  const int grp = threadIdx.x >> 4;
  const int gg  = blockIdx.x * 16 + grp;
  const int ngg = gridDim.x * 16;
  const int c0  = l * 8;

  float4 bb0 = *(const float4*)(bias + c0);
  float4 bb1 = *(const float4*)(bias + c0 + 4);
  float bbv[8] = {bb0.x,bb0.y,bb0.z,bb0.w,bb1.x,bb1.y,bb1.z,bb1.w};

  float bs[8] = {0,0,0,0,0,0,0,0};
  float bq[8] = {0,0,0,0,0,0,0,0};

  for(int node = gg; node < n; node += ngg){
    int off = offsets[node], end = offsets[node+1];
    float di = dinv[node];
    const float* hr = h + (size_t)node*D + c0;
    float4 s0 = *(const float4*)hr;
    float4 s1 = *(const float4*)(hr+4);
    float aa[8] = {di*s0.x,di*s0.y,di*s0.z,di*s0.w,di*s1.x,di*s1.y,di*s1.z,di*s1.w};
    float ab[8] = {0,0,0,0,0,0,0,0};
    float ac[8] = {0,0,0,0,0,0,0,0};
    float ad[8] = {0,0,0,0,0,0,0,0};
    int e = off;
    for(; e + 3 < end; e += 4){
      int i0 = csrE[e].x,   i1 = csrE[e+1].x, i2 = csrE[e+2].x, i3 = csrE[e+3].x;
      float d0 = dinv[i0], d1 = dinv[i1], d2 = dinv[i2], d3 = dinv[i3];
      const float* h0 = h + (size_t)i0*D + c0;
      const float* h1 = h + (size_t)i1*D + c0;
      const float* h2 = h + (size_t)i2*D + c0;
      const float* h3 = h + (size_t)i3*D + c0;
      float4 v00 = *(const float4*)h0, v01 = *(const float4*)(h0+4);
      float4 v10 = *(const float4*)h1, v11 = *(const float4*)(h1+4);
      float4 v20 = *(const float4*)h2, v21 = *(const float4*)(h2+4);
      float4 v30 = *(const float4*)h3, v31 = *(const float4*)(h3+4);
      aa[0]=fmaf(d0,v00.x,aa[0]); aa[1]=fmaf(d0,v00.y,aa[1]); aa[2]=fmaf(d0,v00.z,aa[2]); aa[3]=fmaf(d0,v00.w,aa[3]);
      aa[4]=fmaf(d0,v01.x,aa[4]); aa[5]=fmaf(d0,v01.y,aa[5]); aa[6]=fmaf(d0,v01.z,aa[6]); aa[7]=fmaf(d0,v01.w,aa[7]);
      ab[0]=fmaf(d1,v10.x,ab[0]); ab[1]=fmaf(d1,v10.y,ab[1]); ab[2]=fmaf(d1,v10.z,ab[2]); ab[3]=fmaf(d1,v10.w,ab[3]);
      ab[4]=fmaf(d1,v11.x,ab[4]); ab[5]=fmaf(d1,v11.y,ab[5]); ab[6]=fmaf(d1,v11.z,ab[6]); ab[7]=fmaf(d1,v11.w,ab[7]);
      ac[0]=fmaf(d2,v20.x,ac[0]); ac[1]=fmaf(d2,v20.y,ac[1]); ac[2]=fmaf(d2,v20.z,ac[2]); ac[3]=fmaf(d2,v20.w,ac[3]);
      ac[4]=fmaf(d2,v21.x,ac[4]); ac[5]=fmaf(d2,v21.y,ac[5]); ac[6]=fmaf(d2,v21.z,ac[6]); ac[7]=fmaf(d2,v21.w,ac[7]);
      ad[0]=fmaf(d3,v30.x,ad[0]); ad[1]=fmaf(d3,v30.y,ad[1]); ad[2]=fmaf(d3,v30.z,ad[2]); ad[3]=fmaf(d3,v30.w,ad[3]);
      ad[4]=fmaf(d3,v31.x,ad[4]); ad[5]=fmaf(d3,v31.y,ad[5]); ad[6]=fmaf(d3,v31.z,ad[6]); ad[7]=fmaf(d3,v31.w,ad[7]);
    }
    for(; e < end; e++){
      int i0 = csrE[e].x;
      float d0 = dinv[i0];
      const float* h0 = h + (size_t)i0*D + c0;
      float4 v00 = *(const float4*)h0, v01 = *(const float4*)(h0+4);
      aa[0]=fmaf(d0,v00.x,aa[0]); aa[1]=fmaf(d0,v00.y,aa[1]); aa[2]=fmaf(d0,v00.z,aa[2]); aa[3]=fmaf(d0,v00.w,aa[3]);
      aa[4]=fmaf(d0,v01.x,aa[4]); aa[5]=fmaf(d0,v01.y,aa[5]); aa[6]=fmaf(d0,v01.z,aa[6]); aa[7]=fmaf(d0,v01.w,aa[7]);
    }
    float r[8];
    #pragma unroll
    for(int j=0;j<8;j++){
      r[j] = fmaxf(fmaf(di, aa[j]+ab[j]+ac[j]+ad[j], bbv[j]), 0.f);
      bs[j] += r[j];
      bq[j] += r[j]*r[j];
    }
    float* orow = out + (size_t)node*D + c0;
    *(float4*)orow     = make_float4(r[0],r[1],r[2],r[3]);
    *(float4*)(orow+4) = make_float4(r[4],r[5],r[6],r[7]);
  }

  __shared__ float red[16][D];
  #pragma unroll
  for(int j=0;j<8;j++) red[grp][c0+j] = bs[j];
  __syncthreads();
  if(threadIdx.x < D){
    float s = 0.f;
    #pragma unroll
    for(int g=0;g<16;g++) s += red[g][threadIdx.x];
    psum[(size_t)blockIdx.x*D + threadIdx.x] = s;
  }
  __syncthreads();
  #pragma unroll
  for(int j=0;j<8;j++) red[grp][c0+j] = bq[j];
  __syncthreads();
  if(threadIdx.x < D){
    float s = 0.f;
    #pragma unroll
    for(int g=0;g<16;g++) s += red[g][threadIdx.x];
    psq[(size_t)blockIdx.x*D + threadIdx.x] = s;
  }
}

// ---------- BN params ----------
__global__ void k_colreduce(const float* __restrict__ psum, const float* __restrict__ psq,
                            int nb, const float* __restrict__ g, const float* __restrict__ be,
                            float* scale, float* shift, int n){
  int c = blockIdx.x;
  float s = 0, q = 0;
  for(int b = threadIdx.x; b < nb; b += blockDim.x){
    s += psum[(size_t)b*D + c]; q += psq[(size_t)b*D + c];
  }
  for(int o = 32; o; o >>= 1){ s += __shfl_xor(s, o); q += __shfl_xor(q, o); }
  __shared__ float ls[4], lq[4];
  int wv = threadIdx.x >> 6;
  if((threadIdx.x & 63) == 0){ ls[wv] = s; lq[wv] = q; }
  __syncthreads();
  if(threadIdx.x == 0){
    float S = ls[0]+ls[1]+ls[2]+ls[3], Q = lq[0]+lq[1]+lq[2]+lq[3];
    float mean = S / n;
    float var  = fmaxf(Q / n - mean*mean, 0.f);
    float sc   = g[c] * rsqrtf(var + 1e-5f);
    scale[c] = sc;
    shift[c] = fmaf(-mean, sc, be[c]);
  }
}

__global__ void k_fold(const float* __restrict__ W, const float* __restrict__ scale,
                       const float* __restrict__ shift, float* Wmod, float* cconst){
  int j = blockIdx.x, k = threadIdx.x;
  float w = W[k*D + j];
  Wmod[k*D + j] = scale[k] * w;
  float sm = shift[k] * w;
  for(int o = 32; o; o >>= 1) sm += __shfl_xor(sm, o);
  __shared__ float l2[2];
  if((k & 63) == 0) l2[k >> 6] = sm;
  __syncthreads();
  if(k == 0) cconst[j] = l2[0] + l2[1];
}

// ---------- semantic table ----------
__global__ void k_sem(const float* __restrict__ emb, const float* __restrict__ Wa,
                      const float* __restrict__ ba, const float* __restrict__ Wf, float* sem){
  int t = threadIdx.x;
  if(t < 32){
    float s = ba[0], q0 = 0, q1 = 0;
    for(int c = 0; c < D; c++){
      float e = emb[t*D + c];
      s  = fmaf(e, Wa[c],     s);
      q0 = fmaf(e, Wf[2*c],   q0);
      q1 = fmaf(e, Wf[2*c+1], q1);
    }
    sem[t] = s; sem[32 + t] = q0; sem[64 + t] = q1;
  }
}

// ---------- spatial branch scores ----------
__global__ void __launch_bounds__(256)
k_spatial(const float* __restrict__ R, const float* __restrict__ scale,
          const float* __restrict__ shift, const float* __restrict__ Wa,
          const float* __restrict__ ba, const float* __restrict__ Wf,
          const int* __restrict__ tt, const float* __restrict__ sem,
          float* s_sp, float* p0_sp, float* p1_sp, unsigned* maxkey, int n){
  int lane = threadIdx.x & 63;
  int wid  = (blockIdx.x*blockDim.x + threadIdx.x) >> 6;
  int nw   = (gridDim.x*blockDim.x) >> 6;
  float2 sc = ((const float2*)scale)[lane];
  float2 sh = ((const float2*)shift)[lane];
  float2 wa = ((const float2*)Wa)[lane];
  float4 wf = ((const float4*)Wf)[lane];
  float ba0 = ba[0];
  float mloc = -INFINITY, msem = -INFINITY;
  for(int node = wid; node < n; node += nw){
    float2 v = ((const float2*)(R + (size_t)node*D))[lane];
    float v0 = fmaf(v.x, sc.x, sh.x);
    float v1 = fmaf(v.y, sc.y, sh.y);
    float s  = v0*wa.x + v1*wa.y;
    float p0 = v0*wf.x + v1*wf.z;
    float p1 = v0*wf.y + v1*wf.w;
    for(int o = 32; o; o >>= 1){
      s += __shfl_xor(s, o); p0 += __shfl_xor(p0, o); p1 += __shfl_xor(p1, o);
    }
    s += ba0;
    if(lane == 0){ s_sp[node] = s; p0_sp[node] = p0; p1_sp[node] = p1; }
    mloc = fmaxf(mloc, s);
    msem = fmaxf(msem, sem[tt[node]]);
  }
  __shared__ float lm[4], lsm[4];
  int wv = threadIdx.x >> 6;
  if(lane == 0){ lm[wv] = mloc; lsm[wv] = msem; }
  __syncthreads();
  if(threadIdx.x == 0){
    float M  = fmaxf(fmaxf(lm[0], lm[1]),  fmaxf(lm[2], lm[3]));
    float M2 = fmaxf(fmaxf(lsm[0], lsm[1]), fmaxf(lsm[2], lsm[3]));
    atomicMax(&maxkey[0], fkey(M));
    atomicMax(&maxkey[2], fkey(M2));
  }
}

// ---------- softmax denominators ----------
__global__ void k_zsum(const float* __restrict__ s_sp, const float* __restrict__ s_te,
                       const int* __restrict__ tt, const float* __restrict__ sem,
                       Scal* sc, int n){
  float M0 = fdec(sc->maxkey[0]), M1 = fdec(sc->maxkey[1]), M2 = fdec(sc->maxkey[2]);
  int i = blockIdx.x*blockDim.x + threadIdx.x;
  int stride = gridDim.x*blockDim.x;
  float z0 = 0, z1 = 0, z2 = 0;
  for(; i < n; i += stride){
    z0 += expf(s_sp[i] - M0);
    z1 += expf(s_te[i] - M1);
    z2 += expf(sem[tt[i]] - M2);
  }
  for(int o = 32; o; o >>= 1){
    z0 += __shfl_xor(z0, o); z1 += __shfl_xor(z1, o); z2 += __shfl_xor(z2, o);
  }
  __shared__ float l0[4], l1[4], l2[4];
  int wv = threadIdx.x >> 6;
  if((threadIdx.x & 63) == 0){ l0[wv] = z0; l1[wv] = z1; l2[wv] = z2; }
  __syncthreads();
  if(threadIdx.x == 0){
    atomAddF(&sc->Z[0], l0[0]+l0[1]+l0[2]+l0[3]);
    atomAddF(&sc->Z[1], l1[0]+l1[1]+l1[2]+l1[3]);
    atomAddF(&sc->Z[2], l2[0]+l2[1]+l2[2]+l2[3]);
  }
}

// ---------- final combine ----------
__global__ void k_final(const float* __restrict__ s_sp, const float* __restrict__ p0_sp,
                        const float* __restrict__ p1_sp, const float* __restrict__ s_te,
                        const float* __restrict__ p0_te, const float* __restrict__ p1_te,
                        const int* __restrict__ tt, const float* __restrict__ sem,
                        const Scal* sc, const float* __restrict__ bf,
                        float* __restrict__ out, int n){
  int i = blockIdx.x*blockDim.x + threadIdx.x;
  if(i < n){
    float M0 = fdec(sc->maxkey[0]), M1 = fdec(sc->maxkey[1]), M2 = fdec(sc->maxkey[2]);
    float w0 = expf(s_sp[i] - M0) / sc->Z[0];
    float w1 = expf(s_te[i] - M1) / sc->Z[1];
    int t = tt[i];
    float w2 = expf(sem[t] - M2) / sc->Z[2];
    float o0 = w0*p0_sp[i] + w1*p0_te[i] + w2*sem[32 + t] + bf[0];
    float o1 = w0*p1_sp[i] + w1*p1_te[i] + w2*sem[64 + t] + bf[1];
    ((float2*)out)[i] = make_float2(o0, o1);
  }
}

extern "C" void kernel_launch(void* const* d_in, const int* in_sizes, int n_in,
                              void* d_out, int out_size, void* d_ws, size_t ws_size,
                              hipStream_t stream) {
  const int N = in_sizes[5];   // timestamps
  const int E = in_sizes[1];   // src

  const float* x   = (const float*)d_in[0];
  const int*   src = (const int*)  d_in[1];
  const int*   dst = (const int*)  d_in[2];
  const float* ea  = (const float*)d_in[3];
  const int*   tt  = (const int*)  d_in[4];
  const float* W1  = (const float*)d_in[6];  const float* b1 = (const float*)d_in[7];
  const float* W2  = (const float*)d_in[8];  const float* b2 = (const float*)d_in[9];
  const float* W3  = (const float*)d_in[10]; const float* b3 = (const float*)d_in[11];
  const float* Wt  = (const float*)d_in[12]; const float* bt = (const float*)d_in[13];
  const float* emb = (const float*)d_in[14];
  const float* Wa  = (const float*)d_in[15]; const float* ba = (const float*)d_in[16];
  const float* g1  = (const float*)d_in[17]; const float* be1= (const float*)d_in[18];
  const float* g2  = (const float*)d_in[19]; const float* be2= (const float*)d_in[20];
  const float* g3  = (const float*)d_in[21]; const float* be3= (const float*)d_in[22];
  const float* Wf  = (const float*)d_in[23]; const float* bf = (const float*)d_in[24];
  float* out = (float*)d_out;

  char* w = (char*)d_ws;
  size_t off = 0;
  auto take = [&](size_t bytes) -> char* {
    char* p = w + off;
    off = (off + bytes + 255) & ~(size_t)255;
    return p;
  };

  const int NB_AGG = 2048, NB_SP = 2048, NB_Z = 1024, NB_TF = 1024;

  float* bufA    = (float*)take((size_t)N*D*4);   // h (unscaled)
  float* bufB    = (float*)take((size_t)N*D*4);   // accT, then agg outputs
  int2*  csrE    = (int2*) take((size_t)E*8);
  int*   pos     = (int*)  take((size_t)E*4);
  int*   offsets = (int*)  take((size_t)(N+1)*4);
  float* dinv    = (float*)take((size_t)N*4);
  int*   blockSum= (int*)  take((size_t)SCAN_B*4);
  float* s_sp    = (float*)take((size_t)N*4);
  float* p0_sp   = (float*)take((size_t)N*4);
  float* p1_sp   = (float*)take((size_t)N*4);
  float* s_te    = (float*)take((size_t)N*4);
  float* p0_te   = (float*)take((size_t)N*4);
  float* p1_te   = (float*)take((size_t)N*4);
  float* psum    = (float*)take((size_t)NB_AGG*D*4);
  float* psq     = (float*)take((size_t)NB_AGG*D*4);
  float* Wmod    = (float*)take((size_t)D*D*4);
  float* cconst  = (float*)take((size_t)D*4);
  float* scaleb  = (float*)take((size_t)D*4);
  float* shiftb  = (float*)take((size_t)D*4);
  float* sem     = (float*)take((size_t)96*4);
  // --- zero-init region (contiguous) ---
  Scal* sc     = (Scal*)take(sizeof(Scal));
  int*  indeg  = (int*) take((size_t)N*4);
  unsigned long long* outAcc = (unsigned long long*)take((size_t)N*8);
  size_t zbytes = (size_t)((w + off) - (char*)sc);
  hipMemsetAsync(sc, 0, zbytes, stream);

  int gN  = (N + 255) / 256;
  int gT  = (N + BN - 1) / BN;
  int gF4 = ((E + 3) / 4 + 255) / 256;

  // mega: edge pass (atomics) overlapped with layer-1 + temporal GEMMs
  k_mega<<<MEGA_GRID, 256, 0, stream>>>(src, dst, ea, indeg, outAcc, pos, sc, E,
                                        x, W1, Wt, bufA, bufB, N);
  // offsets + dinv (scan2 also finalizes edge stats)
  k_scan1<<<SCAN_B, SCAN_T, 0, stream>>>(indeg, blockSum, N);
  k_scan2<<<1, SCAN_B, 0, stream>>>(blockSum, sc, E);
  k_scan3<<<SCAN_B, SCAN_T, 0, stream>>>(indeg, blockSum, offsets, dinv, N);
  // CSR fill (no atomics, 4 edges/thread)
  k_fill<<<gF4, 256, 0, stream>>>(src, dst, ea, offsets, pos, csrE, E);
  // temporal finish (td inline; reads accT=bufB BEFORE agg1 overwrites it)
  k_tempfin<<<NB_TF, 256, 0, stream>>>(bufB, offsets, csrE, outAcc, sc, Wt, bt,
                                       Wa, ba, Wf, s_te, p0_te, p1_te, sc->maxkey, N);
  // layer 1
  k_agg<<<NB_AGG, 256, 0, stream>>>(bufA, offsets, csrE, dinv, b1, bufB, psum, psq, N);
  k_colreduce<<<D, 256, 0, stream>>>(psum, psq, NB_AGG, g1, be1, scaleb, shiftb, N);
  k_fold<<<D, D, 0, stream>>>(W2, scaleb, shiftb, Wmod, cconst);
  // layer 2
  k_gemm<<<gT, 256, 0, stream>>>(bufB, Wmod, cconst, bufA, N);
  k_agg<<<NB_AGG, 256, 0, stream>>>(bufA, offsets, csrE, dinv, b2, bufB, psum, psq, N);
  k_colreduce<<<D, 256, 0, stream>>>(psum, psq, NB_AGG, g2, be2, scaleb, shiftb, N);
  k_fold<<<D, D, 0, stream>>>(W3, scaleb, shiftb, Wmod, cconst);
  // layer 3
  k_gemm<<<gT, 256, 0, stream>>>(bufB, Wmod, cconst, bufA, N);
  k_agg<<<NB_AGG, 256, 0, stream>>>(bufA, offsets, csrE, dinv, b3, bufB, psum, psq, N);
  k_colreduce<<<D, 256, 0, stream>>>(psum, psq, NB_AGG, g3, be3, scaleb, shiftb, N);

  // branches
  k_sem<<<1, 64, 0, stream>>>(emb, Wa, ba, Wf, sem);
  k_spatial<<<NB_SP, 256, 0, stream>>>(bufB, scaleb, shiftb, Wa, ba, Wf, tt, sem,
                                       s_sp, p0_sp, p1_sp, sc->maxkey, N);
  // softmax + combine
  k_zsum<<<NB_Z, 256, 0, stream>>>(s_sp, s_te, tt, sem, sc, N);
  k_final<<<gN, 256, 0, stream>>>(s_sp, p0_sp, p1_sp, s_te, p0_te, p1_te,
                                  tt, sem, sc, bf, out, N);
}